// Round 2
// baseline (4079.453 us; speedup 1.0000x reference)
//
#include <hip/hip_runtime.h>

#define DEV __device__ __forceinline__

typedef __attribute__((ext_vector_type(4))) float  f32x4;
typedef __attribute__((ext_vector_type(8))) short  s16x8;   // 8 bf16 (MFMA frag)
typedef __attribute__((ext_vector_type(4))) short  s16x4;   // 4 bf16 (8B ld/st)

union FragU { s16x8 v; unsigned short h[8]; };
union U4    { s16x4 v; unsigned short h[4]; };

DEV float lrelu(float x){ return x > 0.f ? x : 0.2f*x; }
DEV unsigned short bfrne(float f){
    unsigned u = __builtin_bit_cast(unsigned, f);
    u += 0x7fffu + ((u>>16)&1u);
    return (unsigned short)(u>>16);
}
DEV float bf2f(unsigned short h){
    unsigned u = ((unsigned)h)<<16; return __builtin_bit_cast(float,u);
}
DEV f32x4 mfma16(s16x8 a, s16x8 b, f32x4 c){
    return __builtin_amdgcn_mfma_f32_16x16x32_bf16(a, b, c, 0, 0, 0);
}
DEV float wave_sum(float v){
    #pragma unroll
    for(int m=32;m>0;m>>=1) v += __shfl_xor(v, m, 64);
    return v;
}
DEV void blk_reduce2(float& a, float& b, float* sm){
    a = wave_sum(a); b = wave_sum(b);
    int wv = threadIdx.x>>6, ln = threadIdx.x&63;
    if(ln==0){ sm[wv*2]=a; sm[wv*2+1]=b; }
    __syncthreads();
    a = sm[0]+sm[2]+sm[4]+sm[6];
    b = sm[1]+sm[3]+sm[5]+sm[7];
    __syncthreads();
}

// ---------------- sizes ----------------
// B=8 CIN=3 IMG=64 HW=4096 NF=32 NCALLS=8 LAT=512 F=384 GRP=4 CG=96
// DK_TOT=111744 S=36864 DK_HID=1024 OUT_CH=97 STATE=8224
#define EMB   1048576               // 8*32*4096, one out_emb
#define DKT   111744

// ---------------- init ----------------
__global__ __launch_bounds__(256) void k_init(
    float* state, float* latout, const float* otlb,
    float* lats, const float* inj,
    float* sbuf, const float* flbs, float* hbuf, const float* flb0,
    float* tbuf, const float* flb1,
    float* Hpre, const float* dkb0,
    unsigned short* w016, const float* c0w,
    unsigned short* w116, const float* c1w,
    unsigned short* wcsh, unsigned short* wcsl, const float* csw)
{
    int i = blockIdx.x*256 + threadIdx.x;
    if(i < 65792){ state[i] = 0.f; return; }            i -= 65792;
    if(i < 4096){ latout[i] = otlb[i&511]; return; }    i -= 4096;
    if(i < 4096){ lats[i] = inj[i]; return; }           i -= 4096;
    if(i < 32768){ sbuf[i] = flbs[(i>>12)*512 + (i&511)]; return; } i -= 32768;
    if(i < 32768){ hbuf[i] = flb0[(i>>12)*512 + (i&511)]; return; } i -= 32768;
    if(i < 32768){ tbuf[i] = flb1[(i>>12)*512 + (i&511)]; return; } i -= 32768;
    if(i < 65536){ Hpre[i] = dkb0[i&1023]; return; }    i -= 65536;
    if(i < 147456){ w016[i] = bfrne(c0w[i]); return; }  i -= 147456;
    if(i < 12288){ w116[i] = bfrne(c1w[i]); return; }   i -= 12288;
    if(i < 12288){ wcsh[i] = bfrne(csw[i]); return; }   i -= 12288;
    if(i < 12288){ unsigned short hh = bfrne(csw[i]); wcsl[i] = bfrne(csw[i] - bf2f(hh)); return; }
}

// ---------------- out_embs[0] = in_conv(x) ----------------
__global__ __launch_bounds__(256) void k_out0(const float* __restrict__ x,
    const float* __restrict__ w, const float* __restrict__ b, float* __restrict__ out0)
{
    int i = blockIdx.x*256 + threadIdx.x;       // < 1048576
    int p = i & 4095, o = (i>>12)&31, bb = i>>17;
    const float* xb = x + (size_t)bb*12288 + p;
    out0[i] = b[o] + w[o*3]*xb[0] + w[o*3+1]*xb[4096] + w[o*3+2]*xb[8192];
}

// ---------------- latent chain (f32) -----------------
__global__ __launch_bounds__(256) void k_latA(const float* __restrict__ lat,
    const float* __restrict__ Ws, const float* __restrict__ W0,
    float* __restrict__ sbuf, float* __restrict__ hbuf)
{
    __shared__ float ls[8][128];
    int t = threadIdx.x;
    int kb = blockIdx.y*128;
    for(int i=t;i<1024;i+=256) ls[i>>7][i&127] = lat[(i>>7)*512 + kb + (i&127)];
    __syncthreads();
    const float* W = blockIdx.z ? W0 : Ws;
    float* ob = blockIdx.z ? hbuf : sbuf;
    int j = blockIdx.x*128 + (t&127);
    int klo = (t>>7)*64;
    float acc[8] = {0,0,0,0,0,0,0,0};
    for(int kk=0;kk<64;kk++){
        float wv_ = W[(size_t)(kb+klo+kk)*512 + j];
        #pragma unroll
        for(int m=0;m<8;m++) acc[m] += ls[m][klo+kk]*wv_;
    }
    #pragma unroll
    for(int m=0;m<8;m++) atomicAdd(ob + m*512 + j, acc[m]);
}

__global__ __launch_bounds__(256) void k_latB(const float* __restrict__ hpre,
    const float* __restrict__ W1, float* __restrict__ tbuf)
{
    __shared__ float ls[8][128];
    int t = threadIdx.x;
    int kb = blockIdx.y*128;
    for(int i=t;i<1024;i+=256){ float v = hpre[(i>>7)*512 + kb + (i&127)]; ls[i>>7][i&127] = lrelu(v); }
    __syncthreads();
    int j = blockIdx.x*128 + (t&127);
    int klo = (t>>7)*64;
    float acc[8] = {0,0,0,0,0,0,0,0};
    for(int kk=0;kk<64;kk++){
        float wv_ = W1[(size_t)(kb+klo+kk)*512 + j];
        #pragma unroll
        for(int m=0;m<8;m++) acc[m] += ls[m][klo+kk]*wv_;
    }
    #pragma unroll
    for(int m=0;m<8;m++) atomicAdd(tbuf + m*512 + j, acc[m]);
}

__global__ __launch_bounds__(256) void k_latC(const float* __restrict__ latc,
    const float* __restrict__ sb, const float* __restrict__ tb, float* __restrict__ latn)
{
    int i = blockIdx.x*256 + threadIdx.x;
    latn[i] = latc[i] + 0.1f*sb[i] + 0.01f*tb[i];
}

// ---------------- DK hidden: Hpre += latsAll[64,512] @ dk_W0 (f32) ------------
__global__ __launch_bounds__(256) void k_dkH(const float* __restrict__ latsAll,
    const float* __restrict__ W0, float* __restrict__ Hpre)
{
    __shared__ float ls[64][128];
    int t = threadIdx.x;
    int kb = blockIdx.y*128;
    for(int i=t;i<8192;i+=256) ls[i>>7][i&127] = latsAll[(i>>7)*512 + kb + (i&127)];
    __syncthreads();
    int j = blockIdx.x*128 + (t&127);
    int ksub = t>>7;
    for(int mc=0;mc<4;mc++){
        float acc[16] = {0,0,0,0,0,0,0,0,0,0,0,0,0,0,0,0};
        for(int kk=0;kk<64;kk++){
            float wv_ = W0[(size_t)(kb + ksub*64 + kk)*1024 + j];
            #pragma unroll
            for(int mi=0;mi<16;mi++) acc[mi] += ls[mc*16+mi][ksub*64+kk]*wv_;
        }
        #pragma unroll
        for(int mi=0;mi<16;mi++) atomicAdd(Hpre + (size_t)(mc*16+mi)*1024 + j, acc[mi]);
    }
}

// A = [lats | 0.1*leaky(Hpre)] split hi/lo
__global__ __launch_bounds__(256) void k_dkAcvt(const float* __restrict__ latsAll,
    const float* __restrict__ Hpre, unsigned short* __restrict__ Ahi,
    unsigned short* __restrict__ Alo)
{
    int i = blockIdx.x*256 + threadIdx.x;   // < 98304
    int m = i/1536, k = i - m*1536;
    float v = (k < 512) ? latsAll[m*512 + k] : 0.1f*lrelu(Hpre[(size_t)m*1024 + (k-512)]);
    unsigned short hh = bfrne(v);
    Ahi[i] = hh; Alo[i] = bfrne(v - bf2f(hh));
}

// ---------------- KS[64,111744] = A @ [dkWs ; dkW1] + bias (split precision) --
__global__ __launch_bounds__(256) void k_dkMain(const unsigned short* __restrict__ Ahi,
    const unsigned short* __restrict__ Alo,
    const float* __restrict__ Wsb, const float* __restrict__ W1b,
    const float* __restrict__ bs, const float* __restrict__ b1,
    unsigned short* __restrict__ KShi, unsigned short* __restrict__ KSlo,
    float* __restrict__ KSb32)
{
    int t = threadIdx.x, wv = t>>6, lane = t&63, l15 = lane&15, lg = lane>>4, lkb = lg*8;
    int nb = blockIdx.x*128 + wv*32;
    f32x4 acc[4][2];
    #pragma unroll
    for(int mt=0;mt<4;mt++){ acc[mt][0]=f32x4{0,0,0,0}; acc[mt][1]=f32x4{0,0,0,0}; }

    #pragma unroll 1
    for(int kt=0;kt<48;kt++){
        int k0 = kt*32 + lkb;
        s16x8 ah[4], al[4];
        #pragma unroll
        for(int mt=0;mt<4;mt++){
            ah[mt] = *(const s16x8*)(Ahi + (size_t)(mt*16+l15)*1536 + kt*32 + lkb);
            al[mt] = *(const s16x8*)(Alo + (size_t)(mt*16+l15)*1536 + kt*32 + lkb);
        }
        #pragma unroll
        for(int nt=0;nt<2;nt++){
            int n = nb + nt*16 + l15;
            const float* W = (kt<16) ? (Wsb + (size_t)k0*DKT + n)
                                     : (W1b + (size_t)(k0-512)*DKT + n);
            FragU fh, fl;
            #pragma unroll
            for(int jj=0;jj<8;jj++){
                float w = W[(size_t)jj*DKT];
                unsigned short hh = bfrne(w);
                fh.h[jj] = hh; fl.h[jj] = bfrne(w - bf2f(hh));
            }
            #pragma unroll
            for(int mt=0;mt<4;mt++){
                acc[mt][nt] = mfma16(ah[mt], fh.v, acc[mt][nt]);
                acc[mt][nt] = mfma16(ah[mt], fl.v, acc[mt][nt]);
                acc[mt][nt] = mfma16(al[mt], fh.v, acc[mt][nt]);
            }
        }
    }
    #pragma unroll
    for(int nt=0;nt<2;nt++){
        int n = nb + nt*16 + l15;
        float bias = bs[n] + 0.1f*b1[n];
        #pragma unroll
        for(int mt=0;mt<4;mt++)
            #pragma unroll
            for(int q=0;q<4;q++){
                int row = mt*16 + lg*4 + q;
                float v = acc[mt][nt][q] + bias;
                unsigned short hh = bfrne(v);
                KShi[(size_t)row*DKT + n] = hh;
                KSlo[(size_t)row*DKT + n] = bfrne(v - bf2f(hh));
                if(n >= 110592) KSb32[(size_t)row*1152 + (n - 110592)] = v;
            }
    }
}

// ---------------- separable sin-sobel + instance-norm -> z hi/lo (NHWC) -------
__global__ __launch_bounds__(256) void k_sobel(const float* __restrict__ outPrev,
    unsigned short* __restrict__ zh, unsigned short* __restrict__ zl)
{
    __shared__ float img[4096], va[4096], vb[4096];
    __shared__ float ct[17], stp[17];
    __shared__ float red[8];
    int t = threadIdx.x, ch = blockIdx.x, b = blockIdx.y;
    const float* src = outPrev + ((size_t)b*32 + ch)*4096;
    for(int i=t;i<4096;i+=256) img[i] = src[i];
    __syncthreads();
    float s0=0.f, s1=0.f;
    for(int i=t;i<4096;i+=256){ float v=img[i]; s0+=v; s1+=v*v; }
    blk_reduce2(s0, s1, red);
    float mu = s0*(1.f/4096.f);
    float var = s1*(1.f/4096.f) - mu*mu; var = var<0.f?0.f:var;
    float rs = rsqrtf(var + 1e-5f);
    unsigned short* zbh = zh + (size_t)b*4096*384;
    unsigned short* zbl = zl + (size_t)b*4096*384;
    for(int i=t;i<4096;i+=256){
        float v = (img[i]-mu)*rs;
        unsigned short hh = bfrne(v), hl = bfrne(v - bf2f(hh));
        #pragma unroll
        for(int s=0;s<4;s++){
            zbh[(size_t)i*384 + 96*s + ch] = hh;
            zbl[(size_t)i*384 + 96*s + ch] = hl;
        }
    }
    const int ksz[4] = {3,5,9,17};
    for(int s=0;s<4;s++){
        int k = ksz[s], p = (k-1)>>1;
        if(t < k){
            float cc = -1.f + 2.f*(float)t/(float)(k-1);
            ct[t]  = cosf(1.5707963267948966f*cc);
            stp[t] = sinf(1.5707963267948966f*cc);
        }
        __syncthreads();
        for(int i=t;i<4096;i+=256){                     // vertical pass
            int y = i>>6, x = i&63; float ac=0.f, as=0.f;
            for(int tt=0;tt<k;tt++){
                int yy = y+tt-p;
                if(yy>=0 && yy<64){ float f = img[yy*64+x]; ac += ct[tt]*f; as += stp[tt]*f; }
            }
            va[i]=ac; vb[i]=as;
        }
        __syncthreads();
        float gx0=0.f,gx1=0.f,gy0=0.f,gy1=0.f;
        for(int i=t;i<4096;i+=256){
            int y=i>>6, x=i&63; float gx=0.f, gy=0.f;
            for(int tt=0;tt<k;tt++){
                int xx = x+tt-p;
                if(xx>=0 && xx<64){ gx += stp[tt]*va[y*64+xx]; gy += ct[tt]*vb[y*64+xx]; }
            }
            gx0+=gx; gx1+=gx*gx; gy0+=gy; gy1+=gy*gy;
        }
        blk_reduce2(gx0, gx1, red);
        blk_reduce2(gy0, gy1, red);
        float mgx = gx0*(1.f/4096.f), vgx = gx1*(1.f/4096.f)-mgx*mgx; vgx=vgx<0.f?0.f:vgx;
        float mgy = gy0*(1.f/4096.f), vgy = gy1*(1.f/4096.f)-mgy*mgy; vgy=vgy<0.f?0.f:vgy;
        float rgx = rsqrtf(vgx+1e-5f), rgy = rsqrtf(vgy+1e-5f);
        for(int i=t;i<4096;i+=256){
            int y=i>>6, x=i&63; float gx=0.f, gy=0.f;
            for(int tt=0;tt<k;tt++){
                int xx = x+tt-p;
                if(xx>=0 && xx<64){ gx += stp[tt]*va[y*64+xx]; gy += ct[tt]*vb[y*64+xx]; }
            }
            float vx = (gx-mgx)*rgx, vy = (gy-mgy)*rgy;
            unsigned short hx = bfrne(vx), hy = bfrne(vy);
            zbh[(size_t)i*384 + 96*s + 32 + ch] = hx;
            zbl[(size_t)i*384 + 96*s + 32 + ch] = bfrne(vx - bf2f(hx));
            zbh[(size_t)i*384 + 96*s + 64 + ch] = hy;
            zbl[(size_t)i*384 + 96*s + 64 + ch] = bfrne(vy - bf2f(hy));
        }
        __syncthreads();
    }
}

// ---------------- dyna grouped convs (split precision) + sigmoid gate ---------
// In-place: reads z (hi/lo), writes zz (hi/lo) to the same buffers. Safe: each
// (b,g,px) handled by exactly one wave; reads precede writes in program order.
__global__ __launch_bounds__(256) void k_dyna(
    const unsigned short* __restrict__ KShi, const unsigned short* __restrict__ KSlo,
    const float* __restrict__ KSb32,
    unsigned short* __restrict__ zh, unsigned short* __restrict__ zl, int cCall)
{
    __shared__ __align__(16) unsigned short lh[4][2][2][16][104];  // [wv][buf][hi/lo][px][och]
    int t=threadIdx.x, wv=t>>6, lane=t&63, l15=lane&15, lg=lane>>4, lkb=lg*8;
    int b=blockIdx.z, g=blockIdx.y, px0=blockIdx.x*64 + wv*16;
    int row = cCall*8 + b;
    const unsigned short* Khi = KShi + (size_t)row*DKT + g*9216;
    const unsigned short* Klo = KSlo + (size_t)row*DKT + g*9216;
    const float* Bf = KSb32 + (size_t)row*1152 + g*96;
    size_t zrow = ((size_t)b*4096 + px0 + l15)*384 + g*96;

    f32x4 acc[6];
    // ---- layer 1: k_in @ z ----
    #pragma unroll
    for(int mt=0;mt<6;mt++) acc[mt]=f32x4{0,0,0,0};
    #pragma unroll
    for(int kt=0;kt<3;kt++){
        s16x8 bh = *(const s16x8*)(zh + zrow + kt*32 + lkb);
        s16x8 bl = *(const s16x8*)(zl + zrow + kt*32 + lkb);
        #pragma unroll
        for(int mt=0;mt<6;mt++){
            s16x8 ah = *(const s16x8*)(Khi + (mt*16+l15)*96 + kt*32 + lkb);
            s16x8 al = *(const s16x8*)(Klo + (mt*16+l15)*96 + kt*32 + lkb);
            acc[mt] = mfma16(ah, bh, acc[mt]);
            acc[mt] = mfma16(ah, bl, acc[mt]);
            acc[mt] = mfma16(al, bh, acc[mt]);
        }
    }
    #pragma unroll
    for(int mt=0;mt<6;mt++){
        int o0 = mt*16 + lg*4;
        f32x4 bb = *(const f32x4*)(Bf + o0);
        U4 hh, hl;
        #pragma unroll
        for(int q=0;q<4;q++){
            float v = lrelu(acc[mt][q] + bb[q]);
            hh.h[q] = bfrne(v); hl.h[q] = bfrne(v - bf2f(hh.h[q]));
        }
        *(s16x4*)(&lh[wv][0][0][l15][o0]) = hh.v;
        *(s16x4*)(&lh[wv][0][1][l15][o0]) = hl.v;
    }
    // ---- layer 2: k_mid @ h1 ----
    #pragma unroll
    for(int mt=0;mt<6;mt++) acc[mt]=f32x4{0,0,0,0};
    #pragma unroll
    for(int kt=0;kt<3;kt++){
        s16x8 bh = *(const s16x8*)(&lh[wv][0][0][l15][kt*32+lkb]);
        s16x8 bl = *(const s16x8*)(&lh[wv][0][1][l15][kt*32+lkb]);
        #pragma unroll
        for(int mt=0;mt<6;mt++){
            s16x8 ah = *(const s16x8*)(Khi + 36864 + (mt*16+l15)*96 + kt*32 + lkb);
            s16x8 al = *(const s16x8*)(Klo + 36864 + (mt*16+l15)*96 + kt*32 + lkb);
            acc[mt] = mfma16(ah, bh, acc[mt]);
            acc[mt] = mfma16(ah, bl, acc[mt]);
            acc[mt] = mfma16(al, bh, acc[mt]);
        }
    }
    #pragma unroll
    for(int mt=0;mt<6;mt++){
        int o0 = mt*16 + lg*4;
        f32x4 bb = *(const f32x4*)(Bf + 384 + o0);
        U4 hh, hl;
        #pragma unroll
        for(int q=0;q<4;q++){
            float v = lrelu(acc[mt][q] + bb[q]);
            hh.h[q] = bfrne(v); hl.h[q] = bfrne(v - bf2f(hh.h[q]));
        }
        *(s16x4*)(&lh[wv][1][0][l15][o0]) = hh.v;
        *(s16x4*)(&lh[wv][1][1][l15][o0]) = hl.v;
    }
    // ---- layer 3: k_out @ h2, then gate ----
    #pragma unroll
    for(int mt=0;mt<6;mt++) acc[mt]=f32x4{0,0,0,0};
    #pragma unroll
    for(int kt=0;kt<3;kt++){
        s16x8 bh = *(const s16x8*)(&lh[wv][1][0][l15][kt*32+lkb]);
        s16x8 bl = *(const s16x8*)(&lh[wv][1][1][l15][kt*32+lkb]);
        #pragma unroll
        for(int mt=0;mt<6;mt++){
            s16x8 ah = *(const s16x8*)(Khi + 73728 + (mt*16+l15)*96 + kt*32 + lkb);
            s16x8 al = *(const s16x8*)(Klo + 73728 + (mt*16+l15)*96 + kt*32 + lkb);
            acc[mt] = mfma16(ah, bh, acc[mt]);
            acc[mt] = mfma16(ah, bl, acc[mt]);
            acc[mt] = mfma16(al, bh, acc[mt]);
        }
    }
    #pragma unroll
    for(int mt=0;mt<6;mt++){
        int o0 = mt*16 + lg*4;
        f32x4 bb = *(const f32x4*)(Bf + 768 + o0);
        U4 zvh, zvl;
        zvh.v = *(const s16x4*)(zh + zrow + o0);
        zvl.v = *(const s16x4*)(zl + zrow + o0);
        U4 ozh, ozl;
        #pragma unroll
        for(int q=0;q<4;q++){
            float zf = bf2f(zvh.h[q]) + bf2f(zvl.h[q]);
            float d  = zf + acc[mt][q] + bb[q];
            float sg = 1.f/(1.f + __expf(-d));
            float zz = zf*sg;
            ozh.h[q] = bfrne(zz); ozl.h[q] = bfrne(zz - bf2f(ozh.h[q]));
        }
        *(s16x4*)(zh + zrow + o0) = ozh.v;
        *(s16x4*)(zl + zrow + o0) = ozl.v;
    }
}

// ---------------- res_block + out update --------------------------------------
// zzh/zzl are the gated activations (stored in the z buffers by k_dyna).
__global__ __launch_bounds__(256) void k_resb(const unsigned short* __restrict__ zzh,
    const unsigned short* __restrict__ zzl,
    const unsigned short* __restrict__ w016, const unsigned short* __restrict__ w116,
    const unsigned short* __restrict__ wcsh, const unsigned short* __restrict__ wcsl,
    const float* __restrict__ c0b, const float* __restrict__ c1b, const float* __restrict__ csb,
    const float* __restrict__ outPrev, float* __restrict__ outNext)
{
    __shared__ __align__(16) unsigned short ldx[4][16][392];
    int t=threadIdx.x, wv=t>>6, lane=t&63, l15=lane&15, lg=lane>>4, lkb=lg*8;
    int b=blockIdx.y; int px0=blockIdx.x*64 + wv*16;
    size_t zrow = ((size_t)b*4096 + px0 + l15)*384;

    // G1: dx1[384][16] = c0w @ leaky(zz_full)
    f32x4 a1[24];
    #pragma unroll
    for(int mt=0;mt<24;mt++) a1[mt]=f32x4{0,0,0,0};
    #pragma unroll 1
    for(int kt=0;kt<12;kt++){
        FragU bzh, bzl, blz;
        bzh.v = *(const s16x8*)(zzh + zrow + kt*32 + lkb);
        bzl.v = *(const s16x8*)(zzl + zrow + kt*32 + lkb);
        #pragma unroll
        for(int j=0;j<8;j++) blz.h[j] = bfrne(lrelu(bf2f(bzh.h[j]) + bf2f(bzl.h[j])));
        #pragma unroll
        for(int mt=0;mt<24;mt++){
            s16x8 af = *(const s16x8*)(w016 + (size_t)(mt*16+l15)*384 + kt*32 + lkb);
            a1[mt] = mfma16(af, blz.v, a1[mt]);
        }
    }
    #pragma unroll
    for(int mt=0;mt<24;mt++){
        int o0 = mt*16 + lg*4;
        f32x4 bb = *(const f32x4*)(c0b + o0);
        U4 hv;
        #pragma unroll
        for(int q=0;q<4;q++) hv.h[q] = bfrne(lrelu(a1[mt][q] + bb[q]));
        *(s16x4*)(&ldx[wv][l15][o0]) = hv.v;
    }
    // G2: dx2 = c1w @ leaky(dx1) ; G3: r0 = csw @ zz  (split)
    f32x4 a2[2] = {f32x4{0,0,0,0}, f32x4{0,0,0,0}};
    f32x4 a3[2] = {f32x4{0,0,0,0}, f32x4{0,0,0,0}};
    #pragma unroll 1
    for(int kt=0;kt<12;kt++){
        s16x8 bh_ = *(const s16x8*)(&ldx[wv][l15][kt*32+lkb]);
        s16x8 bzh = *(const s16x8*)(zzh + zrow + kt*32 + lkb);
        s16x8 bzl = *(const s16x8*)(zzl + zrow + kt*32 + lkb);
        #pragma unroll
        for(int mt=0;mt<2;mt++){
            s16x8 af1 = *(const s16x8*)(w116 + (size_t)(mt*16+l15)*384 + kt*32 + lkb);
            a2[mt] = mfma16(af1, bh_, a2[mt]);
            s16x8 wh = *(const s16x8*)(wcsh + (size_t)(mt*16+l15)*384 + kt*32 + lkb);
            s16x8 wl = *(const s16x8*)(wcsl + (size_t)(mt*16+l15)*384 + kt*32 + lkb);
            a3[mt] = mfma16(wh, bzh, a3[mt]);
            a3[mt] = mfma16(wh, bzl, a3[mt]);
            a3[mt] = mfma16(wl, bzh, a3[mt]);
        }
    }
    #pragma unroll
    for(int mt=0;mt<2;mt++){
        int o0 = mt*16 + lg*4;
        #pragma unroll
        for(int q=0;q<4;q++){
            int o = o0+q, px = px0 + l15;
            float dx2 = a2[mt][q] + c1b[o];
            float r   = a3[mt][q] + csb[o] + 0.1f*dx2;
            size_t oidx = (size_t)b*131072 + (size_t)o*4096 + px;
            outNext[oidx] = outPrev[oidx] + 0.1f*r;
        }
    }
}

// ---------------- head ---------------------------------------------------------
__global__ __launch_bounds__(256) void k_head1(const float* __restrict__ outF,
    const float* __restrict__ wout, const float* __restrict__ bout, float* __restrict__ state)
{
    __shared__ float sw[97*32];
    __shared__ float sb_[97];
    __shared__ float fp[32];
    __shared__ float fwp[2048];
    int t = threadIdx.x, b = blockIdx.y, pxb = blockIdx.x*256;
    for(int i=t;i<97*32;i+=256) sw[i] = wout[i];
    if(t<97) sb_[t] = bout[t];
    if(t<32) fp[t] = 0.f;
    for(int i=t;i<2048;i+=256) fwp[i] = 0.f;
    __syncthreads();
    int px = pxb + t, lane = t&63, wv = t>>6;
    float xi[32];
    #pragma unroll
    for(int i=0;i<32;i++) xi[i] = outF[(size_t)b*131072 + (size_t)i*4096 + px];
    float* st = state + (size_t)b*8224;
    int row = (pxb>>6) + wv, x = lane;
    for(int o=0;o<97;o++){
        float acc = sb_[o];
        #pragma unroll
        for(int i=0;i<32;i++) acc += sw[o*32+i]*xi[i];
        if(o < 32){
            float s = wave_sum(acc);
            if(lane==0) atomicAdd(&fp[o], s);
        } else if(o < 64){
            float s = wave_sum(acc);
            if(lane==0) st[32 + (o-32)*64 + row] = s*(1.f/64.f);
        } else if(o < 96){
            atomicAdd(&fwp[(o-64)*64 + x], acc);
        } else {
            st[4128 + px] = acc;
        }
    }
    __syncthreads();
    if(t<32) atomicAdd(&st[t], fp[t]*(1.f/4096.f));
    for(int i=t;i<2048;i+=256) atomicAdd(&st[2080+i], fwp[i]*(1.f/64.f));
}

__global__ __launch_bounds__(256) void k_head2(const float* __restrict__ state,
    const float* __restrict__ otlw, float* __restrict__ latout)
{
    __shared__ float ss[8*514];
    int t = threadIdx.x, j = blockIdx.x*256 + t, s0 = blockIdx.y*514;
    for(int i=t;i<8*514;i+=256){ int bb=i/514, si=i-bb*514; ss[i] = state[(size_t)bb*8224 + s0 + si]; }
    __syncthreads();
    float acc[8] = {0,0,0,0,0,0,0,0};
    for(int si=0;si<514;si++){
        float wv_ = otlw[(size_t)(s0+si)*512 + j];
        #pragma unroll
        for(int b2=0;b2<8;b2++) acc[b2] += ss[b2*514+si]*wv_;
    }
    #pragma unroll
    for(int b2=0;b2<8;b2++) atomicAdd(latout + b2*512 + j, acc[b2]);
}

// =============================================================================
extern "C" void kernel_launch(void* const* d_in, const int* in_sizes, int n_in,
                              void* d_out, int out_size, void* d_ws, size_t ws_size,
                              hipStream_t stream)
{
    const float* x    = (const float*)d_in[0];
    const float* inj  = (const float*)d_in[1];
    const float* icw  = (const float*)d_in[2];
    const float* icb  = (const float*)d_in[3];
    const float* flWs = (const float*)d_in[4];
    const float* flbs = (const float*)d_in[5];
    const float* flW0 = (const float*)d_in[6];
    const float* flb0 = (const float*)d_in[7];
    const float* flW1 = (const float*)d_in[8];
    const float* flb1 = (const float*)d_in[9];
    const float* dkWs = (const float*)d_in[10];
    const float* dkbs = (const float*)d_in[11];
    const float* dkW0 = (const float*)d_in[12];
    const float* dkb0 = (const float*)d_in[13];
    const float* dkW1 = (const float*)d_in[14];
    const float* dkb1 = (const float*)d_in[15];
    const float* c0w  = (const float*)d_in[16];
    const float* c0b  = (const float*)d_in[17];
    const float* c1w  = (const float*)d_in[18];
    const float* c1b  = (const float*)d_in[19];
    const float* csw  = (const float*)d_in[20];
    const float* csb  = (const float*)d_in[21];
    const float* ocw  = (const float*)d_in[22];
    const float* ocb  = (const float*)d_in[23];
    const float* otlw = (const float*)d_in[24];
    const float* otlb = (const float*)d_in[25];
    float* out = (float*)d_out;

    // ---- carve workspace ----
    char* wp = (char*)d_ws;
    auto carve = [&](size_t bytes)->void*{ void* p = wp; wp += (bytes + 255) & ~(size_t)255; return p; };
    float* lats  = (float*)carve(36864*4);
    float* sbuf  = (float*)carve(32768*4);
    float* hbuf  = (float*)carve(32768*4);
    float* tbuf  = (float*)carve(32768*4);
    float* Hpre  = (float*)carve(65536*4);
    float* state = (float*)carve(65792*4);
    unsigned short* Ahi   = (unsigned short*)carve((size_t)98304*2);
    unsigned short* Alo   = (unsigned short*)carve((size_t)98304*2);
    unsigned short* KShi  = (unsigned short*)carve((size_t)7151616*2);
    unsigned short* KSlo  = (unsigned short*)carve((size_t)7151616*2);
    float*          KSb32 = (float*)carve((size_t)73728*4);          // [64][1152]
    unsigned short* w016  = (unsigned short*)carve((size_t)147456*2);
    unsigned short* w116  = (unsigned short*)carve((size_t)12288*2);
    unsigned short* wcsh  = (unsigned short*)carve((size_t)12288*2);
    unsigned short* wcsl  = (unsigned short*)carve((size_t)12288*2);
    unsigned short* zh    = (unsigned short*)carve((size_t)12582912*2);  // z then zz (hi)
    unsigned short* zl    = (unsigned short*)carve((size_t)12582912*2);  // z then zz (lo)

    k_init<<<1649,256,0,stream>>>(state, out, otlb, lats, inj,
                                  sbuf, flbs, hbuf, flb0, tbuf, flb1,
                                  Hpre, dkb0, w016, c0w, w116, c1w, wcsh, wcsl, csw);
    k_out0<<<4096,256,0,stream>>>(x, icw, icb, out + 4096);

    // latent chain (image-independent)
    for(int c=0;c<8;c++){
        const float* latc = lats + c*4096;
        k_latA<<<dim3(4,4,2),256,0,stream>>>(latc, flWs + (size_t)c*262144, flW0 + (size_t)c*262144,
                                             sbuf + c*4096, hbuf + c*4096);
        k_latB<<<dim3(4,4),256,0,stream>>>(hbuf + c*4096, flW1 + (size_t)c*262144, tbuf + c*4096);
        k_latC<<<16,256,0,stream>>>(latc, sbuf + c*4096, tbuf + c*4096, lats + (c+1)*4096);
    }

    // batched dynamic-weight generation (reads dk_Ws/dk_W1 exactly once)
    k_dkH<<<dim3(8,4),256,0,stream>>>(lats + 4096, dkW0, Hpre);
    k_dkAcvt<<<384,256,0,stream>>>(lats + 4096, Hpre, Ahi, Alo);
    k_dkMain<<<873,256,0,stream>>>(Ahi, Alo, dkWs, dkW1, dkbs, dkb1, KShi, KSlo, KSb32);

    // image path
    for(int c=0;c<8;c++){
        const float* outPrev = out + 4096 + (size_t)c*EMB;
        float*       outNext = out + 4096 + (size_t)(c+1)*EMB;
        k_sobel<<<dim3(32,8),256,0,stream>>>(outPrev, zh, zl);
        k_dyna<<<dim3(64,4,8),256,0,stream>>>(KShi, KSlo, KSb32, zh, zl, c);
        k_resb<<<dim3(64,8),256,0,stream>>>(zh, zl, w016, w116, wcsh, wcsl,
                                            c0b, c1b, csb, outPrev, outNext);
    }

    // head
    k_head1<<<dim3(16,8),256,0,stream>>>(out + 4096 + (size_t)8*EMB, ocw, ocb, state);
    k_head2<<<dim3(2,16),256,0,stream>>>(state, otlw, out);
}

// Round 3
// 4005.147 us; speedup vs baseline: 1.0186x; 1.0186x over previous
//
#include <hip/hip_runtime.h>

#define DEV __device__ __forceinline__

typedef __attribute__((ext_vector_type(4))) float  f32x4;
typedef __attribute__((ext_vector_type(8))) short  s16x8;   // 8 bf16 (MFMA frag)
typedef __attribute__((ext_vector_type(4))) short  s16x4;   // 4 bf16 (8B ld/st)
typedef __attribute__((ext_vector_type(4))) unsigned short u16x4;

union FragU { s16x8 v; unsigned short h[8]; };
union U4    { s16x4 v; unsigned short h[4]; };

DEV float lrelu(float x){ return x > 0.f ? x : 0.2f*x; }
DEV unsigned short bfrne(float f){
    unsigned u = __builtin_bit_cast(unsigned, f);
    u += 0x7fffu + ((u>>16)&1u);
    return (unsigned short)(u>>16);
}
DEV float bf2f(unsigned short h){
    unsigned u = ((unsigned)h)<<16; return __builtin_bit_cast(float,u);
}
DEV f32x4 mfma16(s16x8 a, s16x8 b, f32x4 c){
    return __builtin_amdgcn_mfma_f32_16x16x32_bf16(a, b, c, 0, 0, 0);
}
DEV float wave_sum(float v){
    #pragma unroll
    for(int m=32;m>0;m>>=1) v += __shfl_xor(v, m, 64);
    return v;
}
DEV void blk_reduce2(float& a, float& b, float* sm){
    a = wave_sum(a); b = wave_sum(b);
    int wv = threadIdx.x>>6, ln = threadIdx.x&63;
    if(ln==0){ sm[wv*2]=a; sm[wv*2+1]=b; }
    __syncthreads();
    a = sm[0]+sm[2]+sm[4]+sm[6];
    b = sm[1]+sm[3]+sm[5]+sm[7];
    __syncthreads();
}

// ---------------- sizes ----------------
// B=8 CIN=3 IMG=64 HW=4096 NF=32 NCALLS=8 LAT=512 F=384 GRP=4 CG=96
// DK_TOT=111744 S=36864 DK_HID=1024 OUT_CH=97 STATE=8224
#define EMB   1048576               // 8*32*4096, one out_emb
#define DKT   111744
// z layout: [b][part 0..11][px 0..4095][ch 0..31], part = 3*scale + {id,gx,gy}
#define ZPART 131072                // 4096*32

// ---------------- init ----------------
__global__ __launch_bounds__(256) void k_init(
    float* state, float* latout, const float* otlb,
    float* lats, const float* inj,
    float* sbuf, const float* flbs, float* hbuf, const float* flb0,
    float* Hpre, const float* dkb0,
    unsigned short* w016, const float* c0w,
    unsigned short* w116, const float* c1w,
    unsigned short* wcsh, unsigned short* wcsl, const float* csw)
{
    int i = blockIdx.x*256 + threadIdx.x;
    if(i < 65792){ state[i] = 0.f; return; }            i -= 65792;
    if(i < 4096){ latout[i] = otlb[i&511]; return; }    i -= 4096;
    if(i < 4096){ lats[i] = inj[i]; return; }           i -= 4096;
    if(i < 32768){ sbuf[i] = flbs[(i>>12)*512 + (i&511)]; return; } i -= 32768;
    if(i < 32768){ hbuf[i] = flb0[(i>>12)*512 + (i&511)]; return; } i -= 32768;
    if(i < 65536){ Hpre[i] = dkb0[i&1023]; return; }    i -= 65536;
    if(i < 147456){ w016[i] = bfrne(c0w[i]); return; }  i -= 147456;
    if(i < 12288){ w116[i] = bfrne(c1w[i]); return; }   i -= 12288;
    if(i < 12288){ wcsh[i] = bfrne(csw[i]); return; }   i -= 12288;
    if(i < 12288){ unsigned short hh = bfrne(csw[i]); wcsl[i] = bfrne(csw[i] - bf2f(hh)); return; }
}

// ---------------- out_embs[0] = in_conv(x) ----------------
__global__ __launch_bounds__(256) void k_out0(const float* __restrict__ x,
    const float* __restrict__ w, const float* __restrict__ b, float* __restrict__ out0)
{
    int i = blockIdx.x*256 + threadIdx.x;       // < 1048576
    int p = i & 4095, o = (i>>12)&31, bb = i>>17;
    const float* xb = x + (size_t)bb*12288 + p;
    out0[i] = b[o] + w[o*3]*xb[0] + w[o*3+1]*xb[4096] + w[o*3+2]*xb[8192];
}

// ---------------- latent chain (f32) -----------------
__global__ __launch_bounds__(256) void k_latA(const float* __restrict__ lat,
    const float* __restrict__ Ws, const float* __restrict__ W0,
    float* __restrict__ sbuf, float* __restrict__ hbuf)
{
    __shared__ float ls[8][128];
    int t = threadIdx.x;
    int kb = blockIdx.y*128;
    for(int i=t;i<1024;i+=256) ls[i>>7][i&127] = lat[(i>>7)*512 + kb + (i&127)];
    __syncthreads();
    const float* W = blockIdx.z ? W0 : Ws;
    float* ob = blockIdx.z ? hbuf : sbuf;
    int j = blockIdx.x*128 + (t&127);
    int klo = (t>>7)*64;
    float acc[8] = {0,0,0,0,0,0,0,0};
    for(int kk=0;kk<64;kk++){
        float wv_ = W[(size_t)(kb+klo+kk)*512 + j];
        #pragma unroll
        for(int m=0;m<8;m++) acc[m] += ls[m][klo+kk]*wv_;
    }
    #pragma unroll
    for(int m=0;m<8;m++) atomicAdd(ob + m*512 + j, acc[m]);
}

// fused: t1 = lrelu(hpre)@W1 + b1; latn = latc + 0.1*s + 0.01*t1
__global__ __launch_bounds__(256) void k_latBC(const float* __restrict__ hpre,
    const float* __restrict__ W1, const float* __restrict__ b1c,
    const float* __restrict__ latc, const float* __restrict__ sb,
    float* __restrict__ latn)
{
    __shared__ float lh[8][512];
    __shared__ float part[8][128];
    int t = threadIdx.x;
    for(int i=t;i<4096;i+=256) lh[i>>9][i&511] = lrelu(hpre[i]);
    __syncthreads();
    int j = blockIdx.x*128 + (t&127), half = t>>7;
    float acc[8] = {0,0,0,0,0,0,0,0};
    int k0 = half*256;
    for(int kk=k0;kk<k0+256;kk++){
        float w = W1[(size_t)kk*512 + j];
        #pragma unroll
        for(int m=0;m<8;m++) acc[m] += lh[m][kk]*w;
    }
    if(half==1){
        #pragma unroll
        for(int m=0;m<8;m++) part[m][t&127] = acc[m];
    }
    __syncthreads();
    if(half==0){
        #pragma unroll
        for(int m=0;m<8;m++){
            float t1 = acc[m] + part[m][t&127] + b1c[j];
            latn[m*512+j] = latc[m*512+j] + 0.1f*sb[m*512+j] + 0.01f*t1;
        }
    }
}

// ---------------- DK hidden: Hpre += latsAll[64,512] @ dk_W0 (f32) ------------
__global__ __launch_bounds__(256) void k_dkH(const float* __restrict__ latsAll,
    const float* __restrict__ W0, float* __restrict__ Hpre)
{
    __shared__ float ls[64][128];
    int t = threadIdx.x;
    int kb = blockIdx.y*128;
    for(int i=t;i<8192;i+=256) ls[i>>7][i&127] = latsAll[(i>>7)*512 + kb + (i&127)];
    __syncthreads();
    int j = blockIdx.x*128 + (t&127);
    int ksub = t>>7;
    for(int mc=0;mc<4;mc++){
        float acc[16] = {0,0,0,0,0,0,0,0,0,0,0,0,0,0,0,0};
        for(int kk=0;kk<64;kk++){
            float wv_ = W0[(size_t)(kb + ksub*64 + kk)*1024 + j];
            #pragma unroll
            for(int mi=0;mi<16;mi++) acc[mi] += ls[mc*16+mi][ksub*64+kk]*wv_;
        }
        #pragma unroll
        for(int mi=0;mi<16;mi++) atomicAdd(Hpre + (size_t)(mc*16+mi)*1024 + j, acc[mi]);
    }
}

// A = [lats | 0.1*leaky(Hpre)] split hi/lo
__global__ __launch_bounds__(256) void k_dkAcvt(const float* __restrict__ latsAll,
    const float* __restrict__ Hpre, unsigned short* __restrict__ Ahi,
    unsigned short* __restrict__ Alo)
{
    int i = blockIdx.x*256 + threadIdx.x;   // < 98304
    int m = i/1536, k = i - m*1536;
    float v = (k < 512) ? latsAll[m*512 + k] : 0.1f*lrelu(Hpre[(size_t)m*1024 + (k-512)]);
    unsigned short hh = bfrne(v);
    Ahi[i] = hh; Alo[i] = bfrne(v - bf2f(hh));
}

// ---------------- KS[64,111744] = A @ [dkWs ; dkW1] + bias (split precision) --
// 64 cols/block (grid 1746) for occupancy; was 128 cols (grid 873, Occ 26%).
__global__ __launch_bounds__(256) void k_dkMain(const unsigned short* __restrict__ Ahi,
    const unsigned short* __restrict__ Alo,
    const float* __restrict__ Wsb, const float* __restrict__ W1b,
    const float* __restrict__ bs, const float* __restrict__ b1,
    unsigned short* __restrict__ KShi, unsigned short* __restrict__ KSlo,
    float* __restrict__ KSb32)
{
    int t = threadIdx.x, wv = t>>6, lane = t&63, l15 = lane&15, lg = lane>>4, lkb = lg*8;
    int nb = blockIdx.x*64 + wv*16;
    int n = nb + l15;
    f32x4 acc[4];
    #pragma unroll
    for(int mt=0;mt<4;mt++) acc[mt]=f32x4{0,0,0,0};

    #pragma unroll 2
    for(int kt=0;kt<48;kt++){
        int k0 = kt*32 + lkb;
        const float* W = (kt<16) ? (Wsb + (size_t)k0*DKT + n)
                                 : (W1b + (size_t)(k0-512)*DKT + n);
        float w[8];
        #pragma unroll
        for(int jj=0;jj<8;jj++) w[jj] = W[(size_t)jj*DKT];
        s16x8 ah[4], al[4];
        #pragma unroll
        for(int mt=0;mt<4;mt++){
            ah[mt] = *(const s16x8*)(Ahi + (size_t)(mt*16+l15)*1536 + kt*32 + lkb);
            al[mt] = *(const s16x8*)(Alo + (size_t)(mt*16+l15)*1536 + kt*32 + lkb);
        }
        FragU fh, fl;
        #pragma unroll
        for(int jj=0;jj<8;jj++){
            unsigned short hh = bfrne(w[jj]);
            fh.h[jj] = hh; fl.h[jj] = bfrne(w[jj] - bf2f(hh));
        }
        #pragma unroll
        for(int mt=0;mt<4;mt++){
            acc[mt] = mfma16(ah[mt], fh.v, acc[mt]);
            acc[mt] = mfma16(ah[mt], fl.v, acc[mt]);
            acc[mt] = mfma16(al[mt], fh.v, acc[mt]);
        }
    }
    float bias = bs[n] + 0.1f*b1[n];
    #pragma unroll
    for(int mt=0;mt<4;mt++)
        #pragma unroll
        for(int q=0;q<4;q++){
            int row = mt*16 + lg*4 + q;
            float v = acc[mt][q] + bias;
            unsigned short hh = bfrne(v);
            KShi[(size_t)row*DKT + n] = hh;
            KSlo[(size_t)row*DKT + n] = bfrne(v - bf2f(hh));
            if(n >= 110592) KSb32[(size_t)row*1152 + (n - 110592)] = v;
        }
}

// ---------------- stats: per (b,ch) mean/rsqrt for id + 4x(gx,gy) -------------
__global__ __launch_bounds__(256) void k_stat(const float* __restrict__ outPrev,
    float2* __restrict__ stats)
{
    __shared__ float img[4096], va[4096], vb[4096];
    __shared__ float ct[17], stp[17];
    __shared__ float red[8];
    int t = threadIdx.x, ch = blockIdx.x, b = blockIdx.y;
    const float* src = outPrev + ((size_t)b*32 + ch)*4096;
    float2* stc = stats + (b*32 + ch)*9;
    for(int i=t;i<4096;i+=256) img[i] = src[i];
    __syncthreads();
    float s0=0.f, s1=0.f;
    for(int i=t;i<4096;i+=256){ float v=img[i]; s0+=v; s1+=v*v; }
    blk_reduce2(s0, s1, red);
    float mu = s0*(1.f/4096.f);
    float var = s1*(1.f/4096.f) - mu*mu; var = var<0.f?0.f:var;
    if(t==0) stc[0] = make_float2(mu, rsqrtf(var + 1e-5f));
    const int ksz[4] = {3,5,9,17};
    for(int s=0;s<4;s++){
        int k = ksz[s], p = (k-1)>>1;
        if(t < k){
            float cc = -1.f + 2.f*(float)t/(float)(k-1);
            ct[t]  = cosf(1.5707963267948966f*cc);
            stp[t] = sinf(1.5707963267948966f*cc);
        }
        __syncthreads();
        for(int i=t;i<4096;i+=256){                     // vertical pass
            int y = i>>6, x = i&63; float ac=0.f, as=0.f;
            for(int tt=0;tt<k;tt++){
                int yy = y+tt-p;
                if(yy>=0 && yy<64){ float f = img[yy*64+x]; ac += ct[tt]*f; as += stp[tt]*f; }
            }
            va[i]=ac; vb[i]=as;
        }
        __syncthreads();
        float gx0=0.f,gx1=0.f,gy0=0.f,gy1=0.f;
        for(int i=t;i<4096;i+=256){
            int y=i>>6, x=i&63; float gx=0.f, gy=0.f;
            for(int tt=0;tt<k;tt++){
                int xx = x+tt-p;
                if(xx>=0 && xx<64){ gx += stp[tt]*va[y*64+xx]; gy += ct[tt]*vb[y*64+xx]; }
            }
            gx0+=gx; gx1+=gx*gx; gy0+=gy; gy1+=gy*gy;
        }
        blk_reduce2(gx0, gx1, red);
        blk_reduce2(gy0, gy1, red);
        float mgx = gx0*(1.f/4096.f), vgx = gx1*(1.f/4096.f)-mgx*mgx; vgx=vgx<0.f?0.f:vgx;
        float mgy = gy0*(1.f/4096.f), vgy = gy1*(1.f/4096.f)-mgy*mgy; vgy=vgy<0.f?0.f:vgy;
        if(t==0){
            stc[1+2*s] = make_float2(mgx, rsqrtf(vgx+1e-5f));
            stc[2+2*s] = make_float2(mgy, rsqrtf(vgy+1e-5f));
        }
        __syncthreads();
    }
}

// coop write of one [64 px][32 ch] hi/lo tile to part-major z
DEV void coopw(const unsigned short (*zt)[64][36], int part, int b, int y,
               unsigned short* zh, unsigned short* zl, int t)
{
    #pragma unroll
    for(int buf=0;buf<2;buf++){
        unsigned short* dst = (buf ? zl : zh) + ((size_t)(b*12+part)*4096 + y*64)*32;
        #pragma unroll
        for(int pos=t; pos<512; pos+=256){
            int px = pos>>3, c4 = pos&7;
            u16x4 v = *(const u16x4*)(&zt[buf][px][c4*4]);
            *(u16x4*)(dst + pos*4) = v;
        }
    }
}

// ---------------- znorm: recompute convs, normalize, coalesced NHWC-part write
// grid (64 rows, 8 b); wave cq handles channels [cq*8, cq*8+8)
__global__ __launch_bounds__(256) void k_znorm(const float* __restrict__ outPrev,
    const float2* __restrict__ stats,
    unsigned short* __restrict__ zh, unsigned short* __restrict__ zl)
{
    __shared__ unsigned short zt[2][2][64][36];  // [partSlot][hi/lo][px][ch]
    __shared__ float va[4][80], vb[4][80];
    __shared__ float ct[17], stp[17];
    __shared__ float2 sst[288];
    int t = threadIdx.x, x = t&63, cq = t>>6;
    int y = blockIdx.x, b = blockIdx.y;
    const float* ob = outPrev + (size_t)b*131072;
    for(int i=t;i<288;i+=256) sst[i] = stats[b*288 + i];
    // zero the horizontal halo once (positions 0..7 and 72..79 are pad)
    if(x < 16){
        int xp2 = (x<8) ? x : (x+64);
        va[cq][xp2] = 0.f; vb[cq][xp2] = 0.f;
    }
    __syncthreads();
    // ---- identity part (value shared by all 4 scales) ----
    #pragma unroll
    for(int i=0;i<8;i++){
        int ch = cq*8 + i;
        float v = ob[(size_t)ch*4096 + y*64 + x];
        float2 sr = sst[ch*9];
        float z = (v - sr.x)*sr.y;
        unsigned short hh = bfrne(z);
        zt[0][0][x][ch] = hh; zt[0][1][x][ch] = bfrne(z - bf2f(hh));
    }
    __syncthreads();
    coopw(zt[0], 0, b, y, zh, zl, t);
    coopw(zt[0], 3, b, y, zh, zl, t);
    coopw(zt[0], 6, b, y, zh, zl, t);
    coopw(zt[0], 9, b, y, zh, zl, t);
    const int ksz[4] = {3,5,9,17};
    for(int s=0;s<4;s++){
        int k = ksz[s], p = (k-1)>>1, off = 8-p;
        __syncthreads();                // zt reuse + table safety
        if(t < k){
            float cc = -1.f + 2.f*(float)t/(float)(k-1);
            ct[t]  = cosf(1.5707963267948966f*cc);
            stp[t] = sinf(1.5707963267948966f*cc);
        }
        __syncthreads();
        #pragma unroll 1
        for(int i=0;i<8;i++){
            int ch = cq*8 + i;
            const float* oc = ob + (size_t)ch*4096;
            // vertical pass: main positions only (halo is zero-pad)
            float ac=0.f, as=0.f;
            for(int tt=0;tt<k;tt++){
                int yy = y+tt-p;
                if(yy>=0 && yy<64){ float f = oc[yy*64 + x]; ac += ct[tt]*f; as += stp[tt]*f; }
            }
            va[cq][x+8] = ac; vb[cq][x+8] = as;
            __builtin_amdgcn_wave_barrier();   // order wave-internal LDS RAW
            float gx=0.f, gy=0.f;
            for(int tt=0;tt<k;tt++){
                gx += stp[tt]*va[cq][x+tt+off];
                gy += ct[tt]*vb[cq][x+tt+off];
            }
            __builtin_amdgcn_wave_barrier();   // next i overwrites va/vb
            float2 sx = sst[ch*9 + 1+2*s], sy = sst[ch*9 + 2+2*s];
            float zx = (gx - sx.x)*sx.y, zy = (gy - sy.x)*sy.y;
            unsigned short hx = bfrne(zx), hy = bfrne(zy);
            zt[0][0][x][ch] = hx; zt[0][1][x][ch] = bfrne(zx - bf2f(hx));
            zt[1][0][x][ch] = hy; zt[1][1][x][ch] = bfrne(zy - bf2f(hy));
        }
        __syncthreads();
        coopw(zt[0], 3*s+1, b, y, zh, zl, t);
        coopw(zt[1], 3*s+2, b, y, zh, zl, t);
    }
}

// ---------------- dyna grouped convs (split precision) + sigmoid gate ---------
// In-place: reads z (hi/lo), writes zz (hi/lo) to the same buffers (own px only).
__global__ __launch_bounds__(256) void k_dyna(
    const unsigned short* __restrict__ KShi, const unsigned short* __restrict__ KSlo,
    const float* __restrict__ KSb32,
    unsigned short* __restrict__ zh, unsigned short* __restrict__ zl, int cCall)
{
    __shared__ __align__(16) unsigned short lh[4][2][2][16][104];  // [wv][buf][hi/lo][px][och]
    int t=threadIdx.x, wv=t>>6, lane=t&63, l15=lane&15, lg=lane>>4, lkb=lg*8;
    int b=blockIdx.z, g=blockIdx.y, px0=blockIdx.x*64 + wv*16;
    int row = cCall*8 + b;
    const unsigned short* Khi = KShi + (size_t)row*DKT + g*9216;
    const unsigned short* Klo = KSlo + (size_t)row*DKT + g*9216;
    const float* Bf = KSb32 + (size_t)row*1152 + g*96;
    // part-major z base for this wave's px and group g's first part
    size_t zb0 = ((size_t)(b*12 + g*3)*4096 + px0 + l15)*32;

    f32x4 acc[6];
    // ---- layer 1: k_in @ z ----
    #pragma unroll
    for(int mt=0;mt<6;mt++) acc[mt]=f32x4{0,0,0,0};
    #pragma unroll
    for(int kt=0;kt<3;kt++){
        s16x8 bh = *(const s16x8*)(zh + zb0 + (size_t)kt*ZPART + lkb);
        s16x8 bl = *(const s16x8*)(zl + zb0 + (size_t)kt*ZPART + lkb);
        #pragma unroll
        for(int mt=0;mt<6;mt++){
            s16x8 ah = *(const s16x8*)(Khi + (mt*16+l15)*96 + kt*32 + lkb);
            s16x8 al = *(const s16x8*)(Klo + (mt*16+l15)*96 + kt*32 + lkb);
            acc[mt] = mfma16(ah, bh, acc[mt]);
            acc[mt] = mfma16(ah, bl, acc[mt]);
            acc[mt] = mfma16(al, bh, acc[mt]);
        }
    }
    #pragma unroll
    for(int mt=0;mt<6;mt++){
        int o0 = mt*16 + lg*4;
        f32x4 bb = *(const f32x4*)(Bf + o0);
        U4 hh, hl;
        #pragma unroll
        for(int q=0;q<4;q++){
            float v = lrelu(acc[mt][q] + bb[q]);
            hh.h[q] = bfrne(v); hl.h[q] = bfrne(v - bf2f(hh.h[q]));
        }
        *(s16x4*)(&lh[wv][0][0][l15][o0]) = hh.v;
        *(s16x4*)(&lh[wv][0][1][l15][o0]) = hl.v;
    }
    // ---- layer 2: k_mid @ h1 ----
    #pragma unroll
    for(int mt=0;mt<6;mt++) acc[mt]=f32x4{0,0,0,0};
    #pragma unroll
    for(int kt=0;kt<3;kt++){
        s16x8 bh = *(const s16x8*)(&lh[wv][0][0][l15][kt*32+lkb]);
        s16x8 bl = *(const s16x8*)(&lh[wv][0][1][l15][kt*32+lkb]);
        #pragma unroll
        for(int mt=0;mt<6;mt++){
            s16x8 ah = *(const s16x8*)(Khi + 36864 + (mt*16+l15)*96 + kt*32 + lkb);
            s16x8 al = *(const s16x8*)(Klo + 36864 + (mt*16+l15)*96 + kt*32 + lkb);
            acc[mt] = mfma16(ah, bh, acc[mt]);
            acc[mt] = mfma16(ah, bl, acc[mt]);
            acc[mt] = mfma16(al, bh, acc[mt]);
        }
    }
    #pragma unroll
    for(int mt=0;mt<6;mt++){
        int o0 = mt*16 + lg*4;
        f32x4 bb = *(const f32x4*)(Bf + 384 + o0);
        U4 hh, hl;
        #pragma unroll
        for(int q=0;q<4;q++){
            float v = lrelu(acc[mt][q] + bb[q]);
            hh.h[q] = bfrne(v); hl.h[q] = bfrne(v - bf2f(hh.h[q]));
        }
        *(s16x4*)(&lh[wv][1][0][l15][o0]) = hh.v;
        *(s16x4*)(&lh[wv][1][1][l15][o0]) = hl.v;
    }
    // ---- layer 3: k_out @ h2, then gate ----
    #pragma unroll
    for(int mt=0;mt<6;mt++) acc[mt]=f32x4{0,0,0,0};
    #pragma unroll
    for(int kt=0;kt<3;kt++){
        s16x8 bh = *(const s16x8*)(&lh[wv][1][0][l15][kt*32+lkb]);
        s16x8 bl = *(const s16x8*)(&lh[wv][1][1][l15][kt*32+lkb]);
        #pragma unroll
        for(int mt=0;mt<6;mt++){
            s16x8 ah = *(const s16x8*)(Khi + 73728 + (mt*16+l15)*96 + kt*32 + lkb);
            s16x8 al = *(const s16x8*)(Klo + 73728 + (mt*16+l15)*96 + kt*32 + lkb);
            acc[mt] = mfma16(ah, bh, acc[mt]);
            acc[mt] = mfma16(ah, bl, acc[mt]);
            acc[mt] = mfma16(al, bh, acc[mt]);
        }
    }
    #pragma unroll
    for(int mt=0;mt<6;mt++){
        int o0 = mt*16 + lg*4;
        f32x4 bb = *(const f32x4*)(Bf + 768 + o0);
        size_t zo = zb0 + (size_t)(o0>>5)*ZPART + (o0&31);
        U4 zvh, zvl;
        zvh.v = *(const s16x4*)(zh + zo);
        zvl.v = *(const s16x4*)(zl + zo);
        U4 ozh, ozl;
        #pragma unroll
        for(int q=0;q<4;q++){
            float zf = bf2f(zvh.h[q]) + bf2f(zvl.h[q]);
            float d  = zf + acc[mt][q] + bb[q];
            float sg = 1.f/(1.f + __expf(-d));
            float zz = zf*sg;
            ozh.h[q] = bfrne(zz); ozl.h[q] = bfrne(zz - bf2f(ozh.h[q]));
        }
        *(s16x4*)(zh + zo) = ozh.v;
        *(s16x4*)(zl + zo) = ozl.v;
    }
}

// ---------------- res_block + out update --------------------------------------
__global__ __launch_bounds__(256) void k_resb(const unsigned short* __restrict__ zzh,
    const unsigned short* __restrict__ zzl,
    const unsigned short* __restrict__ w016, const unsigned short* __restrict__ w116,
    const unsigned short* __restrict__ wcsh, const unsigned short* __restrict__ wcsl,
    const float* __restrict__ c0b, const float* __restrict__ c1b, const float* __restrict__ csb,
    const float* __restrict__ outPrev, float* __restrict__ outNext)
{
    __shared__ __align__(16) unsigned short ldx[4][16][392];
    int t=threadIdx.x, wv=t>>6, lane=t&63, l15=lane&15, lg=lane>>4, lkb=lg*8;
    int b=blockIdx.y; int px0=blockIdx.x*64 + wv*16;
    size_t zb0 = ((size_t)(b*12)*4096 + px0 + l15)*32;

    // G1: dx1[384][16] = c0w @ leaky(zz_full)
    f32x4 a1[24];
    #pragma unroll
    for(int mt=0;mt<24;mt++) a1[mt]=f32x4{0,0,0,0};
    #pragma unroll 1
    for(int kt=0;kt<12;kt++){
        FragU bzh, bzl, blz;
        bzh.v = *(const s16x8*)(zzh + zb0 + (size_t)kt*ZPART + lkb);
        bzl.v = *(const s16x8*)(zzl + zb0 + (size_t)kt*ZPART + lkb);
        #pragma unroll
        for(int j=0;j<8;j++) blz.h[j] = bfrne(lrelu(bf2f(bzh.h[j]) + bf2f(bzl.h[j])));
        #pragma unroll
        for(int mt=0;mt<24;mt++){
            s16x8 af = *(const s16x8*)(w016 + (size_t)(mt*16+l15)*384 + kt*32 + lkb);
            a1[mt] = mfma16(af, blz.v, a1[mt]);
        }
    }
    #pragma unroll
    for(int mt=0;mt<24;mt++){
        int o0 = mt*16 + lg*4;
        f32x4 bb = *(const f32x4*)(c0b + o0);
        U4 hv;
        #pragma unroll
        for(int q=0;q<4;q++) hv.h[q] = bfrne(lrelu(a1[mt][q] + bb[q]));
        *(s16x4*)(&ldx[wv][l15][o0]) = hv.v;
    }
    // G2: dx2 = c1w @ leaky(dx1) ; G3: r0 = csw @ zz (split)
    f32x4 a2[2] = {f32x4{0,0,0,0}, f32x4{0,0,0,0}};
    f32x4 a3[2] = {f32x4{0,0,0,0}, f32x4{0,0,0,0}};
    #pragma unroll 1
    for(int kt=0;kt<12;kt++){
        s16x8 bh_ = *(const s16x8*)(&ldx[wv][l15][kt*32+lkb]);
        s16x8 bzh = *(const s16x8*)(zzh + zb0 + (size_t)kt*ZPART + lkb);
        s16x8 bzl = *(const s16x8*)(zzl + zb0 + (size_t)kt*ZPART + lkb);
        #pragma unroll
        for(int mt=0;mt<2;mt++){
            s16x8 af1 = *(const s16x8*)(w116 + (size_t)(mt*16+l15)*384 + kt*32 + lkb);
            a2[mt] = mfma16(af1, bh_, a2[mt]);
            s16x8 wh = *(const s16x8*)(wcsh + (size_t)(mt*16+l15)*384 + kt*32 + lkb);
            s16x8 wl = *(const s16x8*)(wcsl + (size_t)(mt*16+l15)*384 + kt*32 + lkb);
            a3[mt] = mfma16(wh, bzh, a3[mt]);
            a3[mt] = mfma16(wh, bzl, a3[mt]);
            a3[mt] = mfma16(wl, bzh, a3[mt]);
        }
    }
    #pragma unroll
    for(int mt=0;mt<2;mt++){
        int o0 = mt*16 + lg*4;
        #pragma unroll
        for(int q=0;q<4;q++){
            int o = o0+q, px = px0 + l15;
            float dx2 = a2[mt][q] + c1b[o];
            float r   = a3[mt][q] + csb[o] + 0.1f*dx2;
            size_t oidx = (size_t)b*131072 + (size_t)o*4096 + px;
            outNext[oidx] = outPrev[oidx] + 0.1f*r;
        }
    }
}

// ---------------- head ---------------------------------------------------------
__global__ __launch_bounds__(256) void k_head1(const float* __restrict__ outF,
    const float* __restrict__ wout, const float* __restrict__ bout, float* __restrict__ state)
{
    __shared__ float sw[97*32];
    __shared__ float sb_[97];
    __shared__ float fp[32];
    __shared__ float fwp[2048];
    int t = threadIdx.x, b = blockIdx.y, pxb = blockIdx.x*256;
    for(int i=t;i<97*32;i+=256) sw[i] = wout[i];
    if(t<97) sb_[t] = bout[t];
    if(t<32) fp[t] = 0.f;
    for(int i=t;i<2048;i+=256) fwp[i] = 0.f;
    __syncthreads();
    int px = pxb + t, lane = t&63, wv = t>>6;
    float xi[32];
    #pragma unroll
    for(int i=0;i<32;i++) xi[i] = outF[(size_t)b*131072 + (size_t)i*4096 + px];
    float* st = state + (size_t)b*8224;
    int row = (pxb>>6) + wv, x = lane;
    for(int o=0;o<97;o++){
        float acc = sb_[o];
        #pragma unroll
        for(int i=0;i<32;i++) acc += sw[o*32+i]*xi[i];
        if(o < 32){
            float s = wave_sum(acc);
            if(lane==0) atomicAdd(&fp[o], s);
        } else if(o < 64){
            float s = wave_sum(acc);
            if(lane==0) st[32 + (o-32)*64 + row] = s*(1.f/64.f);
        } else if(o < 96){
            atomicAdd(&fwp[(o-64)*64 + x], acc);
        } else {
            st[4128 + px] = acc;
        }
    }
    __syncthreads();
    if(t<32) atomicAdd(&st[t], fp[t]*(1.f/4096.f));
    for(int i=t;i<2048;i+=256) atomicAdd(&st[2080+i], fwp[i]*(1.f/64.f));
}

__global__ __launch_bounds__(256) void k_head2(const float* __restrict__ state,
    const float* __restrict__ otlw, float* __restrict__ latout)
{
    __shared__ float ss[8*514];
    int t = threadIdx.x, j = blockIdx.x*256 + t, s0 = blockIdx.y*514;
    for(int i=t;i<8*514;i+=256){ int bb=i/514, si=i-bb*514; ss[i] = state[(size_t)bb*8224 + s0 + si]; }
    __syncthreads();
    float acc[8] = {0,0,0,0,0,0,0,0};
    for(int si=0;si<514;si++){
        float wv_ = otlw[(size_t)(s0+si)*512 + j];
        #pragma unroll
        for(int b2=0;b2<8;b2++) acc[b2] += ss[b2*514+si]*wv_;
    }
    #pragma unroll
    for(int b2=0;b2<8;b2++) atomicAdd(latout + b2*512 + j, acc[b2]);
}

// =============================================================================
extern "C" void kernel_launch(void* const* d_in, const int* in_sizes, int n_in,
                              void* d_out, int out_size, void* d_ws, size_t ws_size,
                              hipStream_t stream)
{
    const float* x    = (const float*)d_in[0];
    const float* inj  = (const float*)d_in[1];
    const float* icw  = (const float*)d_in[2];
    const float* icb  = (const float*)d_in[3];
    const float* flWs = (const float*)d_in[4];
    const float* flbs = (const float*)d_in[5];
    const float* flW0 = (const float*)d_in[6];
    const float* flb0 = (const float*)d_in[7];
    const float* flW1 = (const float*)d_in[8];
    const float* flb1 = (const float*)d_in[9];
    const float* dkWs = (const float*)d_in[10];
    const float* dkbs = (const float*)d_in[11];
    const float* dkW0 = (const float*)d_in[12];
    const float* dkb0 = (const float*)d_in[13];
    const float* dkW1 = (const float*)d_in[14];
    const float* dkb1 = (const float*)d_in[15];
    const float* c0w  = (const float*)d_in[16];
    const float* c0b  = (const float*)d_in[17];
    const float* c1w  = (const float*)d_in[18];
    const float* c1b  = (const float*)d_in[19];
    const float* csw  = (const float*)d_in[20];
    const float* csb  = (const float*)d_in[21];
    const float* ocw  = (const float*)d_in[22];
    const float* ocb  = (const float*)d_in[23];
    const float* otlw = (const float*)d_in[24];
    const float* otlb = (const float*)d_in[25];
    float* out = (float*)d_out;

    // ---- carve workspace ----
    char* wp = (char*)d_ws;
    auto carve = [&](size_t bytes)->void*{ void* p = wp; wp += (bytes + 255) & ~(size_t)255; return p; };
    float* lats  = (float*)carve(36864*4);
    float* sbuf  = (float*)carve(32768*4);
    float* hbuf  = (float*)carve(32768*4);
    float* Hpre  = (float*)carve(65536*4);
    float* state = (float*)carve(65792*4);
    float2* stats = (float2*)carve(2304*8);
    unsigned short* Ahi   = (unsigned short*)carve((size_t)98304*2);
    unsigned short* Alo   = (unsigned short*)carve((size_t)98304*2);
    unsigned short* KShi  = (unsigned short*)carve((size_t)7151616*2);
    unsigned short* KSlo  = (unsigned short*)carve((size_t)7151616*2);
    float*          KSb32 = (float*)carve((size_t)73728*4);          // [64][1152]
    unsigned short* w016  = (unsigned short*)carve((size_t)147456*2);
    unsigned short* w116  = (unsigned short*)carve((size_t)12288*2);
    unsigned short* wcsh  = (unsigned short*)carve((size_t)12288*2);
    unsigned short* wcsl  = (unsigned short*)carve((size_t)12288*2);
    unsigned short* zh    = (unsigned short*)carve((size_t)12582912*2);  // z then zz (hi)
    unsigned short* zl    = (unsigned short*)carve((size_t)12582912*2);  // z then zz (lo)

    k_init<<<1521,256,0,stream>>>(state, out, otlb, lats, inj,
                                  sbuf, flbs, hbuf, flb0,
                                  Hpre, dkb0, w016, c0w, w116, c1w, wcsh, wcsl, csw);
    k_out0<<<4096,256,0,stream>>>(x, icw, icb, out + 4096);

    // latent chain (image-independent)
    for(int c=0;c<8;c++){
        const float* latc = lats + c*4096;
        k_latA<<<dim3(4,4,2),256,0,stream>>>(latc, flWs + (size_t)c*262144, flW0 + (size_t)c*262144,
                                             sbuf + c*4096, hbuf + c*4096);
        k_latBC<<<4,256,0,stream>>>(hbuf + c*4096, flW1 + (size_t)c*262144, flb1 + (size_t)c*512,
                                    latc, sbuf + c*4096, lats + (c+1)*4096);
    }

    // batched dynamic-weight generation (reads dk_Ws/dk_W1 exactly once)
    k_dkH<<<dim3(8,4),256,0,stream>>>(lats + 4096, dkW0, Hpre);
    k_dkAcvt<<<384,256,0,stream>>>(lats + 4096, Hpre, Ahi, Alo);
    k_dkMain<<<1746,256,0,stream>>>(Ahi, Alo, dkWs, dkW1, dkbs, dkb1, KShi, KSlo, KSb32);

    // image path
    for(int c=0;c<8;c++){
        const float* outPrev = out + 4096 + (size_t)c*EMB;
        float*       outNext = out + 4096 + (size_t)(c+1)*EMB;
        k_stat<<<dim3(32,8),256,0,stream>>>(outPrev, stats);
        k_znorm<<<dim3(64,8),256,0,stream>>>(outPrev, stats, zh, zl);
        k_dyna<<<dim3(64,4,8),256,0,stream>>>(KShi, KSlo, KSb32, zh, zl, c);
        k_resb<<<dim3(64,8),256,0,stream>>>(zh, zl, w016, w116, wcsh, wcsl,
                                            c0b, c1b, csb, outPrev, outNext);
    }

    // head
    k_head1<<<dim3(16,8),256,0,stream>>>(out + 4096 + (size_t)8*EMB, ocw, ocb, state);
    k_head2<<<dim3(2,16),256,0,stream>>>(state, otlw, out);
}

// Round 5
// 3806.012 us; speedup vs baseline: 1.0718x; 1.0523x over previous
//
#include <hip/hip_runtime.h>

#define DEV __device__ __forceinline__

typedef __attribute__((ext_vector_type(4))) float  f32x4;
typedef __attribute__((ext_vector_type(8))) short  s16x8;   // 8 bf16 (MFMA frag)
typedef __attribute__((ext_vector_type(4))) short  s16x4;   // 4 bf16 (8B ld/st)
typedef __attribute__((ext_vector_type(4))) unsigned short u16x4;

union FragU { s16x8 v; unsigned short h[8]; };
union U4    { s16x4 v; unsigned short h[4]; };

DEV float lrelu(float x){ return x > 0.f ? x : 0.2f*x; }
DEV unsigned short bfrne(float f){
    unsigned u = __builtin_bit_cast(unsigned, f);
    u += 0x7fffu + ((u>>16)&1u);
    return (unsigned short)(u>>16);
}
DEV float bf2f(unsigned short h){
    unsigned u = ((unsigned)h)<<16; return __builtin_bit_cast(float,u);
}
DEV f32x4 mfma16(s16x8 a, s16x8 b, f32x4 c){
    return __builtin_amdgcn_mfma_f32_16x16x32_bf16(a, b, c, 0, 0, 0);
}
DEV float wave_sum(float v){
    #pragma unroll
    for(int m=32;m>0;m>>=1) v += __shfl_xor(v, m, 64);
    return v;
}
DEV void blk_reduce2(float& a, float& b, float* sm){
    a = wave_sum(a); b = wave_sum(b);
    int wv = threadIdx.x>>6, ln = threadIdx.x&63;
    if(ln==0){ sm[wv*2]=a; sm[wv*2+1]=b; }
    __syncthreads();
    a = sm[0]+sm[2]+sm[4]+sm[6];
    b = sm[1]+sm[3]+sm[5]+sm[7];
    __syncthreads();
}

// ---------------- sizes ----------------
// B=8 CIN=3 IMG=64 HW=4096 NF=32 NCALLS=8 LAT=512 F=384 GRP=4 CG=96
// DK_TOT=111744 S=36864 DK_HID=1024 OUT_CH=97 STATE=8224
#define EMB   1048576               // 8*32*4096, one out_emb
#define DKT   111744
// z layout: [b][part 0..11][px 0..4095][ch 0..31], part = 3*scale + {id,gx,gy}
#define ZPART 131072                // 4096*32

// ---------------- init ----------------
__global__ __launch_bounds__(256) void k_init(
    float* state, float* latout, const float* otlb,
    float* lats, const float* inj,
    unsigned short* w016, const float* c0w,
    unsigned short* w116, const float* c1w,
    unsigned short* wcsh, unsigned short* wcsl, const float* csw)
{
    int i = blockIdx.x*256 + threadIdx.x;
    if(i < 65792){ state[i] = 0.f; return; }            i -= 65792;
    if(i < 4096){ latout[i] = otlb[i&511]; return; }    i -= 4096;
    if(i < 4096){ lats[i] = inj[i]; return; }           i -= 4096;
    if(i < 147456){ w016[i] = bfrne(c0w[i]); return; }  i -= 147456;
    if(i < 12288){ w116[i] = bfrne(c1w[i]); return; }   i -= 12288;
    if(i < 12288){ wcsh[i] = bfrne(csw[i]); return; }   i -= 12288;
    if(i < 12288){ unsigned short hh = bfrne(csw[i]); wcsl[i] = bfrne(csw[i] - bf2f(hh)); return; }
}

// ---------------- out_embs[0] = in_conv(x) ----------------
__global__ __launch_bounds__(256) void k_out0(const float* __restrict__ x,
    const float* __restrict__ w, const float* __restrict__ b, float* __restrict__ out0)
{
    int i = blockIdx.x*256 + threadIdx.x;       // < 1048576
    int p = i & 4095, o = (i>>12)&31, bb = i>>17;
    const float* xb = x + (size_t)bb*12288 + p;
    out0[i] = b[o] + w[o*3]*xb[0] + w[o*3+1]*xb[4096] + w[o*3+2]*xb[8192];
}

// ---------------- latent chain (f32, DETERMINISTIC partial sums) --------------
// writes partial p = kb*2 + half of (lat @ W) to pp[(p*8+m)*512 + j]
__global__ __launch_bounds__(256) void k_latA(const float* __restrict__ lat,
    const float* __restrict__ Ws, const float* __restrict__ W0,
    float* __restrict__ ppS, float* __restrict__ ppH)
{
    __shared__ float ls[8][128];
    int t = threadIdx.x;
    int kb = blockIdx.y*128;
    for(int i=t;i<1024;i+=256) ls[i>>7][i&127] = lat[(i>>7)*512 + kb + (i&127)];
    __syncthreads();
    const float* W = blockIdx.z ? W0 : Ws;
    float* pp = blockIdx.z ? ppH : ppS;
    int j = blockIdx.x*128 + (t&127);
    int half = t>>7, klo = half*64;
    int p = blockIdx.y*2 + half;
    float acc[8] = {0,0,0,0,0,0,0,0};
    for(int kk=0;kk<64;kk++){
        float wv_ = W[(size_t)(kb+klo+kk)*512 + j];
        #pragma unroll
        for(int m=0;m<8;m++) acc[m] += ls[m][klo+kk]*wv_;
    }
    #pragma unroll
    for(int m=0;m<8;m++) pp[(size_t)(p*8+m)*512 + j] = acc[m];
}

// fused: combine partials (fixed order) -> hpre,s ; t1 GEMM ; latn update
__global__ __launch_bounds__(256) void k_latBC(const float* __restrict__ ppH,
    const float* __restrict__ flb0c,
    const float* __restrict__ W1, const float* __restrict__ b1c,
    const float* __restrict__ latc, const float* __restrict__ ppS,
    const float* __restrict__ flbsc, float* __restrict__ latn)
{
    __shared__ float lh[8][512];
    __shared__ float part[8][128];
    int t = threadIdx.x;
    for(int i=t;i<4096;i+=256){
        int m = i>>9, jj = i&511;
        float v = flb0c[jj];
        #pragma unroll
        for(int p=0;p<8;p++) v += ppH[(size_t)(p*8+m)*512 + jj];
        lh[m][jj] = lrelu(v);
    }
    __syncthreads();
    int j = blockIdx.x*128 + (t&127), half = t>>7;
    float acc[8] = {0,0,0,0,0,0,0,0};
    int k0 = half*256;
    for(int kk=k0;kk<k0+256;kk++){
        float w = W1[(size_t)kk*512 + j];
        #pragma unroll
        for(int m=0;m<8;m++) acc[m] += lh[m][kk]*w;
    }
    if(half==1){
        #pragma unroll
        for(int m=0;m<8;m++) part[m][t&127] = acc[m];
    }
    __syncthreads();
    if(half==0){
        #pragma unroll
        for(int m=0;m<8;m++){
            float sv = flbsc[j];
            #pragma unroll
            for(int p=0;p<8;p++) sv += ppS[(size_t)(p*8+m)*512 + j];
            float t1 = acc[m] + part[m][t&127] + b1c[j];
            latn[m*512+j] = latc[m*512+j] + 0.1f*sv + 0.01f*t1;
        }
    }
}

// ---------------- DK hidden partials: ppD[p][64][1024] (DETERMINISTIC) --------
__global__ __launch_bounds__(256) void k_dkH(const float* __restrict__ latsAll,
    const float* __restrict__ W0, float* __restrict__ ppD)
{
    __shared__ float ls[64][128];
    int t = threadIdx.x;
    int kb = blockIdx.y*128;
    for(int i=t;i<8192;i+=256) ls[i>>7][i&127] = latsAll[(i>>7)*512 + kb + (i&127)];
    __syncthreads();
    int j = blockIdx.x*128 + (t&127);
    int ksub = t>>7;
    int p = blockIdx.y*2 + ksub;
    for(int mc=0;mc<4;mc++){
        float acc[16] = {0,0,0,0,0,0,0,0,0,0,0,0,0,0,0,0};
        for(int kk=0;kk<64;kk++){
            float wv_ = W0[(size_t)(kb + ksub*64 + kk)*1024 + j];
            #pragma unroll
            for(int mi=0;mi<16;mi++) acc[mi] += ls[mc*16+mi][ksub*64+kk]*wv_;
        }
        #pragma unroll
        for(int mi=0;mi<16;mi++) ppD[(size_t)(p*64 + mc*16+mi)*1024 + j] = acc[mi];
    }
}

// A = [lats | 0.1*leaky(dkb0 + sum_p ppD)] split hi/lo (fixed combine order)
__global__ __launch_bounds__(256) void k_dkAcvt(const float* __restrict__ latsAll,
    const float* __restrict__ ppD, const float* __restrict__ dkb0,
    unsigned short* __restrict__ Ahi, unsigned short* __restrict__ Alo)
{
    int i = blockIdx.x*256 + threadIdx.x;   // < 98304
    int m = i/1536, k = i - m*1536;
    float v;
    if(k < 512) v = latsAll[m*512 + k];
    else {
        int j = k - 512;
        float hv = dkb0[j];
        #pragma unroll
        for(int p=0;p<8;p++) hv += ppD[(size_t)(p*64+m)*1024 + j];
        v = 0.1f*lrelu(hv);
    }
    unsigned short hh = bfrne(v);
    Ahi[i] = hh; Alo[i] = bfrne(v - bf2f(hh));
}

// ---------------- KS[64,111744] = A @ [dkWs ; dkW1] + bias (split precision) --
// LDS-staged streaming GEMM: coalesced dwordx4 W reads, reg-staged prefetch.
__global__ __launch_bounds__(256) void k_dkMain(const unsigned short* __restrict__ Ahi,
    const unsigned short* __restrict__ Alo,
    const float* __restrict__ Wsb, const float* __restrict__ W1b,
    const float* __restrict__ bs, const float* __restrict__ b1,
    unsigned short* __restrict__ KShi, unsigned short* __restrict__ KSlo,
    float* __restrict__ KSb32)
{
    __shared__ unsigned short Wh[64][138];   // pad 138: B-col reads conflict-free
    __shared__ unsigned short Wl[64][138];
    __shared__ unsigned short Ah[64][72];
    __shared__ unsigned short Al[64][72];
    int t = threadIdx.x, wv = t>>6, lane = t&63, l15 = lane&15, lg = lane>>4, lkb = lg*8;
    int n0 = blockIdx.x*128;
    int sk = t>>5, sc = (t&31)*4;      // W staging: rows sk+8s, 4 cols at sc
    int am = t>>2, ac = (t&3)*16;      // A staging: row am, 16 cols at ac

    f32x4 wreg[8];
    s16x8 ah0, ah1, al0, al1;

    // prologue: load tile 0 into regs (coalesced dwordx4)
    {
        #pragma unroll
        for(int s=0;s<8;s++)
            wreg[s] = *(const f32x4*)(Wsb + (size_t)(sk + s*8)*DKT + n0 + sc);
        const unsigned short* Abh = Ahi + am*1536 + ac;
        const unsigned short* Abl = Alo + am*1536 + ac;
        ah0 = *(const s16x8*)(Abh);     ah1 = *(const s16x8*)(Abh + 8);
        al0 = *(const s16x8*)(Abl);     al1 = *(const s16x8*)(Abl + 8);
    }

    f32x4 acc[4][2];
    #pragma unroll
    for(int mt=0;mt<4;mt++){ acc[mt][0]=f32x4{0,0,0,0}; acc[mt][1]=f32x4{0,0,0,0}; }

    for(int kt=0;kt<24;kt++){
        // write staged regs to LDS (hi/lo split happens here)
        #pragma unroll
        for(int s=0;s<8;s++){
            int k = sk + s*8;
            unsigned short hh[4], ll[4];
            #pragma unroll
            for(int e=0;e<4;e++){
                float w = wreg[s][e];
                hh[e] = bfrne(w); ll[e] = bfrne(w - bf2f(hh[e]));
            }
            *(unsigned*)(&Wh[k][sc])   = (unsigned)hh[0] | ((unsigned)hh[1]<<16);
            *(unsigned*)(&Wh[k][sc+2]) = (unsigned)hh[2] | ((unsigned)hh[3]<<16);
            *(unsigned*)(&Wl[k][sc])   = (unsigned)ll[0] | ((unsigned)ll[1]<<16);
            *(unsigned*)(&Wl[k][sc+2]) = (unsigned)ll[2] | ((unsigned)ll[3]<<16);
        }
        *(s16x8*)(&Ah[am][ac]) = ah0;  *(s16x8*)(&Ah[am][ac+8]) = ah1;
        *(s16x8*)(&Al[am][ac]) = al0;  *(s16x8*)(&Al[am][ac+8]) = al1;
        __syncthreads();
        // prefetch next tile into regs; lands under the MFMA phase
        if(kt < 23){
            int kn = kt+1;
            const float* Wb = (kn<8) ? (Wsb + (size_t)(kn*64)*DKT)
                                     : (W1b + (size_t)(kn*64-512)*DKT);
            #pragma unroll
            for(int s=0;s<8;s++)
                wreg[s] = *(const f32x4*)(Wb + (size_t)(sk + s*8)*DKT + n0 + sc);
            const unsigned short* Abh = Ahi + am*1536 + kn*64 + ac;
            const unsigned short* Abl = Alo + am*1536 + kn*64 + ac;
            ah0 = *(const s16x8*)(Abh);     ah1 = *(const s16x8*)(Abh + 8);
            al0 = *(const s16x8*)(Abl);     al1 = *(const s16x8*)(Abl + 8);
        }
        // MFMA phase: wave wv owns cols [wv*32, wv*32+32)
        #pragma unroll
        for(int ks=0;ks<2;ks++){
            s16x8 afh[4], afl[4];
            #pragma unroll
            for(int mt=0;mt<4;mt++){
                afh[mt] = *(const s16x8*)(&Ah[mt*16+l15][ks*32+lkb]);
                afl[mt] = *(const s16x8*)(&Al[mt*16+l15][ks*32+lkb]);
            }
            #pragma unroll
            for(int nt=0;nt<2;nt++){
                int col = wv*32 + nt*16 + l15;
                FragU bh, bl;
                #pragma unroll
                for(int j=0;j<8;j++){
                    bh.h[j] = Wh[ks*32+lkb+j][col];
                    bl.h[j] = Wl[ks*32+lkb+j][col];
                }
                #pragma unroll
                for(int mt=0;mt<4;mt++){
                    acc[mt][nt] = mfma16(afh[mt], bh.v, acc[mt][nt]);
                    acc[mt][nt] = mfma16(afh[mt], bl.v, acc[mt][nt]);
                    acc[mt][nt] = mfma16(afl[mt], bh.v, acc[mt][nt]);
                }
            }
        }
        __syncthreads();
    }
    // epilogue
    #pragma unroll
    for(int nt=0;nt<2;nt++){
        int n = n0 + wv*32 + nt*16 + l15;
        float bias = bs[n] + 0.1f*b1[n];
        #pragma unroll
        for(int mt=0;mt<4;mt++)
            #pragma unroll
            for(int q=0;q<4;q++){
                int row = mt*16 + lg*4 + q;
                float v = acc[mt][nt][q] + bias;
                unsigned short hh = bfrne(v);
                KShi[(size_t)row*DKT + n] = hh;
                KSlo[(size_t)row*DKT + n] = bfrne(v - bf2f(hh));
                if(n >= 110592) KSb32[(size_t)row*1152 + (n - 110592)] = v;
            }
    }
}

// ---------------- stats: per (b,ch) mean/rsqrt for id + 4x(gx,gy) -------------
__global__ __launch_bounds__(256) void k_stat(const float* __restrict__ outPrev,
    float2* __restrict__ stats)
{
    __shared__ float img[4096], va[4096], vb[4096];
    __shared__ float ct[17], stp[17];
    __shared__ float red[8];
    int t = threadIdx.x, ch = blockIdx.x, b = blockIdx.y;
    const float* src = outPrev + ((size_t)b*32 + ch)*4096;
    float2* stc = stats + (b*32 + ch)*9;
    for(int i=t;i<4096;i+=256) img[i] = src[i];
    __syncthreads();
    float s0=0.f, s1=0.f;
    for(int i=t;i<4096;i+=256){ float v=img[i]; s0+=v; s1+=v*v; }
    blk_reduce2(s0, s1, red);
    float mu = s0*(1.f/4096.f);
    float var = s1*(1.f/4096.f) - mu*mu; var = var<0.f?0.f:var;
    if(t==0) stc[0] = make_float2(mu, rsqrtf(var + 1e-5f));
    const int ksz[4] = {3,5,9,17};
    for(int s=0;s<4;s++){
        int k = ksz[s], p = (k-1)>>1;
        if(t < k){
            float cc = -1.f + 2.f*(float)t/(float)(k-1);
            ct[t]  = cosf(1.5707963267948966f*cc);
            stp[t] = sinf(1.5707963267948966f*cc);
        }
        __syncthreads();
        for(int i=t;i<4096;i+=256){                     // vertical pass
            int y = i>>6, x = i&63; float ac=0.f, as=0.f;
            for(int tt=0;tt<k;tt++){
                int yy = y+tt-p;
                if(yy>=0 && yy<64){ float f = img[yy*64+x]; ac += ct[tt]*f; as += stp[tt]*f; }
            }
            va[i]=ac; vb[i]=as;
        }
        __syncthreads();
        float gx0=0.f,gx1=0.f,gy0=0.f,gy1=0.f;
        for(int i=t;i<4096;i+=256){
            int y=i>>6, x=i&63; float gx=0.f, gy=0.f;
            for(int tt=0;tt<k;tt++){
                int xx = x+tt-p;
                if(xx>=0 && xx<64){ gx += stp[tt]*va[y*64+xx]; gy += ct[tt]*vb[y*64+xx]; }
            }
            gx0+=gx; gx1+=gx*gx; gy0+=gy; gy1+=gy*gy;
        }
        blk_reduce2(gx0, gx1, red);
        blk_reduce2(gy0, gy1, red);
        float mgx = gx0*(1.f/4096.f), vgx = gx1*(1.f/4096.f)-mgx*mgx; vgx=vgx<0.f?0.f:vgx;
        float mgy = gy0*(1.f/4096.f), vgy = gy1*(1.f/4096.f)-mgy*mgy; vgy=vgy<0.f?0.f:vgy;
        if(t==0){
            stc[1+2*s] = make_float2(mgx, rsqrtf(vgx+1e-5f));
            stc[2+2*s] = make_float2(mgy, rsqrtf(vgy+1e-5f));
        }
        __syncthreads();
    }
}

// coop write of one [64 px][32 ch] hi/lo tile to part-major z
DEV void coopw(const unsigned short (*zt)[64][36], int part, int b, int y,
               unsigned short* zh, unsigned short* zl, int t)
{
    #pragma unroll
    for(int buf=0;buf<2;buf++){
        unsigned short* dst = (buf ? zl : zh) + ((size_t)(b*12+part)*4096 + y*64)*32;
        #pragma unroll
        for(int pos=t; pos<512; pos+=256){
            int px = pos>>3, c4 = pos&7;
            u16x4 v = *(const u16x4*)(&zt[buf][px][c4*4]);
            *(u16x4*)(dst + pos*4) = v;
        }
    }
}

// ---------------- znorm: recompute convs, normalize, coalesced part-major write
__global__ __launch_bounds__(256) void k_znorm(const float* __restrict__ outPrev,
    const float2* __restrict__ stats,
    unsigned short* __restrict__ zh, unsigned short* __restrict__ zl)
{
    __shared__ unsigned short zt[2][2][64][36];  // [partSlot][hi/lo][px][ch]
    __shared__ float va[4][80], vb[4][80];
    __shared__ float ct[17], stp[17];
    __shared__ float2 sst[288];
    int t = threadIdx.x, x = t&63, cq = t>>6;
    int y = blockIdx.x, b = blockIdx.y;
    const float* ob = outPrev + (size_t)b*131072;
    for(int i=t;i<288;i+=256) sst[i] = stats[b*288 + i];
    if(x < 16){
        int xp2 = (x<8) ? x : (x+64);
        va[cq][xp2] = 0.f; vb[cq][xp2] = 0.f;
    }
    __syncthreads();
    // ---- identity part (value shared by all 4 scales) ----
    #pragma unroll
    for(int i=0;i<8;i++){
        int ch = cq*8 + i;
        float v = ob[(size_t)ch*4096 + y*64 + x];
        float2 sr = sst[ch*9];
        float z = (v - sr.x)*sr.y;
        unsigned short hh = bfrne(z);
        zt[0][0][x][ch] = hh; zt[0][1][x][ch] = bfrne(z - bf2f(hh));
    }
    __syncthreads();
    coopw(zt[0], 0, b, y, zh, zl, t);
    coopw(zt[0], 3, b, y, zh, zl, t);
    coopw(zt[0], 6, b, y, zh, zl, t);
    coopw(zt[0], 9, b, y, zh, zl, t);
    const int ksz[4] = {3,5,9,17};
    for(int s=0;s<4;s++){
        int k = ksz[s], p = (k-1)>>1, off = 8-p;
        __syncthreads();
        if(t < k){
            float cc = -1.f + 2.f*(float)t/(float)(k-1);
            ct[t]  = cosf(1.5707963267948966f*cc);
            stp[t] = sinf(1.5707963267948966f*cc);
        }
        __syncthreads();
        #pragma unroll 1
        for(int i=0;i<8;i++){
            int ch = cq*8 + i;
            const float* oc = ob + (size_t)ch*4096;
            float ac=0.f, as=0.f;
            for(int tt=0;tt<k;tt++){
                int yy = y+tt-p;
                if(yy>=0 && yy<64){ float f = oc[yy*64 + x]; ac += ct[tt]*f; as += stp[tt]*f; }
            }
            va[cq][x+8] = ac; vb[cq][x+8] = as;
            __builtin_amdgcn_wave_barrier();
            float gx=0.f, gy=0.f;
            for(int tt=0;tt<k;tt++){
                gx += stp[tt]*va[cq][x+tt+off];
                gy += ct[tt]*vb[cq][x+tt+off];
            }
            __builtin_amdgcn_wave_barrier();
            float2 sx = sst[ch*9 + 1+2*s], sy = sst[ch*9 + 2+2*s];
            float zx = (gx - sx.x)*sx.y, zy = (gy - sy.x)*sy.y;
            unsigned short hx = bfrne(zx), hy = bfrne(zy);
            zt[0][0][x][ch] = hx; zt[0][1][x][ch] = bfrne(zx - bf2f(hx));
            zt[1][0][x][ch] = hy; zt[1][1][x][ch] = bfrne(zy - bf2f(hy));
        }
        __syncthreads();
        coopw(zt[0], 3*s+1, b, y, zh, zl, t);
        coopw(zt[1], 3*s+2, b, y, zh, zl, t);
    }
}

// ---------------- dyna grouped convs (split precision) + sigmoid gate ---------
__global__ __launch_bounds__(256) void k_dyna(
    const unsigned short* __restrict__ KShi, const unsigned short* __restrict__ KSlo,
    const float* __restrict__ KSb32,
    unsigned short* __restrict__ zh, unsigned short* __restrict__ zl, int cCall)
{
    __shared__ __align__(16) unsigned short lh[4][2][2][16][104];  // [wv][buf][hi/lo][px][och]
    int t=threadIdx.x, wv=t>>6, lane=t&63, l15=lane&15, lg=lane>>4, lkb=lg*8;
    int b=blockIdx.z, g=blockIdx.y, px0=blockIdx.x*64 + wv*16;
    int row = cCall*8 + b;
    const unsigned short* Khi = KShi + (size_t)row*DKT + g*9216;
    const unsigned short* Klo = KSlo + (size_t)row*DKT + g*9216;
    const float* Bf = KSb32 + (size_t)row*1152 + g*96;
    size_t zb0 = ((size_t)(b*12 + g*3)*4096 + px0 + l15)*32;

    f32x4 acc[6];
    // ---- layer 1: k_in @ z ----
    #pragma unroll
    for(int mt=0;mt<6;mt++) acc[mt]=f32x4{0,0,0,0};
    #pragma unroll
    for(int kt=0;kt<3;kt++){
        s16x8 bh = *(const s16x8*)(zh + zb0 + (size_t)kt*ZPART + lkb);
        s16x8 bl = *(const s16x8*)(zl + zb0 + (size_t)kt*ZPART + lkb);
        #pragma unroll
        for(int mt=0;mt<6;mt++){
            s16x8 ah = *(const s16x8*)(Khi + (mt*16+l15)*96 + kt*32 + lkb);
            s16x8 al = *(const s16x8*)(Klo + (mt*16+l15)*96 + kt*32 + lkb);
            acc[mt] = mfma16(ah, bh, acc[mt]);
            acc[mt] = mfma16(ah, bl, acc[mt]);
            acc[mt] = mfma16(al, bh, acc[mt]);
        }
    }
    #pragma unroll
    for(int mt=0;mt<6;mt++){
        int o0 = mt*16 + lg*4;
        f32x4 bb = *(const f32x4*)(Bf + o0);
        U4 hh, hl;
        #pragma unroll
        for(int q=0;q<4;q++){
            float v = lrelu(acc[mt][q] + bb[q]);
            hh.h[q] = bfrne(v); hl.h[q] = bfrne(v - bf2f(hh.h[q]));
        }
        *(s16x4*)(&lh[wv][0][0][l15][o0]) = hh.v;
        *(s16x4*)(&lh[wv][0][1][l15][o0]) = hl.v;
    }
    // ---- layer 2: k_mid @ h1 ----
    #pragma unroll
    for(int mt=0;mt<6;mt++) acc[mt]=f32x4{0,0,0,0};
    #pragma unroll
    for(int kt=0;kt<3;kt++){
        s16x8 bh = *(const s16x8*)(&lh[wv][0][0][l15][kt*32+lkb]);
        s16x8 bl = *(const s16x8*)(&lh[wv][0][1][l15][kt*32+lkb]);
        #pragma unroll
        for(int mt=0;mt<6;mt++){
            s16x8 ah = *(const s16x8*)(Khi + 36864 + (mt*16+l15)*96 + kt*32 + lkb);
            s16x8 al = *(const s16x8*)(Klo + 36864 + (mt*16+l15)*96 + kt*32 + lkb);
            acc[mt] = mfma16(ah, bh, acc[mt]);
            acc[mt] = mfma16(ah, bl, acc[mt]);
            acc[mt] = mfma16(al, bh, acc[mt]);
        }
    }
    #pragma unroll
    for(int mt=0;mt<6;mt++){
        int o0 = mt*16 + lg*4;
        f32x4 bb = *(const f32x4*)(Bf + 384 + o0);
        U4 hh, hl;
        #pragma unroll
        for(int q=0;q<4;q++){
            float v = lrelu(acc[mt][q] + bb[q]);
            hh.h[q] = bfrne(v); hl.h[q] = bfrne(v - bf2f(hh.h[q]));
        }
        *(s16x4*)(&lh[wv][1][0][l15][o0]) = hh.v;
        *(s16x4*)(&lh[wv][1][1][l15][o0]) = hl.v;
    }
    // ---- layer 3: k_out @ h2, then gate ----
    #pragma unroll
    for(int mt=0;mt<6;mt++) acc[mt]=f32x4{0,0,0,0};
    #pragma unroll
    for(int kt=0;kt<3;kt++){
        s16x8 bh = *(const s16x8*)(&lh[wv][1][0][l15][kt*32+lkb]);
        s16x8 bl = *(const s16x8*)(&lh[wv][1][1][l15][kt*32+lkb]);
        #pragma unroll
        for(int mt=0;mt<6;mt++){
            s16x8 ah = *(const s16x8*)(Khi + 73728 + (mt*16+l15)*96 + kt*32 + lkb);
            s16x8 al = *(const s16x8*)(Klo + 73728 + (mt*16+l15)*96 + kt*32 + lkb);
            acc[mt] = mfma16(ah, bh, acc[mt]);
            acc[mt] = mfma16(ah, bl, acc[mt]);
            acc[mt] = mfma16(al, bh, acc[mt]);
        }
    }
    #pragma unroll
    for(int mt=0;mt<6;mt++){
        int o0 = mt*16 + lg*4;
        f32x4 bb = *(const f32x4*)(Bf + 768 + o0);
        size_t zo = zb0 + (size_t)(o0>>5)*ZPART + (o0&31);
        U4 zvh, zvl;
        zvh.v = *(const s16x4*)(zh + zo);
        zvl.v = *(const s16x4*)(zl + zo);
        U4 ozh, ozl;
        #pragma unroll
        for(int q=0;q<4;q++){
            float zf = bf2f(zvh.h[q]) + bf2f(zvl.h[q]);
            float d  = zf + acc[mt][q] + bb[q];
            float sg = 1.f/(1.f + __expf(-d));
            float zz = zf*sg;
            ozh.h[q] = bfrne(zz); ozl.h[q] = bfrne(zz - bf2f(ozh.h[q]));
        }
        *(s16x4*)(zh + zo) = ozh.v;
        *(s16x4*)(zl + zo) = ozl.v;
    }
}

// ---------------- res_block + out update --------------------------------------
__global__ __launch_bounds__(256) void k_resb(const unsigned short* __restrict__ zzh,
    const unsigned short* __restrict__ zzl,
    const unsigned short* __restrict__ w016, const unsigned short* __restrict__ w116,
    const unsigned short* __restrict__ wcsh, const unsigned short* __restrict__ wcsl,
    const float* __restrict__ c0b, const float* __restrict__ c1b, const float* __restrict__ csb,
    const float* __restrict__ outPrev, float* __restrict__ outNext)
{
    __shared__ __align__(16) unsigned short ldx[4][16][392];
    int t=threadIdx.x, wv=t>>6, lane=t&63, l15=lane&15, lg=lane>>4, lkb=lg*8;
    int b=blockIdx.y; int px0=blockIdx.x*64 + wv*16;
    size_t zb0 = ((size_t)(b*12)*4096 + px0 + l15)*32;

    // G1: dx1[384][16] = c0w @ leaky(zz_full)
    f32x4 a1[24];
    #pragma unroll
    for(int mt=0;mt<24;mt++) a1[mt]=f32x4{0,0,0,0};
    #pragma unroll 1
    for(int kt=0;kt<12;kt++){
        FragU bzh, bzl, blz;
        bzh.v = *(const s16x8*)(zzh + zb0 + (size_t)kt*ZPART + lkb);
        bzl.v = *(const s16x8*)(zzl + zb0 + (size_t)kt*ZPART + lkb);
        #pragma unroll
        for(int j=0;j<8;j++) blz.h[j] = bfrne(lrelu(bf2f(bzh.h[j]) + bf2f(bzl.h[j])));
        #pragma unroll
        for(int mt=0;mt<24;mt++){
            s16x8 af = *(const s16x8*)(w016 + (size_t)(mt*16+l15)*384 + kt*32 + lkb);
            a1[mt] = mfma16(af, blz.v, a1[mt]);
        }
    }
    #pragma unroll
    for(int mt=0;mt<24;mt++){
        int o0 = mt*16 + lg*4;
        f32x4 bb = *(const f32x4*)(c0b + o0);
        U4 hv;
        #pragma unroll
        for(int q=0;q<4;q++) hv.h[q] = bfrne(lrelu(a1[mt][q] + bb[q]));
        *(s16x4*)(&ldx[wv][l15][o0]) = hv.v;
    }
    // G2: dx2 = c1w @ leaky(dx1) ; G3: r0 = csw @ zz (split)
    f32x4 a2[2] = {f32x4{0,0,0,0}, f32x4{0,0,0,0}};
    f32x4 a3[2] = {f32x4{0,0,0,0}, f32x4{0,0,0,0}};
    #pragma unroll 1
    for(int kt=0;kt<12;kt++){
        s16x8 bh_ = *(const s16x8*)(&ldx[wv][l15][kt*32+lkb]);
        s16x8 bzh = *(const s16x8*)(zzh + zb0 + (size_t)kt*ZPART + lkb);
        s16x8 bzl = *(const s16x8*)(zzl + zb0 + (size_t)kt*ZPART + lkb);
        #pragma unroll
        for(int mt=0;mt<2;mt++){
            s16x8 af1 = *(const s16x8*)(w116 + (size_t)(mt*16+l15)*384 + kt*32 + lkb);
            a2[mt] = mfma16(af1, bh_, a2[mt]);
            s16x8 wh = *(const s16x8*)(wcsh + (size_t)(mt*16+l15)*384 + kt*32 + lkb);
            s16x8 wl = *(const s16x8*)(wcsl + (size_t)(mt*16+l15)*384 + kt*32 + lkb);
            a3[mt] = mfma16(wh, bzh, a3[mt]);
            a3[mt] = mfma16(wh, bzl, a3[mt]);
            a3[mt] = mfma16(wl, bzh, a3[mt]);
        }
    }
    #pragma unroll
    for(int mt=0;mt<2;mt++){
        int o0 = mt*16 + lg*4;
        #pragma unroll
        for(int q=0;q<4;q++){
            int o = o0+q, px = px0 + l15;
            float dx2 = a2[mt][q] + c1b[o];
            float r   = a3[mt][q] + csb[o] + 0.1f*dx2;
            size_t oidx = (size_t)b*131072 + (size_t)o*4096 + px;
            outNext[oidx] = outPrev[oidx] + 0.1f*r;
        }
    }
}

// ---------------- head ---------------------------------------------------------
__global__ __launch_bounds__(256) void k_head1(const float* __restrict__ outF,
    const float* __restrict__ wout, const float* __restrict__ bout, float* __restrict__ state)
{
    __shared__ float sw[97*32];
    __shared__ float sb_[97];
    __shared__ float fp[32];
    __shared__ float fwp[2048];
    int t = threadIdx.x, b = blockIdx.y, pxb = blockIdx.x*256;
    for(int i=t;i<97*32;i+=256) sw[i] = wout[i];
    if(t<97) sb_[t] = bout[t];
    if(t<32) fp[t] = 0.f;
    for(int i=t;i<2048;i+=256) fwp[i] = 0.f;
    __syncthreads();
    int px = pxb + t, lane = t&63, wv = t>>6;
    float xi[32];
    #pragma unroll
    for(int i=0;i<32;i++) xi[i] = outF[(size_t)b*131072 + (size_t)i*4096 + px];
    float* st = state + (size_t)b*8224;
    int row = (pxb>>6) + wv, x = lane;
    for(int o=0;o<97;o++){
        float acc = sb_[o];
        #pragma unroll
        for(int i=0;i<32;i++) acc += sw[o*32+i]*xi[i];
        if(o < 32){
            float s = wave_sum(acc);
            if(lane==0) atomicAdd(&fp[o], s);
        } else if(o < 64){
            float s = wave_sum(acc);
            if(lane==0) st[32 + (o-32)*64 + row] = s*(1.f/64.f);
        } else if(o < 96){
            atomicAdd(&fwp[(o-64)*64 + x], acc);
        } else {
            st[4128 + px] = acc;
        }
    }
    __syncthreads();
    if(t<32) atomicAdd(&st[t], fp[t]*(1.f/4096.f));
    for(int i=t;i<2048;i+=256) atomicAdd(&st[2080+i], fwp[i]*(1.f/64.f));
}

__global__ __launch_bounds__(256) void k_head2(const float* __restrict__ state,
    const float* __restrict__ otlw, float* __restrict__ latout)
{
    __shared__ float ss[8*514];
    int t = threadIdx.x, j = blockIdx.x*256 + t, s0 = blockIdx.y*514;
    for(int i=t;i<8*514;i+=256){ int bb=i/514, si=i-bb*514; ss[i] = state[(size_t)bb*8224 + s0 + si]; }
    __syncthreads();
    float acc[8] = {0,0,0,0,0,0,0,0};
    for(int si=0;si<514;si++){
        float wv_ = otlw[(size_t)(s0+si)*512 + j];
        #pragma unroll
        for(int b2=0;b2<8;b2++) acc[b2] += ss[b2*514+si]*wv_;
    }
    #pragma unroll
    for(int b2=0;b2<8;b2++) atomicAdd(latout + b2*512 + j, acc[b2]);
}

// =============================================================================
extern "C" void kernel_launch(void* const* d_in, const int* in_sizes, int n_in,
                              void* d_out, int out_size, void* d_ws, size_t ws_size,
                              hipStream_t stream)
{
    const float* x    = (const float*)d_in[0];
    const float* inj  = (const float*)d_in[1];
    const float* icw  = (const float*)d_in[2];
    const float* icb  = (const float*)d_in[3];
    const float* flWs = (const float*)d_in[4];
    const float* flbs = (const float*)d_in[5];
    const float* flW0 = (const float*)d_in[6];
    const float* flb0 = (const float*)d_in[7];
    const float* flW1 = (const float*)d_in[8];
    const float* flb1 = (const float*)d_in[9];
    const float* dkWs = (const float*)d_in[10];
    const float* dkbs = (const float*)d_in[11];
    const float* dkW0 = (const float*)d_in[12];
    const float* dkb0 = (const float*)d_in[13];
    const float* dkW1 = (const float*)d_in[14];
    const float* dkb1 = (const float*)d_in[15];
    const float* c0w  = (const float*)d_in[16];
    const float* c0b  = (const float*)d_in[17];
    const float* c1w  = (const float*)d_in[18];
    const float* c1b  = (const float*)d_in[19];
    const float* csw  = (const float*)d_in[20];
    const float* csb  = (const float*)d_in[21];
    const float* ocw  = (const float*)d_in[22];
    const float* ocb  = (const float*)d_in[23];
    const float* otlw = (const float*)d_in[24];
    const float* otlb = (const float*)d_in[25];
    float* out = (float*)d_out;

    // ---- carve workspace ----
    char* wp = (char*)d_ws;
    auto carve = [&](size_t bytes)->void*{ void* p = wp; wp += (bytes + 255) & ~(size_t)255; return p; };
    float* lats  = (float*)carve(36864*4);
    float* ppS   = (float*)carve(32768*4);           // 8 partials x [8][512]
    float* ppH   = (float*)carve(32768*4);
    float* ppD   = (float*)carve(524288*4);          // 8 partials x [64][1024]
    float* state = (float*)carve(65792*4);
    float2* stats = (float2*)carve(2304*8);
    unsigned short* Ahi   = (unsigned short*)carve((size_t)98304*2);
    unsigned short* Alo   = (unsigned short*)carve((size_t)98304*2);
    unsigned short* KShi  = (unsigned short*)carve((size_t)7151616*2);
    unsigned short* KSlo  = (unsigned short*)carve((size_t)7151616*2);
    float*          KSb32 = (float*)carve((size_t)73728*4);          // [64][1152]
    unsigned short* w016  = (unsigned short*)carve((size_t)147456*2);
    unsigned short* w116  = (unsigned short*)carve((size_t)12288*2);
    unsigned short* wcsh  = (unsigned short*)carve((size_t)12288*2);
    unsigned short* wcsl  = (unsigned short*)carve((size_t)12288*2);
    unsigned short* zh    = (unsigned short*)carve((size_t)12582912*2);  // z then zz (hi)
    unsigned short* zl    = (unsigned short*)carve((size_t)12582912*2);  // z then zz (lo)

    k_init<<<1009,256,0,stream>>>(state, out, otlb, lats, inj,
                                  w016, c0w, w116, c1w, wcsh, wcsl, csw);
    k_out0<<<4096,256,0,stream>>>(x, icw, icb, out + 4096);

    // latent chain (image-independent, deterministic fixed-order reductions)
    for(int c=0;c<8;c++){
        const float* latc = lats + c*4096;
        k_latA<<<dim3(4,4,2),256,0,stream>>>(latc, flWs + (size_t)c*262144, flW0 + (size_t)c*262144,
                                             ppS, ppH);
        k_latBC<<<4,256,0,stream>>>(ppH, flb0 + (size_t)c*512,
                                    flW1 + (size_t)c*262144, flb1 + (size_t)c*512,
                                    latc, ppS, flbs + (size_t)c*512, lats + (c+1)*4096);
    }

    // batched dynamic-weight generation (reads dk_Ws/dk_W1 exactly once)
    k_dkH<<<dim3(8,4),256,0,stream>>>(lats + 4096, dkW0, ppD);
    k_dkAcvt<<<384,256,0,stream>>>(lats + 4096, ppD, dkb0, Ahi, Alo);
    k_dkMain<<<873,256,0,stream>>>(Ahi, Alo, dkWs, dkW1, dkbs, dkb1, KShi, KSlo, KSb32);

    // image path
    for(int c=0;c<8;c++){
        const float* outPrev = out + 4096 + (size_t)c*EMB;
        float*       outNext = out + 4096 + (size_t)(c+1)*EMB;
        k_stat<<<dim3(32,8),256,0,stream>>>(outPrev, stats);
        k_znorm<<<dim3(64,8),256,0,stream>>>(outPrev, stats, zh, zl);
        k_dyna<<<dim3(64,4,8),256,0,stream>>>(KShi, KSlo, KSb32, zh, zl, c);
        k_resb<<<dim3(64,8),256,0,stream>>>(zh, zl, w016, w116, wcsh, wcsl,
                                            c0b, c1b, csb, outPrev, outNext);
    }

    // head
    k_head1<<<dim3(16,8),256,0,stream>>>(out + 4096 + (size_t)8*EMB, ocw, ocb, state);
    k_head2<<<dim3(2,16),256,0,stream>>>(state, otlw, out);
}

// Round 6
// 3711.858 us; speedup vs baseline: 1.0990x; 1.0254x over previous
//
#include <hip/hip_runtime.h>

#define DEV __device__ __forceinline__

typedef __attribute__((ext_vector_type(4))) float  f32x4;
typedef __attribute__((ext_vector_type(8))) short  s16x8;   // 8 bf16 (MFMA frag)
typedef __attribute__((ext_vector_type(4))) short  s16x4;   // 4 bf16 (8B ld/st)
typedef __attribute__((ext_vector_type(4))) unsigned short u16x4;

union FragU { s16x8 v; unsigned short h[8]; };
union U4    { s16x4 v; unsigned short h[4]; };

DEV float lrelu(float x){ return x > 0.f ? x : 0.2f*x; }
DEV unsigned short bfrne(float f){
    unsigned u = __builtin_bit_cast(unsigned, f);
    u += 0x7fffu + ((u>>16)&1u);
    return (unsigned short)(u>>16);
}
DEV float bf2f(unsigned short h){
    unsigned u = ((unsigned)h)<<16; return __builtin_bit_cast(float,u);
}
DEV f32x4 mfma16(s16x8 a, s16x8 b, f32x4 c){
    return __builtin_amdgcn_mfma_f32_16x16x32_bf16(a, b, c, 0, 0, 0);
}
DEV float wave_sum(float v){
    #pragma unroll
    for(int m=32;m>0;m>>=1) v += __shfl_xor(v, m, 64);
    return v;
}
DEV void blk_reduce2(float& a, float& b, float* sm){
    a = wave_sum(a); b = wave_sum(b);
    int wv = threadIdx.x>>6, ln = threadIdx.x&63;
    if(ln==0){ sm[wv*2]=a; sm[wv*2+1]=b; }
    __syncthreads();
    a = sm[0]+sm[2]+sm[4]+sm[6];
    b = sm[1]+sm[3]+sm[5]+sm[7];
    __syncthreads();
}

// ---------------- sizes ----------------
#define EMB   1048576               // 8*32*4096, one out_emb
#define DKT   111744
// z layout: [b][part 0..11][px 0..4095][ch 0..31], part = 3*scale + {id,gx,gy}
#define ZPART 131072                // 4096*32

// ---------------- init ----------------
__global__ __launch_bounds__(256) void k_init(
    float* state, float* latout, const float* otlb,
    float* lats, const float* inj,
    unsigned short* w016, const float* c0w,
    unsigned short* w116, const float* c1w,
    unsigned short* wcsh, unsigned short* wcsl, const float* csw)
{
    int i = blockIdx.x*256 + threadIdx.x;
    if(i < 65792){ state[i] = 0.f; return; }            i -= 65792;
    if(i < 4096){ latout[i] = otlb[i&511]; return; }    i -= 4096;
    if(i < 4096){ lats[i] = inj[i]; return; }           i -= 4096;
    if(i < 147456){ w016[i] = bfrne(c0w[i]); return; }  i -= 147456;
    if(i < 12288){ w116[i] = bfrne(c1w[i]); return; }   i -= 12288;
    if(i < 12288){ wcsh[i] = bfrne(csw[i]); return; }   i -= 12288;
    if(i < 12288){ unsigned short hh = bfrne(csw[i]); wcsl[i] = bfrne(csw[i] - bf2f(hh)); return; }
}

// ---------------- out_embs[0] = in_conv(x) ----------------
__global__ __launch_bounds__(256) void k_out0(const float* __restrict__ x,
    const float* __restrict__ w, const float* __restrict__ b, float* __restrict__ out0)
{
    int i = blockIdx.x*256 + threadIdx.x;       // < 1048576
    int p = i & 4095, o = (i>>12)&31, bb = i>>17;
    const float* xb = x + (size_t)bb*12288 + p;
    out0[i] = b[o] + w[o*3]*xb[0] + w[o*3+1]*xb[4096] + w[o*3+2]*xb[8192];
}

// ---------------- latent chain (f32, deterministic partial sums) --------------
__global__ __launch_bounds__(256) void k_latA(const float* __restrict__ lat,
    const float* __restrict__ Ws, const float* __restrict__ W0,
    float* __restrict__ ppS, float* __restrict__ ppH)
{
    __shared__ float ls[8][128];
    int t = threadIdx.x;
    int kb = blockIdx.y*128;
    for(int i=t;i<1024;i+=256) ls[i>>7][i&127] = lat[(i>>7)*512 + kb + (i&127)];
    __syncthreads();
    const float* W = blockIdx.z ? W0 : Ws;
    float* pp = blockIdx.z ? ppH : ppS;
    int j = blockIdx.x*128 + (t&127);
    int half = t>>7, klo = half*64;
    int p = blockIdx.y*2 + half;
    float acc[8] = {0,0,0,0,0,0,0,0};
    for(int kk=0;kk<64;kk++){
        float wv_ = W[(size_t)(kb+klo+kk)*512 + j];
        #pragma unroll
        for(int m=0;m<8;m++) acc[m] += ls[m][klo+kk]*wv_;
    }
    #pragma unroll
    for(int m=0;m<8;m++) pp[(size_t)(p*8+m)*512 + j] = acc[m];
}

__global__ __launch_bounds__(256) void k_latBC(const float* __restrict__ ppH,
    const float* __restrict__ flb0c,
    const float* __restrict__ W1, const float* __restrict__ b1c,
    const float* __restrict__ latc, const float* __restrict__ ppS,
    const float* __restrict__ flbsc, float* __restrict__ latn)
{
    __shared__ float lh[8][512];
    __shared__ float part[8][128];
    int t = threadIdx.x;
    for(int i=t;i<4096;i+=256){
        int m = i>>9, jj = i&511;
        float v = flb0c[jj];
        #pragma unroll
        for(int p=0;p<8;p++) v += ppH[(size_t)(p*8+m)*512 + jj];
        lh[m][jj] = lrelu(v);
    }
    __syncthreads();
    int j = blockIdx.x*128 + (t&127), half = t>>7;
    float acc[8] = {0,0,0,0,0,0,0,0};
    int k0 = half*256;
    for(int kk=k0;kk<k0+256;kk++){
        float w = W1[(size_t)kk*512 + j];
        #pragma unroll
        for(int m=0;m<8;m++) acc[m] += lh[m][kk]*w;
    }
    if(half==1){
        #pragma unroll
        for(int m=0;m<8;m++) part[m][t&127] = acc[m];
    }
    __syncthreads();
    if(half==0){
        #pragma unroll
        for(int m=0;m<8;m++){
            float sv = flbsc[j];
            #pragma unroll
            for(int p=0;p<8;p++) sv += ppS[(size_t)(p*8+m)*512 + j];
            float t1 = acc[m] + part[m][t&127] + b1c[j];
            latn[m*512+j] = latc[m*512+j] + 0.1f*sv + 0.01f*t1;
        }
    }
}

// ---------------- DK hidden partials (deterministic) --------------------------
__global__ __launch_bounds__(256) void k_dkH(const float* __restrict__ latsAll,
    const float* __restrict__ W0, float* __restrict__ ppD)
{
    __shared__ float ls[64][128];
    int t = threadIdx.x;
    int kb = blockIdx.y*128;
    for(int i=t;i<8192;i+=256) ls[i>>7][i&127] = latsAll[(i>>7)*512 + kb + (i&127)];
    __syncthreads();
    int j = blockIdx.x*128 + (t&127);
    int ksub = t>>7;
    int p = blockIdx.y*2 + ksub;
    for(int mc=0;mc<4;mc++){
        float acc[16] = {0,0,0,0,0,0,0,0,0,0,0,0,0,0,0,0};
        for(int kk=0;kk<64;kk++){
            float wv_ = W0[(size_t)(kb + ksub*64 + kk)*1024 + j];
            #pragma unroll
            for(int mi=0;mi<16;mi++) acc[mi] += ls[mc*16+mi][ksub*64+kk]*wv_;
        }
        #pragma unroll
        for(int mi=0;mi<16;mi++) ppD[(size_t)(p*64 + mc*16+mi)*1024 + j] = acc[mi];
    }
}

__global__ __launch_bounds__(256) void k_dkAcvt(const float* __restrict__ latsAll,
    const float* __restrict__ ppD, const float* __restrict__ dkb0,
    unsigned short* __restrict__ Ahi, unsigned short* __restrict__ Alo)
{
    int i = blockIdx.x*256 + threadIdx.x;   // < 98304
    int m = i/1536, k = i - m*1536;
    float v;
    if(k < 512) v = latsAll[m*512 + k];
    else {
        int j = k - 512;
        float hv = dkb0[j];
        #pragma unroll
        for(int p=0;p<8;p++) hv += ppD[(size_t)(p*64+m)*1024 + j];
        v = 0.1f*lrelu(hv);
    }
    unsigned short hh = bfrne(v);
    Ahi[i] = hh; Alo[i] = bfrne(v - bf2f(hh));
}

// ---------------- KS = A @ [dkWs ; dkW1] + bias (LDS-staged GEMM) -------------
__global__ __launch_bounds__(256) void k_dkMain(const unsigned short* __restrict__ Ahi,
    const unsigned short* __restrict__ Alo,
    const float* __restrict__ Wsb, const float* __restrict__ W1b,
    const float* __restrict__ bs, const float* __restrict__ b1,
    unsigned short* __restrict__ KShi, unsigned short* __restrict__ KSlo,
    float* __restrict__ KSb32)
{
    __shared__ unsigned short Wh[64][138];
    __shared__ unsigned short Wl[64][138];
    __shared__ unsigned short Ah[64][72];
    __shared__ unsigned short Al[64][72];
    int t = threadIdx.x, wv = t>>6, lane = t&63, l15 = lane&15, lg = lane>>4, lkb = lg*8;
    int n0 = blockIdx.x*128;
    int sk = t>>5, sc = (t&31)*4;
    int am = t>>2, ac = (t&3)*16;

    f32x4 wreg[8];
    s16x8 ah0, ah1, al0, al1;
    {
        #pragma unroll
        for(int s=0;s<8;s++)
            wreg[s] = *(const f32x4*)(Wsb + (size_t)(sk + s*8)*DKT + n0 + sc);
        const unsigned short* Abh = Ahi + am*1536 + ac;
        const unsigned short* Abl = Alo + am*1536 + ac;
        ah0 = *(const s16x8*)(Abh);     ah1 = *(const s16x8*)(Abh + 8);
        al0 = *(const s16x8*)(Abl);     al1 = *(const s16x8*)(Abl + 8);
    }

    f32x4 acc[4][2];
    #pragma unroll
    for(int mt=0;mt<4;mt++){ acc[mt][0]=f32x4{0,0,0,0}; acc[mt][1]=f32x4{0,0,0,0}; }

    for(int kt=0;kt<24;kt++){
        #pragma unroll
        for(int s=0;s<8;s++){
            int k = sk + s*8;
            unsigned short hh[4], ll[4];
            #pragma unroll
            for(int e=0;e<4;e++){
                float w = wreg[s][e];
                hh[e] = bfrne(w); ll[e] = bfrne(w - bf2f(hh[e]));
            }
            *(unsigned*)(&Wh[k][sc])   = (unsigned)hh[0] | ((unsigned)hh[1]<<16);
            *(unsigned*)(&Wh[k][sc+2]) = (unsigned)hh[2] | ((unsigned)hh[3]<<16);
            *(unsigned*)(&Wl[k][sc])   = (unsigned)ll[0] | ((unsigned)ll[1]<<16);
            *(unsigned*)(&Wl[k][sc+2]) = (unsigned)ll[2] | ((unsigned)ll[3]<<16);
        }
        *(s16x8*)(&Ah[am][ac]) = ah0;  *(s16x8*)(&Ah[am][ac+8]) = ah1;
        *(s16x8*)(&Al[am][ac]) = al0;  *(s16x8*)(&Al[am][ac+8]) = al1;
        __syncthreads();
        if(kt < 23){
            int kn = kt+1;
            const float* Wb = (kn<8) ? (Wsb + (size_t)(kn*64)*DKT)
                                     : (W1b + (size_t)(kn*64-512)*DKT);
            #pragma unroll
            for(int s=0;s<8;s++)
                wreg[s] = *(const f32x4*)(Wb + (size_t)(sk + s*8)*DKT + n0 + sc);
            const unsigned short* Abh = Ahi + am*1536 + kn*64 + ac;
            const unsigned short* Abl = Alo + am*1536 + kn*64 + ac;
            ah0 = *(const s16x8*)(Abh);     ah1 = *(const s16x8*)(Abh + 8);
            al0 = *(const s16x8*)(Abl);     al1 = *(const s16x8*)(Abl + 8);
        }
        #pragma unroll
        for(int ks=0;ks<2;ks++){
            s16x8 afh[4], afl[4];
            #pragma unroll
            for(int mt=0;mt<4;mt++){
                afh[mt] = *(const s16x8*)(&Ah[mt*16+l15][ks*32+lkb]);
                afl[mt] = *(const s16x8*)(&Al[mt*16+l15][ks*32+lkb]);
            }
            #pragma unroll
            for(int nt=0;nt<2;nt++){
                int col = wv*32 + nt*16 + l15;
                FragU bh, bl;
                #pragma unroll
                for(int j=0;j<8;j++){
                    bh.h[j] = Wh[ks*32+lkb+j][col];
                    bl.h[j] = Wl[ks*32+lkb+j][col];
                }
                #pragma unroll
                for(int mt=0;mt<4;mt++){
                    acc[mt][nt] = mfma16(afh[mt], bh.v, acc[mt][nt]);
                    acc[mt][nt] = mfma16(afh[mt], bl.v, acc[mt][nt]);
                    acc[mt][nt] = mfma16(afl[mt], bh.v, acc[mt][nt]);
                }
            }
        }
        __syncthreads();
    }
    #pragma unroll
    for(int nt=0;nt<2;nt++){
        int n = n0 + wv*32 + nt*16 + l15;
        float bias = bs[n] + 0.1f*b1[n];
        #pragma unroll
        for(int mt=0;mt<4;mt++)
            #pragma unroll
            for(int q=0;q<4;q++){
                int row = mt*16 + lg*4 + q;
                float v = acc[mt][nt][q] + bias;
                unsigned short hh = bfrne(v);
                KShi[(size_t)row*DKT + n] = hh;
                KSlo[(size_t)row*DKT + n] = bfrne(v - bf2f(hh));
                if(n >= 110592) KSb32[(size_t)row*1152 + (n - 110592)] = v;
            }
    }
}

// ---------------- stats ----------------
__global__ __launch_bounds__(256) void k_stat(const float* __restrict__ outPrev,
    float2* __restrict__ stats)
{
    __shared__ float img[4096], va[4096], vb[4096];
    __shared__ float ct[17], stp[17];
    __shared__ float red[8];
    int t = threadIdx.x, ch = blockIdx.x, b = blockIdx.y;
    const float* src = outPrev + ((size_t)b*32 + ch)*4096;
    float2* stc = stats + (b*32 + ch)*9;
    for(int i=t;i<4096;i+=256) img[i] = src[i];
    __syncthreads();
    float s0=0.f, s1=0.f;
    for(int i=t;i<4096;i+=256){ float v=img[i]; s0+=v; s1+=v*v; }
    blk_reduce2(s0, s1, red);
    float mu = s0*(1.f/4096.f);
    float var = s1*(1.f/4096.f) - mu*mu; var = var<0.f?0.f:var;
    if(t==0) stc[0] = make_float2(mu, rsqrtf(var + 1e-5f));
    const int ksz[4] = {3,5,9,17};
    for(int s=0;s<4;s++){
        int k = ksz[s], p = (k-1)>>1;
        if(t < k){
            float cc = -1.f + 2.f*(float)t/(float)(k-1);
            ct[t]  = cosf(1.5707963267948966f*cc);
            stp[t] = sinf(1.5707963267948966f*cc);
        }
        __syncthreads();
        for(int i=t;i<4096;i+=256){
            int y = i>>6, x = i&63; float ac=0.f, as=0.f;
            for(int tt=0;tt<k;tt++){
                int yy = y+tt-p;
                if(yy>=0 && yy<64){ float f = img[yy*64+x]; ac += ct[tt]*f; as += stp[tt]*f; }
            }
            va[i]=ac; vb[i]=as;
        }
        __syncthreads();
        float gx0=0.f,gx1=0.f,gy0=0.f,gy1=0.f;
        for(int i=t;i<4096;i+=256){
            int y=i>>6, x=i&63; float gx=0.f, gy=0.f;
            for(int tt=0;tt<k;tt++){
                int xx = x+tt-p;
                if(xx>=0 && xx<64){ gx += stp[tt]*va[y*64+xx]; gy += ct[tt]*vb[y*64+xx]; }
            }
            gx0+=gx; gx1+=gx*gx; gy0+=gy; gy1+=gy*gy;
        }
        blk_reduce2(gx0, gx1, red);
        blk_reduce2(gy0, gy1, red);
        float mgx = gx0*(1.f/4096.f), vgx = gx1*(1.f/4096.f)-mgx*mgx; vgx=vgx<0.f?0.f:vgx;
        float mgy = gy0*(1.f/4096.f), vgy = gy1*(1.f/4096.f)-mgy*mgy; vgy=vgy<0.f?0.f:vgy;
        if(t==0){
            stc[1+2*s] = make_float2(mgx, rsqrtf(vgx+1e-5f));
            stc[2+2*s] = make_float2(mgy, rsqrtf(vgy+1e-5f));
        }
        __syncthreads();
    }
}

// coop write of one [64 px][32 ch] hi/lo tile to part-major z
DEV void coopw(const unsigned short (*zt)[64][36], int part, int b, int y,
               unsigned short* zh, unsigned short* zl, int t)
{
    #pragma unroll
    for(int buf=0;buf<2;buf++){
        unsigned short* dst = (buf ? zl : zh) + ((size_t)(b*12+part)*4096 + y*64)*32;
        #pragma unroll
        for(int pos=t; pos<512; pos+=256){
            int px = pos>>3, c4 = pos&7;
            u16x4 v = *(const u16x4*)(&zt[buf][px][c4*4]);
            *(u16x4*)(dst + pos*4) = v;
        }
    }
}

// ---------------- znorm ----------------
__global__ __launch_bounds__(256) void k_znorm(const float* __restrict__ outPrev,
    const float2* __restrict__ stats,
    unsigned short* __restrict__ zh, unsigned short* __restrict__ zl)
{
    __shared__ unsigned short zt[2][2][64][36];
    __shared__ float va[4][80], vb[4][80];
    __shared__ float ct[17], stp[17];
    __shared__ float2 sst[288];
    int t = threadIdx.x, x = t&63, cq = t>>6;
    int y = blockIdx.x, b = blockIdx.y;
    const float* ob = outPrev + (size_t)b*131072;
    for(int i=t;i<288;i+=256) sst[i] = stats[b*288 + i];
    if(x < 16){
        int xp2 = (x<8) ? x : (x+64);
        va[cq][xp2] = 0.f; vb[cq][xp2] = 0.f;
    }
    __syncthreads();
    #pragma unroll
    for(int i=0;i<8;i++){
        int ch = cq*8 + i;
        float v = ob[(size_t)ch*4096 + y*64 + x];
        float2 sr = sst[ch*9];
        float z = (v - sr.x)*sr.y;
        unsigned short hh = bfrne(z);
        zt[0][0][x][ch] = hh; zt[0][1][x][ch] = bfrne(z - bf2f(hh));
    }
    __syncthreads();
    coopw(zt[0], 0, b, y, zh, zl, t);
    coopw(zt[0], 3, b, y, zh, zl, t);
    coopw(zt[0], 6, b, y, zh, zl, t);
    coopw(zt[0], 9, b, y, zh, zl, t);
    const int ksz[4] = {3,5,9,17};
    for(int s=0;s<4;s++){
        int k = ksz[s], p = (k-1)>>1, off = 8-p;
        __syncthreads();
        if(t < k){
            float cc = -1.f + 2.f*(float)t/(float)(k-1);
            ct[t]  = cosf(1.5707963267948966f*cc);
            stp[t] = sinf(1.5707963267948966f*cc);
        }
        __syncthreads();
        #pragma unroll 1
        for(int i=0;i<8;i++){
            int ch = cq*8 + i;
            const float* oc = ob + (size_t)ch*4096;
            float ac=0.f, as=0.f;
            for(int tt=0;tt<k;tt++){
                int yy = y+tt-p;
                if(yy>=0 && yy<64){ float f = oc[yy*64 + x]; ac += ct[tt]*f; as += stp[tt]*f; }
            }
            va[cq][x+8] = ac; vb[cq][x+8] = as;
            __builtin_amdgcn_wave_barrier();
            float gx=0.f, gy=0.f;
            for(int tt=0;tt<k;tt++){
                gx += stp[tt]*va[cq][x+tt+off];
                gy += ct[tt]*vb[cq][x+tt+off];
            }
            __builtin_amdgcn_wave_barrier();
            float2 sx = sst[ch*9 + 1+2*s], sy = sst[ch*9 + 2+2*s];
            float zx = (gx - sx.x)*sx.y, zy = (gy - sy.x)*sy.y;
            unsigned short hx = bfrne(zx), hy = bfrne(zy);
            zt[0][0][x][ch] = hx; zt[0][1][x][ch] = bfrne(zx - bf2f(hx));
            zt[1][0][x][ch] = hy; zt[1][1][x][ch] = bfrne(zy - bf2f(hy));
        }
        __syncthreads();
        coopw(zt[0], 3*s+1, b, y, zh, zl, t);
        coopw(zt[1], 3*s+2, b, y, zh, zl, t);
    }
}

// ---------------- dyna grouped convs + sigmoid gate ---------------------------
// zz written SINGLE-precision (hi only): post-gate path has gain ~0.04 into out.
__global__ __launch_bounds__(256) void k_dyna(
    const unsigned short* __restrict__ KShi, const unsigned short* __restrict__ KSlo,
    const float* __restrict__ KSb32,
    unsigned short* __restrict__ zh, unsigned short* __restrict__ zl, int cCall)
{
    __shared__ __align__(16) unsigned short lh[4][2][2][16][104];
    int t=threadIdx.x, wv=t>>6, lane=t&63, l15=lane&15, lg=lane>>4, lkb=lg*8;
    int b=blockIdx.z, g=blockIdx.y, px0=blockIdx.x*64 + wv*16;
    int row = cCall*8 + b;
    const unsigned short* Khi = KShi + (size_t)row*DKT + g*9216;
    const unsigned short* Klo = KSlo + (size_t)row*DKT + g*9216;
    const float* Bf = KSb32 + (size_t)row*1152 + g*96;
    size_t zb0 = ((size_t)(b*12 + g*3)*4096 + px0 + l15)*32;

    f32x4 acc[6];
    // ---- layer 1 ----
    #pragma unroll
    for(int mt=0;mt<6;mt++) acc[mt]=f32x4{0,0,0,0};
    #pragma unroll
    for(int kt=0;kt<3;kt++){
        s16x8 bh = *(const s16x8*)(zh + zb0 + (size_t)kt*ZPART + lkb);
        s16x8 bl = *(const s16x8*)(zl + zb0 + (size_t)kt*ZPART + lkb);
        #pragma unroll
        for(int mt=0;mt<6;mt++){
            s16x8 ah = *(const s16x8*)(Khi + (mt*16+l15)*96 + kt*32 + lkb);
            s16x8 al = *(const s16x8*)(Klo + (mt*16+l15)*96 + kt*32 + lkb);
            acc[mt] = mfma16(ah, bh, acc[mt]);
            acc[mt] = mfma16(ah, bl, acc[mt]);
            acc[mt] = mfma16(al, bh, acc[mt]);
        }
    }
    #pragma unroll
    for(int mt=0;mt<6;mt++){
        int o0 = mt*16 + lg*4;
        f32x4 bb = *(const f32x4*)(Bf + o0);
        U4 hh, hl;
        #pragma unroll
        for(int q=0;q<4;q++){
            float v = lrelu(acc[mt][q] + bb[q]);
            hh.h[q] = bfrne(v); hl.h[q] = bfrne(v - bf2f(hh.h[q]));
        }
        *(s16x4*)(&lh[wv][0][0][l15][o0]) = hh.v;
        *(s16x4*)(&lh[wv][0][1][l15][o0]) = hl.v;
    }
    // ---- layer 2 ----
    #pragma unroll
    for(int mt=0;mt<6;mt++) acc[mt]=f32x4{0,0,0,0};
    #pragma unroll
    for(int kt=0;kt<3;kt++){
        s16x8 bh = *(const s16x8*)(&lh[wv][0][0][l15][kt*32+lkb]);
        s16x8 bl = *(const s16x8*)(&lh[wv][0][1][l15][kt*32+lkb]);
        #pragma unroll
        for(int mt=0;mt<6;mt++){
            s16x8 ah = *(const s16x8*)(Khi + 36864 + (mt*16+l15)*96 + kt*32 + lkb);
            s16x8 al = *(const s16x8*)(Klo + 36864 + (mt*16+l15)*96 + kt*32 + lkb);
            acc[mt] = mfma16(ah, bh, acc[mt]);
            acc[mt] = mfma16(ah, bl, acc[mt]);
            acc[mt] = mfma16(al, bh, acc[mt]);
        }
    }
    #pragma unroll
    for(int mt=0;mt<6;mt++){
        int o0 = mt*16 + lg*4;
        f32x4 bb = *(const f32x4*)(Bf + 384 + o0);
        U4 hh, hl;
        #pragma unroll
        for(int q=0;q<4;q++){
            float v = lrelu(acc[mt][q] + bb[q]);
            hh.h[q] = bfrne(v); hl.h[q] = bfrne(v - bf2f(hh.h[q]));
        }
        *(s16x4*)(&lh[wv][1][0][l15][o0]) = hh.v;
        *(s16x4*)(&lh[wv][1][1][l15][o0]) = hl.v;
    }
    // ---- layer 3 + gate ----
    #pragma unroll
    for(int mt=0;mt<6;mt++) acc[mt]=f32x4{0,0,0,0};
    #pragma unroll
    for(int kt=0;kt<3;kt++){
        s16x8 bh = *(const s16x8*)(&lh[wv][1][0][l15][kt*32+lkb]);
        s16x8 bl = *(const s16x8*)(&lh[wv][1][1][l15][kt*32+lkb]);
        #pragma unroll
        for(int mt=0;mt<6;mt++){
            s16x8 ah = *(const s16x8*)(Khi + 73728 + (mt*16+l15)*96 + kt*32 + lkb);
            s16x8 al = *(const s16x8*)(Klo + 73728 + (mt*16+l15)*96 + kt*32 + lkb);
            acc[mt] = mfma16(ah, bh, acc[mt]);
            acc[mt] = mfma16(ah, bl, acc[mt]);
            acc[mt] = mfma16(al, bh, acc[mt]);
        }
    }
    #pragma unroll
    for(int mt=0;mt<6;mt++){
        int o0 = mt*16 + lg*4;
        f32x4 bb = *(const f32x4*)(Bf + 768 + o0);
        size_t zo = zb0 + (size_t)(o0>>5)*ZPART + (o0&31);
        U4 zvh, zvl;
        zvh.v = *(const s16x4*)(zh + zo);
        zvl.v = *(const s16x4*)(zl + zo);
        U4 ozh;
        #pragma unroll
        for(int q=0;q<4;q++){
            float zf = bf2f(zvh.h[q]) + bf2f(zvl.h[q]);
            float d  = zf + acc[mt][q] + bb[q];
            float sg = 1.f/(1.f + __expf(-d));
            ozh.h[q] = bfrne(zf*sg);
        }
        *(s16x4*)(zh + zo) = ozh.v;     // zz single-precision; zl left stale (dead)
    }
}

// ---------------- res_block + out update (zz single-precision reads) ----------
__global__ __launch_bounds__(256) void k_resb(const unsigned short* __restrict__ zzh,
    const unsigned short* __restrict__ w016, const unsigned short* __restrict__ w116,
    const unsigned short* __restrict__ wcsh, const unsigned short* __restrict__ wcsl,
    const float* __restrict__ c0b, const float* __restrict__ c1b, const float* __restrict__ csb,
    const float* __restrict__ outPrev, float* __restrict__ outNext)
{
    __shared__ __align__(16) unsigned short ldx[4][16][392];
    int t=threadIdx.x, wv=t>>6, lane=t&63, l15=lane&15, lg=lane>>4, lkb=lg*8;
    int b=blockIdx.y; int px0=blockIdx.x*64 + wv*16;
    size_t zb0 = ((size_t)(b*12)*4096 + px0 + l15)*32;

    // G1: dx1 = c0w @ leaky(zz)
    f32x4 a1[24];
    #pragma unroll
    for(int mt=0;mt<24;mt++) a1[mt]=f32x4{0,0,0,0};
    #pragma unroll 1
    for(int kt=0;kt<12;kt++){
        FragU bzh, blz;
        bzh.v = *(const s16x8*)(zzh + zb0 + (size_t)kt*ZPART + lkb);
        #pragma unroll
        for(int j=0;j<8;j++) blz.h[j] = bfrne(lrelu(bf2f(bzh.h[j])));
        #pragma unroll
        for(int mt=0;mt<24;mt++){
            s16x8 af = *(const s16x8*)(w016 + (size_t)(mt*16+l15)*384 + kt*32 + lkb);
            a1[mt] = mfma16(af, blz.v, a1[mt]);
        }
    }
    #pragma unroll
    for(int mt=0;mt<24;mt++){
        int o0 = mt*16 + lg*4;
        f32x4 bb = *(const f32x4*)(c0b + o0);
        U4 hv;
        #pragma unroll
        for(int q=0;q<4;q++) hv.h[q] = bfrne(lrelu(a1[mt][q] + bb[q]));
        *(s16x4*)(&ldx[wv][l15][o0]) = hv.v;
    }
    // G2: dx2 = c1w @ leaky(dx1) ; G3: r0 = csw(split) @ zz(single)
    f32x4 a2[2] = {f32x4{0,0,0,0}, f32x4{0,0,0,0}};
    f32x4 a3[2] = {f32x4{0,0,0,0}, f32x4{0,0,0,0}};
    #pragma unroll 1
    for(int kt=0;kt<12;kt++){
        s16x8 bh_ = *(const s16x8*)(&ldx[wv][l15][kt*32+lkb]);
        s16x8 bzh = *(const s16x8*)(zzh + zb0 + (size_t)kt*ZPART + lkb);
        #pragma unroll
        for(int mt=0;mt<2;mt++){
            s16x8 af1 = *(const s16x8*)(w116 + (size_t)(mt*16+l15)*384 + kt*32 + lkb);
            a2[mt] = mfma16(af1, bh_, a2[mt]);
            s16x8 wh = *(const s16x8*)(wcsh + (size_t)(mt*16+l15)*384 + kt*32 + lkb);
            s16x8 wl = *(const s16x8*)(wcsl + (size_t)(mt*16+l15)*384 + kt*32 + lkb);
            a3[mt] = mfma16(wh, bzh, a3[mt]);
            a3[mt] = mfma16(wl, bzh, a3[mt]);
        }
    }
    #pragma unroll
    for(int mt=0;mt<2;mt++){
        int o0 = mt*16 + lg*4;
        #pragma unroll
        for(int q=0;q<4;q++){
            int o = o0+q, px = px0 + l15;
            float dx2 = a2[mt][q] + c1b[o];
            float r   = a3[mt][q] + csb[o] + 0.1f*dx2;
            size_t oidx = (size_t)b*131072 + (size_t)o*4096 + px;
            outNext[oidx] = outPrev[oidx] + 0.1f*r;
        }
    }
}

// ---------------- head ----------------
__global__ __launch_bounds__(256) void k_head1(const float* __restrict__ outF,
    const float* __restrict__ wout, const float* __restrict__ bout, float* __restrict__ state)
{
    __shared__ float sw[97*32];
    __shared__ float sb_[97];
    __shared__ float fp[32];
    __shared__ float fwp[2048];
    int t = threadIdx.x, b = blockIdx.y, pxb = blockIdx.x*256;
    for(int i=t;i<97*32;i+=256) sw[i] = wout[i];
    if(t<97) sb_[t] = bout[t];
    if(t<32) fp[t] = 0.f;
    for(int i=t;i<2048;i+=256) fwp[i] = 0.f;
    __syncthreads();
    int px = pxb + t, lane = t&63, wv = t>>6;
    float xi[32];
    #pragma unroll
    for(int i=0;i<32;i++) xi[i] = outF[(size_t)b*131072 + (size_t)i*4096 + px];
    float* st = state + (size_t)b*8224;
    int row = (pxb>>6) + wv, x = lane;
    for(int o=0;o<97;o++){
        float acc = sb_[o];
        #pragma unroll
        for(int i=0;i<32;i++) acc += sw[o*32+i]*xi[i];
        if(o < 32){
            float s = wave_sum(acc);
            if(lane==0) atomicAdd(&fp[o], s);
        } else if(o < 64){
            float s = wave_sum(acc);
            if(lane==0) st[32 + (o-32)*64 + row] = s*(1.f/64.f);
        } else if(o < 96){
            atomicAdd(&fwp[(o-64)*64 + x], acc);
        } else {
            st[4128 + px] = acc;
        }
    }
    __syncthreads();
    if(t<32) atomicAdd(&st[t], fp[t]*(1.f/4096.f));
    for(int i=t;i<2048;i+=256) atomicAdd(&st[2080+i], fwp[i]*(1.f/64.f));
}

__global__ __launch_bounds__(256) void k_head2(const float* __restrict__ state,
    const float* __restrict__ otlw, float* __restrict__ latout)
{
    __shared__ float ss[8*514];
    int t = threadIdx.x, j = blockIdx.x*256 + t, s0 = blockIdx.y*514;
    for(int i=t;i<8*514;i+=256){ int bb=i/514, si=i-bb*514; ss[i] = state[(size_t)bb*8224 + s0 + si]; }
    __syncthreads();
    float acc[8] = {0,0,0,0,0,0,0,0};
    for(int si=0;si<514;si++){
        float wv_ = otlw[(size_t)(s0+si)*512 + j];
        #pragma unroll
        for(int b2=0;b2<8;b2++) acc[b2] += ss[b2*514+si]*wv_;
    }
    #pragma unroll
    for(int b2=0;b2<8;b2++) atomicAdd(latout + b2*512 + j, acc[b2]);
}

// =============================================================================
extern "C" void kernel_launch(void* const* d_in, const int* in_sizes, int n_in,
                              void* d_out, int out_size, void* d_ws, size_t ws_size,
                              hipStream_t stream)
{
    const float* x    = (const float*)d_in[0];
    const float* inj  = (const float*)d_in[1];
    const float* icw  = (const float*)d_in[2];
    const float* icb  = (const float*)d_in[3];
    const float* flWs = (const float*)d_in[4];
    const float* flbs = (const float*)d_in[5];
    const float* flW0 = (const float*)d_in[6];
    const float* flb0 = (const float*)d_in[7];
    const float* flW1 = (const float*)d_in[8];
    const float* flb1 = (const float*)d_in[9];
    const float* dkWs = (const float*)d_in[10];
    const float* dkbs = (const float*)d_in[11];
    const float* dkW0 = (const float*)d_in[12];
    const float* dkb0 = (const float*)d_in[13];
    const float* dkW1 = (const float*)d_in[14];
    const float* dkb1 = (const float*)d_in[15];
    const float* c0w  = (const float*)d_in[16];
    const float* c0b  = (const float*)d_in[17];
    const float* c1w  = (const float*)d_in[18];
    const float* c1b  = (const float*)d_in[19];
    const float* csw  = (const float*)d_in[20];
    const float* csb  = (const float*)d_in[21];
    const float* ocw  = (const float*)d_in[22];
    const float* ocb  = (const float*)d_in[23];
    const float* otlw = (const float*)d_in[24];
    const float* otlb = (const float*)d_in[25];
    float* out = (float*)d_out;

    char* wp = (char*)d_ws;
    auto carve = [&](size_t bytes)->void*{ void* p = wp; wp += (bytes + 255) & ~(size_t)255; return p; };
    float* lats  = (float*)carve(36864*4);
    float* ppS   = (float*)carve(32768*4);
    float* ppH   = (float*)carve(32768*4);
    float* ppD   = (float*)carve(524288*4);
    float* state = (float*)carve(65792*4);
    float2* stats = (float2*)carve(2304*8);
    unsigned short* Ahi   = (unsigned short*)carve((size_t)98304*2);
    unsigned short* Alo   = (unsigned short*)carve((size_t)98304*2);
    unsigned short* KShi  = (unsigned short*)carve((size_t)7151616*2);
    unsigned short* KSlo  = (unsigned short*)carve((size_t)7151616*2);
    float*          KSb32 = (float*)carve((size_t)73728*4);
    unsigned short* w016  = (unsigned short*)carve((size_t)147456*2);
    unsigned short* w116  = (unsigned short*)carve((size_t)12288*2);
    unsigned short* wcsh  = (unsigned short*)carve((size_t)12288*2);
    unsigned short* wcsl  = (unsigned short*)carve((size_t)12288*2);
    unsigned short* zh    = (unsigned short*)carve((size_t)12582912*2);  // z then zz (hi)
    unsigned short* zl    = (unsigned short*)carve((size_t)12582912*2);  // z lo (pre-gate only)

    k_init<<<1009,256,0,stream>>>(state, out, otlb, lats, inj,
                                  w016, c0w, w116, c1w, wcsh, wcsl, csw);
    k_out0<<<4096,256,0,stream>>>(x, icw, icb, out + 4096);

    for(int c=0;c<8;c++){
        const float* latc = lats + c*4096;
        k_latA<<<dim3(4,4,2),256,0,stream>>>(latc, flWs + (size_t)c*262144, flW0 + (size_t)c*262144,
                                             ppS, ppH);
        k_latBC<<<4,256,0,stream>>>(ppH, flb0 + (size_t)c*512,
                                    flW1 + (size_t)c*262144, flb1 + (size_t)c*512,
                                    latc, ppS, flbs + (size_t)c*512, lats + (c+1)*4096);
    }

    k_dkH<<<dim3(8,4),256,0,stream>>>(lats + 4096, dkW0, ppD);
    k_dkAcvt<<<384,256,0,stream>>>(lats + 4096, ppD, dkb0, Ahi, Alo);
    k_dkMain<<<873,256,0,stream>>>(Ahi, Alo, dkWs, dkW1, dkbs, dkb1, KShi, KSlo, KSb32);

    for(int c=0;c<8;c++){
        const float* outPrev = out + 4096 + (size_t)c*EMB;
        float*       outNext = out + 4096 + (size_t)(c+1)*EMB;
        k_stat<<<dim3(32,8),256,0,stream>>>(outPrev, stats);
        k_znorm<<<dim3(64,8),256,0,stream>>>(outPrev, stats, zh, zl);
        k_dyna<<<dim3(64,4,8),256,0,stream>>>(KShi, KSlo, KSb32, zh, zl, c);
        k_resb<<<dim3(64,8),256,0,stream>>>(zh, w016, w116, wcsh, wcsl,
                                            c0b, c1b, csb, outPrev, outNext);
    }

    k_head1<<<dim3(16,8),256,0,stream>>>(out + 4096 + (size_t)8*EMB, ocw, ocb, state);
    k_head2<<<dim3(2,16),256,0,stream>>>(state, otlw, out);
}

// Round 7
// 3381.183 us; speedup vs baseline: 1.2065x; 1.0978x over previous
//
#include <hip/hip_runtime.h>

#define DEV __device__ __forceinline__

typedef __attribute__((ext_vector_type(4))) float  f32x4;
typedef __attribute__((ext_vector_type(8))) short  s16x8;   // 8 bf16 (MFMA frag)
typedef __attribute__((ext_vector_type(4))) short  s16x4;   // 4 bf16 (8B ld/st)
typedef __attribute__((ext_vector_type(4))) unsigned short u16x4;

union FragU { s16x8 v; unsigned short h[8]; };
union U4    { s16x4 v; unsigned short h[4]; };

DEV float lrelu(float x){ return x > 0.f ? x : 0.2f*x; }
DEV unsigned short bfrne(float f){
    unsigned u = __builtin_bit_cast(unsigned, f);
    u += 0x7fffu + ((u>>16)&1u);
    return (unsigned short)(u>>16);
}
DEV float bf2f(unsigned short h){
    unsigned u = ((unsigned)h)<<16; return __builtin_bit_cast(float,u);
}
DEV f32x4 mfma16(s16x8 a, s16x8 b, f32x4 c){
    return __builtin_amdgcn_mfma_f32_16x16x32_bf16(a, b, c, 0, 0, 0);
}
DEV float wave_sum(float v){
    #pragma unroll
    for(int m=32;m>0;m>>=1) v += __shfl_xor(v, m, 64);
    return v;
}
DEV void blk_reduce2(float& a, float& b, float* sm){
    a = wave_sum(a); b = wave_sum(b);
    int wv = threadIdx.x>>6, ln = threadIdx.x&63;
    if(ln==0){ sm[wv*2]=a; sm[wv*2+1]=b; }
    __syncthreads();
    a = sm[0]+sm[2]+sm[4]+sm[6];
    b = sm[1]+sm[3]+sm[5]+sm[7];
    __syncthreads();
}

// ---------------- sizes ----------------
#define EMB   1048576               // 8*32*4096, one out_emb
#define DKT   111744
// z layout: [b][part 0..11][px 0..4095][ch 0..31]
#define ZPART 131072                // 4096*32

// ---------------- init (weights emitted FRAG-MAJOR for coalesced A-loads) -----
__global__ __launch_bounds__(256) void k_init(
    float* state, float* latout, const float* otlb,
    float* lats, const float* inj,
    unsigned short* w016, const float* c0w,
    unsigned short* w116, const float* c1w,
    unsigned short* wcsh, unsigned short* wcsl, const float* csw)
{
    int i = blockIdx.x*256 + threadIdx.x;
    if(i < 65792){ state[i] = 0.f; return; }            i -= 65792;
    if(i < 4096){ latout[i] = otlb[i&511]; return; }    i -= 4096;
    if(i < 4096){ lats[i] = inj[i]; return; }           i -= 4096;
    if(i < 147456){     // w016f[(mt*12+kt)*512 + lane*8 + j] <- c0w fragment
        int j = i&7, ln = (i>>3)&63, f2 = i>>9, mt = f2/12, kt = f2 - mt*12;
        w016[i] = bfrne(c0w[(mt*16 + (ln&15))*384 + kt*32 + (ln>>4)*8 + j]);
        return; }                                       i -= 147456;
    if(i < 12288){
        int j = i&7, ln = (i>>3)&63, f2 = i>>9, mt = f2/12, kt = f2 - mt*12;
        w116[i] = bfrne(c1w[(mt*16 + (ln&15))*384 + kt*32 + (ln>>4)*8 + j]);
        return; }                                       i -= 12288;
    if(i < 12288){
        int j = i&7, ln = (i>>3)&63, f2 = i>>9, mt = f2/12, kt = f2 - mt*12;
        wcsh[i] = bfrne(csw[(mt*16 + (ln&15))*384 + kt*32 + (ln>>4)*8 + j]);
        return; }                                       i -= 12288;
    if(i < 12288){
        int j = i&7, ln = (i>>3)&63, f2 = i>>9, mt = f2/12, kt = f2 - mt*12;
        float w = csw[(mt*16 + (ln&15))*384 + kt*32 + (ln>>4)*8 + j];
        unsigned short hh = bfrne(w);
        wcsl[i] = bfrne(w - bf2f(hh)); return; }
}

// ---------------- out_embs[0] = in_conv(x) ----------------
__global__ __launch_bounds__(256) void k_out0(const float* __restrict__ x,
    const float* __restrict__ w, const float* __restrict__ b, float* __restrict__ out0)
{
    int i = blockIdx.x*256 + threadIdx.x;
    int p = i & 4095, o = (i>>12)&31, bb = i>>17;
    const float* xb = x + (size_t)bb*12288 + p;
    out0[i] = b[o] + w[o*3]*xb[0] + w[o*3+1]*xb[4096] + w[o*3+2]*xb[8192];
}

// ---------------- latent chain (f32, deterministic partial sums) --------------
__global__ __launch_bounds__(256) void k_latA(const float* __restrict__ lat,
    const float* __restrict__ Ws, const float* __restrict__ W0,
    float* __restrict__ ppS, float* __restrict__ ppH)
{
    __shared__ float ls[8][128];
    int t = threadIdx.x;
    int kb = blockIdx.y*128;
    for(int i=t;i<1024;i+=256) ls[i>>7][i&127] = lat[(i>>7)*512 + kb + (i&127)];
    __syncthreads();
    const float* W = blockIdx.z ? W0 : Ws;
    float* pp = blockIdx.z ? ppH : ppS;
    int j = blockIdx.x*128 + (t&127);
    int half = t>>7, klo = half*64;
    int p = blockIdx.y*2 + half;
    float acc[8] = {0,0,0,0,0,0,0,0};
    for(int kk=0;kk<64;kk++){
        float wv_ = W[(size_t)(kb+klo+kk)*512 + j];
        #pragma unroll
        for(int m=0;m<8;m++) acc[m] += ls[m][klo+kk]*wv_;
    }
    #pragma unroll
    for(int m=0;m<8;m++) pp[(size_t)(p*8+m)*512 + j] = acc[m];
}

__global__ __launch_bounds__(256) void k_latBC(const float* __restrict__ ppH,
    const float* __restrict__ flb0c,
    const float* __restrict__ W1, const float* __restrict__ b1c,
    const float* __restrict__ latc, const float* __restrict__ ppS,
    const float* __restrict__ flbsc, float* __restrict__ latn)
{
    __shared__ float lh[8][512];
    __shared__ float part[8][128];
    int t = threadIdx.x;
    for(int i=t;i<4096;i+=256){
        int m = i>>9, jj = i&511;
        float v = flb0c[jj];
        #pragma unroll
        for(int p=0;p<8;p++) v += ppH[(size_t)(p*8+m)*512 + jj];
        lh[m][jj] = lrelu(v);
    }
    __syncthreads();
    int j = blockIdx.x*128 + (t&127), half = t>>7;
    float acc[8] = {0,0,0,0,0,0,0,0};
    int k0 = half*256;
    for(int kk=k0;kk<k0+256;kk++){
        float w = W1[(size_t)kk*512 + j];
        #pragma unroll
        for(int m=0;m<8;m++) acc[m] += lh[m][kk]*w;
    }
    if(half==1){
        #pragma unroll
        for(int m=0;m<8;m++) part[m][t&127] = acc[m];
    }
    __syncthreads();
    if(half==0){
        #pragma unroll
        for(int m=0;m<8;m++){
            float sv = flbsc[j];
            #pragma unroll
            for(int p=0;p<8;p++) sv += ppS[(size_t)(p*8+m)*512 + j];
            float t1 = acc[m] + part[m][t&127] + b1c[j];
            latn[m*512+j] = latc[m*512+j] + 0.1f*sv + 0.01f*t1;
        }
    }
}

// ---------------- DK hidden partials (deterministic) --------------------------
__global__ __launch_bounds__(256) void k_dkH(const float* __restrict__ latsAll,
    const float* __restrict__ W0, float* __restrict__ ppD)
{
    __shared__ float ls[64][128];
    int t = threadIdx.x;
    int kb = blockIdx.y*128;
    for(int i=t;i<8192;i+=256) ls[i>>7][i&127] = latsAll[(i>>7)*512 + kb + (i&127)];
    __syncthreads();
    int j = blockIdx.x*128 + (t&127);
    int ksub = t>>7;
    int p = blockIdx.y*2 + ksub;
    for(int mc=0;mc<4;mc++){
        float acc[16] = {0,0,0,0,0,0,0,0,0,0,0,0,0,0,0,0};
        for(int kk=0;kk<64;kk++){
            float wv_ = W0[(size_t)(kb + ksub*64 + kk)*1024 + j];
            #pragma unroll
            for(int mi=0;mi<16;mi++) acc[mi] += ls[mc*16+mi][ksub*64+kk]*wv_;
        }
        #pragma unroll
        for(int mi=0;mi<16;mi++) ppD[(size_t)(p*64 + mc*16+mi)*1024 + j] = acc[mi];
    }
}

__global__ __launch_bounds__(256) void k_dkAcvt(const float* __restrict__ latsAll,
    const float* __restrict__ ppD, const float* __restrict__ dkb0,
    unsigned short* __restrict__ Ahi, unsigned short* __restrict__ Alo)
{
    int i = blockIdx.x*256 + threadIdx.x;
    int m = i/1536, k = i - m*1536;
    float v;
    if(k < 512) v = latsAll[m*512 + k];
    else {
        int j = k - 512;
        float hv = dkb0[j];
        #pragma unroll
        for(int p=0;p<8;p++) hv += ppD[(size_t)(p*64+m)*1024 + j];
        v = 0.1f*lrelu(hv);
    }
    unsigned short hh = bfrne(v);
    Ahi[i] = hh; Alo[i] = bfrne(v - bf2f(hh));
}

// ---------------- KS = A @ [dkWs ; dkW1] + bias (LDS-staged GEMM) -------------
__global__ __launch_bounds__(256) void k_dkMain(const unsigned short* __restrict__ Ahi,
    const unsigned short* __restrict__ Alo,
    const float* __restrict__ Wsb, const float* __restrict__ W1b,
    const float* __restrict__ bs, const float* __restrict__ b1,
    unsigned short* __restrict__ KShi, unsigned short* __restrict__ KSlo,
    float* __restrict__ KSb32)
{
    __shared__ unsigned short Wh[64][138];
    __shared__ unsigned short Wl[64][138];
    __shared__ unsigned short Ah[64][72];
    __shared__ unsigned short Al[64][72];
    int t = threadIdx.x, wv = t>>6, lane = t&63, l15 = lane&15, lg = lane>>4, lkb = lg*8;
    int n0 = blockIdx.x*128;
    int sk = t>>5, sc = (t&31)*4;
    int am = t>>2, ac = (t&3)*16;

    f32x4 wreg[8];
    s16x8 ah0, ah1, al0, al1;
    {
        #pragma unroll
        for(int s=0;s<8;s++)
            wreg[s] = *(const f32x4*)(Wsb + (size_t)(sk + s*8)*DKT + n0 + sc);
        const unsigned short* Abh = Ahi + am*1536 + ac;
        const unsigned short* Abl = Alo + am*1536 + ac;
        ah0 = *(const s16x8*)(Abh);     ah1 = *(const s16x8*)(Abh + 8);
        al0 = *(const s16x8*)(Abl);     al1 = *(const s16x8*)(Abl + 8);
    }

    f32x4 acc[4][2];
    #pragma unroll
    for(int mt=0;mt<4;mt++){ acc[mt][0]=f32x4{0,0,0,0}; acc[mt][1]=f32x4{0,0,0,0}; }

    for(int kt=0;kt<24;kt++){
        #pragma unroll
        for(int s=0;s<8;s++){
            int k = sk + s*8;
            unsigned short hh[4], ll[4];
            #pragma unroll
            for(int e=0;e<4;e++){
                float w = wreg[s][e];
                hh[e] = bfrne(w); ll[e] = bfrne(w - bf2f(hh[e]));
            }
            *(unsigned*)(&Wh[k][sc])   = (unsigned)hh[0] | ((unsigned)hh[1]<<16);
            *(unsigned*)(&Wh[k][sc+2]) = (unsigned)hh[2] | ((unsigned)hh[3]<<16);
            *(unsigned*)(&Wl[k][sc])   = (unsigned)ll[0] | ((unsigned)ll[1]<<16);
            *(unsigned*)(&Wl[k][sc+2]) = (unsigned)ll[2] | ((unsigned)ll[3]<<16);
        }
        *(s16x8*)(&Ah[am][ac]) = ah0;  *(s16x8*)(&Ah[am][ac+8]) = ah1;
        *(s16x8*)(&Al[am][ac]) = al0;  *(s16x8*)(&Al[am][ac+8]) = al1;
        __syncthreads();
        if(kt < 23){
            int kn = kt+1;
            const float* Wb = (kn<8) ? (Wsb + (size_t)(kn*64)*DKT)
                                     : (W1b + (size_t)(kn*64-512)*DKT);
            #pragma unroll
            for(int s=0;s<8;s++)
                wreg[s] = *(const f32x4*)(Wb + (size_t)(sk + s*8)*DKT + n0 + sc);
            const unsigned short* Abh = Ahi + am*1536 + kn*64 + ac;
            const unsigned short* Abl = Alo + am*1536 + kn*64 + ac;
            ah0 = *(const s16x8*)(Abh);     ah1 = *(const s16x8*)(Abh + 8);
            al0 = *(const s16x8*)(Abl);     al1 = *(const s16x8*)(Abl + 8);
        }
        #pragma unroll
        for(int ks=0;ks<2;ks++){
            s16x8 afh[4], afl[4];
            #pragma unroll
            for(int mt=0;mt<4;mt++){
                afh[mt] = *(const s16x8*)(&Ah[mt*16+l15][ks*32+lkb]);
                afl[mt] = *(const s16x8*)(&Al[mt*16+l15][ks*32+lkb]);
            }
            #pragma unroll
            for(int nt=0;nt<2;nt++){
                int col = wv*32 + nt*16 + l15;
                FragU bh, bl;
                #pragma unroll
                for(int j=0;j<8;j++){
                    bh.h[j] = Wh[ks*32+lkb+j][col];
                    bl.h[j] = Wl[ks*32+lkb+j][col];
                }
                #pragma unroll
                for(int mt=0;mt<4;mt++){
                    acc[mt][nt] = mfma16(afh[mt], bh.v, acc[mt][nt]);
                    acc[mt][nt] = mfma16(afh[mt], bl.v, acc[mt][nt]);
                    acc[mt][nt] = mfma16(afl[mt], bh.v, acc[mt][nt]);
                }
            }
        }
        __syncthreads();
    }
    #pragma unroll
    for(int nt=0;nt<2;nt++){
        int n = n0 + wv*32 + nt*16 + l15;
        float bias = bs[n] + 0.1f*b1[n];
        #pragma unroll
        for(int mt=0;mt<4;mt++)
            #pragma unroll
            for(int q=0;q<4;q++){
                int row = mt*16 + lg*4 + q;
                float v = acc[mt][nt][q] + bias;
                unsigned short hh = bfrne(v);
                KShi[(size_t)row*DKT + n] = hh;
                KSlo[(size_t)row*DKT + n] = bfrne(v - bf2f(hh));
                if(n >= 110592) KSb32[(size_t)row*1152 + (n - 110592)] = v;
            }
    }
}

// ---------------- repack KS into frag-major for coalesced dyna A-loads --------
// dst idx = (((r*4+g)*3+L)*18 + f)*64 + lane ; 16B per frag-lane
__global__ __launch_bounds__(256) void k_ksperm(const unsigned short* __restrict__ KShi,
    const unsigned short* __restrict__ KSlo,
    unsigned short* __restrict__ KSfh, unsigned short* __restrict__ KSfl)
{
    int idx = blockIdx.x*256 + threadIdx.x;     // < 884736
    int lane = idx & 63;
    int q    = idx >> 6;                        // (((r*4+g)*3+L)*18 + f)
    int f    = q % 18;       q /= 18;
    int L    = q % 3;        q /= 3;
    int g    = q % 4;
    int r    = q / 4;
    int mt = f/3, kt = f - mt*3;
    size_t src = (size_t)r*DKT + L*36864 + g*9216
               + (mt*16 + (lane&15))*96 + kt*32 + (lane>>4)*8;
    *(s16x8*)(KSfh + (size_t)idx*8) = *(const s16x8*)(KShi + src);
    *(s16x8*)(KSfl + (size_t)idx*8) = *(const s16x8*)(KSlo + src);
}

// ---------------- stats ----------------
__global__ __launch_bounds__(256) void k_stat(const float* __restrict__ outPrev,
    float2* __restrict__ stats)
{
    __shared__ float img[4096], va[4096], vb[4096];
    __shared__ float ct[17], stp[17];
    __shared__ float red[8];
    int t = threadIdx.x, ch = blockIdx.x, b = blockIdx.y;
    const float* src = outPrev + ((size_t)b*32 + ch)*4096;
    float2* stc = stats + (b*32 + ch)*9;
    for(int i=t;i<4096;i+=256) img[i] = src[i];
    __syncthreads();
    float s0=0.f, s1=0.f;
    for(int i=t;i<4096;i+=256){ float v=img[i]; s0+=v; s1+=v*v; }
    blk_reduce2(s0, s1, red);
    float mu = s0*(1.f/4096.f);
    float var = s1*(1.f/4096.f) - mu*mu; var = var<0.f?0.f:var;
    if(t==0) stc[0] = make_float2(mu, rsqrtf(var + 1e-5f));
    const int ksz[4] = {3,5,9,17};
    for(int s=0;s<4;s++){
        int k = ksz[s], p = (k-1)>>1;
        if(t < k){
            float cc = -1.f + 2.f*(float)t/(float)(k-1);
            ct[t]  = cosf(1.5707963267948966f*cc);
            stp[t] = sinf(1.5707963267948966f*cc);
        }
        __syncthreads();
        for(int i=t;i<4096;i+=256){
            int y = i>>6, x = i&63; float ac=0.f, as=0.f;
            for(int tt=0;tt<k;tt++){
                int yy = y+tt-p;
                if(yy>=0 && yy<64){ float f = img[yy*64+x]; ac += ct[tt]*f; as += stp[tt]*f; }
            }
            va[i]=ac; vb[i]=as;
        }
        __syncthreads();
        float gx0=0.f,gx1=0.f,gy0=0.f,gy1=0.f;
        for(int i=t;i<4096;i+=256){
            int y=i>>6, x=i&63; float gx=0.f, gy=0.f;
            for(int tt=0;tt<k;tt++){
                int xx = x+tt-p;
                if(xx>=0 && xx<64){ gx += stp[tt]*va[y*64+xx]; gy += ct[tt]*vb[y*64+xx]; }
            }
            gx0+=gx; gx1+=gx*gx; gy0+=gy; gy1+=gy*gy;
        }
        blk_reduce2(gx0, gx1, red);
        blk_reduce2(gy0, gy1, red);
        float mgx = gx0*(1.f/4096.f), vgx = gx1*(1.f/4096.f)-mgx*mgx; vgx=vgx<0.f?0.f:vgx;
        float mgy = gy0*(1.f/4096.f), vgy = gy1*(1.f/4096.f)-mgy*mgy; vgy=vgy<0.f?0.f:vgy;
        if(t==0){
            stc[1+2*s] = make_float2(mgx, rsqrtf(vgx+1e-5f));
            stc[2+2*s] = make_float2(mgy, rsqrtf(vgy+1e-5f));
        }
        __syncthreads();
    }
}

DEV void coopw(const unsigned short (*zt)[64][36], int part, int b, int y,
               unsigned short* zh, unsigned short* zl, int t)
{
    #pragma unroll
    for(int buf=0;buf<2;buf++){
        unsigned short* dst = (buf ? zl : zh) + ((size_t)(b*12+part)*4096 + y*64)*32;
        #pragma unroll
        for(int pos=t; pos<512; pos+=256){
            int px = pos>>3, c4 = pos&7;
            u16x4 v = *(const u16x4*)(&zt[buf][px][c4*4]);
            *(u16x4*)(dst + pos*4) = v;
        }
    }
}

// ---------------- znorm ----------------
__global__ __launch_bounds__(256) void k_znorm(const float* __restrict__ outPrev,
    const float2* __restrict__ stats,
    unsigned short* __restrict__ zh, unsigned short* __restrict__ zl)
{
    __shared__ unsigned short zt[2][2][64][36];
    __shared__ float va[4][80], vb[4][80];
    __shared__ float ct[17], stp[17];
    __shared__ float2 sst[288];
    int t = threadIdx.x, x = t&63, cq = t>>6;
    int y = blockIdx.x, b = blockIdx.y;
    const float* ob = outPrev + (size_t)b*131072;
    for(int i=t;i<288;i+=256) sst[i] = stats[b*288 + i];
    if(x < 16){
        int xp2 = (x<8) ? x : (x+64);
        va[cq][xp2] = 0.f; vb[cq][xp2] = 0.f;
    }
    __syncthreads();
    #pragma unroll
    for(int i=0;i<8;i++){
        int ch = cq*8 + i;
        float v = ob[(size_t)ch*4096 + y*64 + x];
        float2 sr = sst[ch*9];
        float z = (v - sr.x)*sr.y;
        unsigned short hh = bfrne(z);
        zt[0][0][x][ch] = hh; zt[0][1][x][ch] = bfrne(z - bf2f(hh));
    }
    __syncthreads();
    coopw(zt[0], 0, b, y, zh, zl, t);
    coopw(zt[0], 3, b, y, zh, zl, t);
    coopw(zt[0], 6, b, y, zh, zl, t);
    coopw(zt[0], 9, b, y, zh, zl, t);
    const int ksz[4] = {3,5,9,17};
    for(int s=0;s<4;s++){
        int k = ksz[s], p = (k-1)>>1, off = 8-p;
        __syncthreads();
        if(t < k){
            float cc = -1.f + 2.f*(float)t/(float)(k-1);
            ct[t]  = cosf(1.5707963267948966f*cc);
            stp[t] = sinf(1.5707963267948966f*cc);
        }
        __syncthreads();
        #pragma unroll 1
        for(int i=0;i<8;i++){
            int ch = cq*8 + i;
            const float* oc = ob + (size_t)ch*4096;
            float ac=0.f, as=0.f;
            for(int tt=0;tt<k;tt++){
                int yy = y+tt-p;
                if(yy>=0 && yy<64){ float f = oc[yy*64 + x]; ac += ct[tt]*f; as += stp[tt]*f; }
            }
            va[cq][x+8] = ac; vb[cq][x+8] = as;
            __builtin_amdgcn_wave_barrier();
            float gx=0.f, gy=0.f;
            for(int tt=0;tt<k;tt++){
                gx += stp[tt]*va[cq][x+tt+off];
                gy += ct[tt]*vb[cq][x+tt+off];
            }
            __builtin_amdgcn_wave_barrier();
            float2 sx = sst[ch*9 + 1+2*s], sy = sst[ch*9 + 2+2*s];
            float zx = (gx - sx.x)*sx.y, zy = (gy - sy.x)*sy.y;
            unsigned short hx = bfrne(zx), hy = bfrne(zy);
            zt[0][0][x][ch] = hx; zt[0][1][x][ch] = bfrne(zx - bf2f(hx));
            zt[1][0][x][ch] = hy; zt[1][1][x][ch] = bfrne(zy - bf2f(hy));
        }
        __syncthreads();
        coopw(zt[0], 3*s+1, b, y, zh, zl, t);
        coopw(zt[1], 3*s+2, b, y, zh, zl, t);
    }
}

// ---------------- dyna grouped convs + sigmoid gate (frag-major K reads) ------
__global__ __launch_bounds__(256) void k_dyna(
    const unsigned short* __restrict__ KSfh, const unsigned short* __restrict__ KSfl,
    const float* __restrict__ KSb32,
    unsigned short* __restrict__ zh, unsigned short* __restrict__ zl, int cCall)
{
    __shared__ __align__(16) unsigned short lh[4][2][2][16][104];
    int t=threadIdx.x, wv=t>>6, lane=t&63, l15=lane&15, lg=lane>>4, lkb=lg*8;
    int b=blockIdx.z, g=blockIdx.y, px0=blockIdx.x*64 + wv*16;
    int row = cCall*8 + b;
    const unsigned short* Kfh = KSfh + (size_t)((row*4 + g)*3)*9216;
    const unsigned short* Kfl = KSfl + (size_t)((row*4 + g)*3)*9216;
    const float* Bf = KSb32 + (size_t)row*1152 + g*96;
    size_t zb0 = ((size_t)(b*12 + g*3)*4096 + px0 + l15)*32;

    f32x4 acc[6];
    // ---- layer 1 (K frag-major, coalesced) ----
    #pragma unroll
    for(int mt=0;mt<6;mt++) acc[mt]=f32x4{0,0,0,0};
    #pragma unroll
    for(int kt=0;kt<3;kt++){
        s16x8 bh = *(const s16x8*)(zh + zb0 + (size_t)kt*ZPART + lkb);
        s16x8 bl = *(const s16x8*)(zl + zb0 + (size_t)kt*ZPART + lkb);
        #pragma unroll
        for(int mt=0;mt<6;mt++){
            s16x8 ah = *(const s16x8*)(Kfh + ((mt*3+kt)*64 + lane)*8);
            s16x8 al = *(const s16x8*)(Kfl + ((mt*3+kt)*64 + lane)*8);
            acc[mt] = mfma16(ah, bh, acc[mt]);
            acc[mt] = mfma16(ah, bl, acc[mt]);
            acc[mt] = mfma16(al, bh, acc[mt]);
        }
    }
    #pragma unroll
    for(int mt=0;mt<6;mt++){
        int o0 = mt*16 + lg*4;
        f32x4 bb = *(const f32x4*)(Bf + o0);
        U4 hh, hl;
        #pragma unroll
        for(int q=0;q<4;q++){
            float v = lrelu(acc[mt][q] + bb[q]);
            hh.h[q] = bfrne(v); hl.h[q] = bfrne(v - bf2f(hh.h[q]));
        }
        *(s16x4*)(&lh[wv][0][0][l15][o0]) = hh.v;
        *(s16x4*)(&lh[wv][0][1][l15][o0]) = hl.v;
    }
    // ---- layer 2 ----
    #pragma unroll
    for(int mt=0;mt<6;mt++) acc[mt]=f32x4{0,0,0,0};
    #pragma unroll
    for(int kt=0;kt<3;kt++){
        s16x8 bh = *(const s16x8*)(&lh[wv][0][0][l15][kt*32+lkb]);
        s16x8 bl = *(const s16x8*)(&lh[wv][0][1][l15][kt*32+lkb]);
        #pragma unroll
        for(int mt=0;mt<6;mt++){
            s16x8 ah = *(const s16x8*)(Kfh + 9216 + ((mt*3+kt)*64 + lane)*8);
            s16x8 al = *(const s16x8*)(Kfl + 9216 + ((mt*3+kt)*64 + lane)*8);
            acc[mt] = mfma16(ah, bh, acc[mt]);
            acc[mt] = mfma16(ah, bl, acc[mt]);
            acc[mt] = mfma16(al, bh, acc[mt]);
        }
    }
    #pragma unroll
    for(int mt=0;mt<6;mt++){
        int o0 = mt*16 + lg*4;
        f32x4 bb = *(const f32x4*)(Bf + 384 + o0);
        U4 hh, hl;
        #pragma unroll
        for(int q=0;q<4;q++){
            float v = lrelu(acc[mt][q] + bb[q]);
            hh.h[q] = bfrne(v); hl.h[q] = bfrne(v - bf2f(hh.h[q]));
        }
        *(s16x4*)(&lh[wv][1][0][l15][o0]) = hh.v;
        *(s16x4*)(&lh[wv][1][1][l15][o0]) = hl.v;
    }
    // ---- layer 3 + gate ----
    #pragma unroll
    for(int mt=0;mt<6;mt++) acc[mt]=f32x4{0,0,0,0};
    #pragma unroll
    for(int kt=0;kt<3;kt++){
        s16x8 bh = *(const s16x8*)(&lh[wv][1][0][l15][kt*32+lkb]);
        s16x8 bl = *(const s16x8*)(&lh[wv][1][1][l15][kt*32+lkb]);
        #pragma unroll
        for(int mt=0;mt<6;mt++){
            s16x8 ah = *(const s16x8*)(Kfh + 18432 + ((mt*3+kt)*64 + lane)*8);
            s16x8 al = *(const s16x8*)(Kfl + 18432 + ((mt*3+kt)*64 + lane)*8);
            acc[mt] = mfma16(ah, bh, acc[mt]);
            acc[mt] = mfma16(ah, bl, acc[mt]);
            acc[mt] = mfma16(al, bh, acc[mt]);
        }
    }
    #pragma unroll
    for(int mt=0;mt<6;mt++){
        int o0 = mt*16 + lg*4;
        f32x4 bb = *(const f32x4*)(Bf + 768 + o0);
        size_t zo = zb0 + (size_t)(o0>>5)*ZPART + (o0&31);
        U4 zvh, zvl;
        zvh.v = *(const s16x4*)(zh + zo);
        zvl.v = *(const s16x4*)(zl + zo);
        U4 ozh;
        #pragma unroll
        for(int q=0;q<4;q++){
            float zf = bf2f(zvh.h[q]) + bf2f(zvl.h[q]);
            float d  = zf + acc[mt][q] + bb[q];
            float sg = 1.f/(1.f + __expf(-d));
            ozh.h[q] = bfrne(zf*sg);
        }
        *(s16x4*)(zh + zo) = ozh.v;
    }
}

// ---------------- res_block + out update (frag-major weight reads) ------------
__global__ __launch_bounds__(256) void k_resb(const unsigned short* __restrict__ zzh,
    const unsigned short* __restrict__ w016, const unsigned short* __restrict__ w116,
    const unsigned short* __restrict__ wcsh, const unsigned short* __restrict__ wcsl,
    const float* __restrict__ c0b, const float* __restrict__ c1b, const float* __restrict__ csb,
    const float* __restrict__ outPrev, float* __restrict__ outNext)
{
    __shared__ __align__(16) unsigned short ldx[4][16][392];
    int t=threadIdx.x, wv=t>>6, lane=t&63, l15=lane&15, lg=lane>>4, lkb=lg*8;
    int b=blockIdx.y; int px0=blockIdx.x*64 + wv*16;
    size_t zb0 = ((size_t)(b*12)*4096 + px0 + l15)*32;

    // G1: dx1 = c0w @ leaky(zz)
    f32x4 a1[24];
    #pragma unroll
    for(int mt=0;mt<24;mt++) a1[mt]=f32x4{0,0,0,0};
    #pragma unroll 1
    for(int kt=0;kt<12;kt++){
        FragU bzh, blz;
        bzh.v = *(const s16x8*)(zzh + zb0 + (size_t)kt*ZPART + lkb);
        #pragma unroll
        for(int j=0;j<8;j++) blz.h[j] = bfrne(lrelu(bf2f(bzh.h[j])));
        #pragma unroll
        for(int mt=0;mt<24;mt++){
            s16x8 af = *(const s16x8*)(w016 + ((size_t)(mt*12+kt)<<9) + (lane<<3));
            a1[mt] = mfma16(af, blz.v, a1[mt]);
        }
    }
    #pragma unroll
    for(int mt=0;mt<24;mt++){
        int o0 = mt*16 + lg*4;
        f32x4 bb = *(const f32x4*)(c0b + o0);
        U4 hv;
        #pragma unroll
        for(int q=0;q<4;q++) hv.h[q] = bfrne(lrelu(a1[mt][q] + bb[q]));
        *(s16x4*)(&ldx[wv][l15][o0]) = hv.v;
    }
    // G2: dx2 = c1w @ leaky(dx1) ; G3: r0 = csw(split) @ zz(single)
    f32x4 a2[2] = {f32x4{0,0,0,0}, f32x4{0,0,0,0}};
    f32x4 a3[2] = {f32x4{0,0,0,0}, f32x4{0,0,0,0}};
    #pragma unroll 1
    for(int kt=0;kt<12;kt++){
        s16x8 bh_ = *(const s16x8*)(&ldx[wv][l15][kt*32+lkb]);
        s16x8 bzh = *(const s16x8*)(zzh + zb0 + (size_t)kt*ZPART + lkb);
        #pragma unroll
        for(int mt=0;mt<2;mt++){
            s16x8 af1 = *(const s16x8*)(w116 + ((size_t)(mt*12+kt)<<9) + (lane<<3));
            a2[mt] = mfma16(af1, bh_, a2[mt]);
            s16x8 wh = *(const s16x8*)(wcsh + ((size_t)(mt*12+kt)<<9) + (lane<<3));
            s16x8 wl = *(const s16x8*)(wcsl + ((size_t)(mt*12+kt)<<9) + (lane<<3));
            a3[mt] = mfma16(wh, bzh, a3[mt]);
            a3[mt] = mfma16(wl, bzh, a3[mt]);
        }
    }
    #pragma unroll
    for(int mt=0;mt<2;mt++){
        int o0 = mt*16 + lg*4;
        #pragma unroll
        for(int q=0;q<4;q++){
            int o = o0+q, px = px0 + l15;
            float dx2 = a2[mt][q] + c1b[o];
            float r   = a3[mt][q] + csb[o] + 0.1f*dx2;
            size_t oidx = (size_t)b*131072 + (size_t)o*4096 + px;
            outNext[oidx] = outPrev[oidx] + 0.1f*r;
        }
    }
}

// ---------------- head ----------------
__global__ __launch_bounds__(256) void k_head1(const float* __restrict__ outF,
    const float* __restrict__ wout, const float* __restrict__ bout, float* __restrict__ state)
{
    __shared__ float sw[97*32];
    __shared__ float sb_[97];
    __shared__ float fp[32];
    __shared__ float fwp[2048];
    int t = threadIdx.x, b = blockIdx.y, pxb = blockIdx.x*256;
    for(int i=t;i<97*32;i+=256) sw[i] = wout[i];
    if(t<97) sb_[t] = bout[t];
    if(t<32) fp[t] = 0.f;
    for(int i=t;i<2048;i+=256) fwp[i] = 0.f;
    __syncthreads();
    int px = pxb + t, lane = t&63, wv = t>>6;
    float xi[32];
    #pragma unroll
    for(int i=0;i<32;i++) xi[i] = outF[(size_t)b*131072 + (size_t)i*4096 + px];
    float* st = state + (size_t)b*8224;
    int row = (pxb>>6) + wv, x = lane;
    for(int o=0;o<97;o++){
        float acc = sb_[o];
        #pragma unroll
        for(int i=0;i<32;i++) acc += sw[o*32+i]*xi[i];
        if(o < 32){
            float s = wave_sum(acc);
            if(lane==0) atomicAdd(&fp[o], s);
        } else if(o < 64){
            float s = wave_sum(acc);
            if(lane==0) st[32 + (o-32)*64 + row] = s*(1.f/64.f);
        } else if(o < 96){
            atomicAdd(&fwp[(o-64)*64 + x], acc);
        } else {
            st[4128 + px] = acc;
        }
    }
    __syncthreads();
    if(t<32) atomicAdd(&st[t], fp[t]*(1.f/4096.f));
    for(int i=t;i<2048;i+=256) atomicAdd(&st[2080+i], fwp[i]*(1.f/64.f));
}

__global__ __launch_bounds__(256) void k_head2(const float* __restrict__ state,
    const float* __restrict__ otlw, float* __restrict__ latout)
{
    __shared__ float ss[8*514];
    int t = threadIdx.x, j = blockIdx.x*256 + t, s0 = blockIdx.y*514;
    for(int i=t;i<8*514;i+=256){ int bb=i/514, si=i-bb*514; ss[i] = state[(size_t)bb*8224 + s0 + si]; }
    __syncthreads();
    float acc[8] = {0,0,0,0,0,0,0,0};
    for(int si=0;si<514;si++){
        float wv_ = otlw[(size_t)(s0+si)*512 + j];
        #pragma unroll
        for(int b2=0;b2<8;b2++) acc[b2] += ss[b2*514+si]*wv_;
    }
    #pragma unroll
    for(int b2=0;b2<8;b2++) atomicAdd(latout + b2*512 + j, acc[b2]);
}

// =============================================================================
extern "C" void kernel_launch(void* const* d_in, const int* in_sizes, int n_in,
                              void* d_out, int out_size, void* d_ws, size_t ws_size,
                              hipStream_t stream)
{
    const float* x    = (const float*)d_in[0];
    const float* inj  = (const float*)d_in[1];
    const float* icw  = (const float*)d_in[2];
    const float* icb  = (const float*)d_in[3];
    const float* flWs = (const float*)d_in[4];
    const float* flbs = (const float*)d_in[5];
    const float* flW0 = (const float*)d_in[6];
    const float* flb0 = (const float*)d_in[7];
    const float* flW1 = (const float*)d_in[8];
    const float* flb1 = (const float*)d_in[9];
    const float* dkWs = (const float*)d_in[10];
    const float* dkbs = (const float*)d_in[11];
    const float* dkW0 = (const float*)d_in[12];
    const float* dkb0 = (const float*)d_in[13];
    const float* dkW1 = (const float*)d_in[14];
    const float* dkb1 = (const float*)d_in[15];
    const float* c0w  = (const float*)d_in[16];
    const float* c0b  = (const float*)d_in[17];
    const float* c1w  = (const float*)d_in[18];
    const float* c1b  = (const float*)d_in[19];
    const float* csw  = (const float*)d_in[20];
    const float* csb  = (const float*)d_in[21];
    const float* ocw  = (const float*)d_in[22];
    const float* ocb  = (const float*)d_in[23];
    const float* otlw = (const float*)d_in[24];
    const float* otlb = (const float*)d_in[25];
    float* out = (float*)d_out;

    char* wp = (char*)d_ws;
    auto carve = [&](size_t bytes)->void*{ void* p = wp; wp += (bytes + 255) & ~(size_t)255; return p; };
    float* lats  = (float*)carve(36864*4);
    float* ppS   = (float*)carve(32768*4);
    float* ppH   = (float*)carve(32768*4);
    float* ppD   = (float*)carve(524288*4);
    float* state = (float*)carve(65792*4);
    float2* stats = (float2*)carve(2304*8);
    unsigned short* Ahi   = (unsigned short*)carve((size_t)98304*2);
    unsigned short* Alo   = (unsigned short*)carve((size_t)98304*2);
    unsigned short* KShi  = (unsigned short*)carve((size_t)7151616*2);
    unsigned short* KSlo  = (unsigned short*)carve((size_t)7151616*2);
    unsigned short* KSfh  = (unsigned short*)carve((size_t)7077888*2);  // frag-major
    unsigned short* KSfl  = (unsigned short*)carve((size_t)7077888*2);
    float*          KSb32 = (float*)carve((size_t)73728*4);
    unsigned short* w016  = (unsigned short*)carve((size_t)147456*2);   // frag-major
    unsigned short* w116  = (unsigned short*)carve((size_t)12288*2);
    unsigned short* wcsh  = (unsigned short*)carve((size_t)12288*2);
    unsigned short* wcsl  = (unsigned short*)carve((size_t)12288*2);
    unsigned short* zh    = (unsigned short*)carve((size_t)12582912*2);
    unsigned short* zl    = (unsigned short*)carve((size_t)12582912*2);

    k_init<<<1009,256,0,stream>>>(state, out, otlb, lats, inj,
                                  w016, c0w, w116, c1w, wcsh, wcsl, csw);
    k_out0<<<4096,256,0,stream>>>(x, icw, icb, out + 4096);

    for(int c=0;c<8;c++){
        const float* latc = lats + c*4096;
        k_latA<<<dim3(4,4,2),256,0,stream>>>(latc, flWs + (size_t)c*262144, flW0 + (size_t)c*262144,
                                             ppS, ppH);
        k_latBC<<<4,256,0,stream>>>(ppH, flb0 + (size_t)c*512,
                                    flW1 + (size_t)c*262144, flb1 + (size_t)c*512,
                                    latc, ppS, flbs + (size_t)c*512, lats + (c+1)*4096);
    }

    k_dkH<<<dim3(8,4),256,0,stream>>>(lats + 4096, dkW0, ppD);
    k_dkAcvt<<<384,256,0,stream>>>(lats + 4096, ppD, dkb0, Ahi, Alo);
    k_dkMain<<<873,256,0,stream>>>(Ahi, Alo, dkWs, dkW1, dkbs, dkb1, KShi, KSlo, KSb32);
    k_ksperm<<<3456,256,0,stream>>>(KShi, KSlo, KSfh, KSfl);

    for(int c=0;c<8;c++){
        const float* outPrev = out + 4096 + (size_t)c*EMB;
        float*       outNext = out + 4096 + (size_t)(c+1)*EMB;
        k_stat<<<dim3(32,8),256,0,stream>>>(outPrev, stats);
        k_znorm<<<dim3(64,8),256,0,stream>>>(outPrev, stats, zh, zl);
        k_dyna<<<dim3(64,4,8),256,0,stream>>>(KSfh, KSfl, KSb32, zh, zl, c);
        k_resb<<<dim3(64,8),256,0,stream>>>(zh, w016, w116, wcsh, wcsl,
                                            c0b, c1b, csb, outPrev, outNext);
    }

    k_head1<<<dim3(16,8),256,0,stream>>>(out + 4096 + (size_t)8*EMB, ocw, ocb, state);
    k_head2<<<dim3(2,16),256,0,stream>>>(state, otlw, out);
}

// Round 8
// 3119.290 us; speedup vs baseline: 1.3078x; 1.0840x over previous
//
#include <hip/hip_runtime.h>

#define DEV __device__ __forceinline__

typedef __attribute__((ext_vector_type(4))) float  f32x4;
typedef __attribute__((ext_vector_type(8))) short  s16x8;   // 8 bf16 (MFMA frag)
typedef __attribute__((ext_vector_type(4))) short  s16x4;   // 4 bf16 (8B ld/st)

union FragU { s16x8 v; unsigned short h[8]; };
union U4    { s16x4 v; unsigned short h[4]; };

DEV float lrelu(float x){ return x > 0.f ? x : 0.2f*x; }
DEV unsigned short bfrne(float f){
    unsigned u = __builtin_bit_cast(unsigned, f);
    u += 0x7fffu + ((u>>16)&1u);
    return (unsigned short)(u>>16);
}
DEV float bf2f(unsigned short h){
    unsigned u = ((unsigned)h)<<16; return __builtin_bit_cast(float,u);
}
DEV f32x4 mfma16(s16x8 a, s16x8 b, f32x4 c){
    return __builtin_amdgcn_mfma_f32_16x16x32_bf16(a, b, c, 0, 0, 0);
}
DEV float wave_sum(float v){
    #pragma unroll
    for(int m=32;m>0;m>>=1) v += __shfl_xor(v, m, 64);
    return v;
}
DEV void blk_reduce2(float& a, float& b, float* sm){
    a = wave_sum(a); b = wave_sum(b);
    int wv = threadIdx.x>>6, ln = threadIdx.x&63;
    if(ln==0){ sm[wv*2]=a; sm[wv*2+1]=b; }
    __syncthreads();
    a = sm[0]+sm[2]+sm[4]+sm[6];
    b = sm[1]+sm[3]+sm[5]+sm[7];
    __syncthreads();
}

// ---------------- sizes ----------------
#define EMB   1048576               // 8*32*4096, one out_emb
#define DKT   111744

// ---------------- init (weights emitted FRAG-MAJOR) ---------------------------
__global__ __launch_bounds__(256) void k_init(
    float* state, float* latout, const float* otlb,
    float* lats, const float* inj,
    unsigned short* w016, const float* c0w,
    unsigned short* w116, const float* c1w,
    unsigned short* wcsh, unsigned short* wcsl, const float* csw)
{
    int i = blockIdx.x*256 + threadIdx.x;
    if(i < 65792){ state[i] = 0.f; return; }            i -= 65792;
    if(i < 4096){ latout[i] = otlb[i&511]; return; }    i -= 4096;
    if(i < 4096){ lats[i] = inj[i]; return; }           i -= 4096;
    if(i < 147456){
        int j = i&7, ln = (i>>3)&63, f2 = i>>9, mt = f2/12, kt = f2 - mt*12;
        w016[i] = bfrne(c0w[(mt*16 + (ln&15))*384 + kt*32 + (ln>>4)*8 + j]);
        return; }                                       i -= 147456;
    if(i < 12288){
        int j = i&7, ln = (i>>3)&63, f2 = i>>9, mt = f2/12, kt = f2 - mt*12;
        w116[i] = bfrne(c1w[(mt*16 + (ln&15))*384 + kt*32 + (ln>>4)*8 + j]);
        return; }                                       i -= 12288;
    if(i < 12288){
        int j = i&7, ln = (i>>3)&63, f2 = i>>9, mt = f2/12, kt = f2 - mt*12;
        wcsh[i] = bfrne(csw[(mt*16 + (ln&15))*384 + kt*32 + (ln>>4)*8 + j]);
        return; }                                       i -= 12288;
    if(i < 12288){
        int j = i&7, ln = (i>>3)&63, f2 = i>>9, mt = f2/12, kt = f2 - mt*12;
        float w = csw[(mt*16 + (ln&15))*384 + kt*32 + (ln>>4)*8 + j];
        unsigned short hh = bfrne(w);
        wcsl[i] = bfrne(w - bf2f(hh)); return; }
}

// ---------------- out_embs[0] = in_conv(x) ----------------
__global__ __launch_bounds__(256) void k_out0(const float* __restrict__ x,
    const float* __restrict__ w, const float* __restrict__ b, float* __restrict__ out0)
{
    int i = blockIdx.x*256 + threadIdx.x;
    int p = i & 4095, o = (i>>12)&31, bb = i>>17;
    const float* xb = x + (size_t)bb*12288 + p;
    out0[i] = b[o] + w[o*3]*xb[0] + w[o*3+1]*xb[4096] + w[o*3+2]*xb[8192];
}

// ---------------- latent chain (f32, deterministic partial sums) --------------
__global__ __launch_bounds__(256) void k_latA(const float* __restrict__ lat,
    const float* __restrict__ Ws, const float* __restrict__ W0,
    float* __restrict__ ppS, float* __restrict__ ppH)
{
    __shared__ float ls[8][128];
    int t = threadIdx.x;
    int kb = blockIdx.y*128;
    for(int i=t;i<1024;i+=256) ls[i>>7][i&127] = lat[(i>>7)*512 + kb + (i&127)];
    __syncthreads();
    const float* W = blockIdx.z ? W0 : Ws;
    float* pp = blockIdx.z ? ppH : ppS;
    int j = blockIdx.x*128 + (t&127);
    int half = t>>7, klo = half*64;
    int p = blockIdx.y*2 + half;
    float acc[8] = {0,0,0,0,0,0,0,0};
    for(int kk=0;kk<64;kk++){
        float wv_ = W[(size_t)(kb+klo+kk)*512 + j];
        #pragma unroll
        for(int m=0;m<8;m++) acc[m] += ls[m][klo+kk]*wv_;
    }
    #pragma unroll
    for(int m=0;m<8;m++) pp[(size_t)(p*8+m)*512 + j] = acc[m];
}

__global__ __launch_bounds__(256) void k_latBC(const float* __restrict__ ppH,
    const float* __restrict__ flb0c,
    const float* __restrict__ W1, const float* __restrict__ b1c,
    const float* __restrict__ latc, const float* __restrict__ ppS,
    const float* __restrict__ flbsc, float* __restrict__ latn)
{
    __shared__ float lh[8][512];
    __shared__ float part[8][128];
    int t = threadIdx.x;
    for(int i=t;i<4096;i+=256){
        int m = i>>9, jj = i&511;
        float v = flb0c[jj];
        #pragma unroll
        for(int p=0;p<8;p++) v += ppH[(size_t)(p*8+m)*512 + jj];
        lh[m][jj] = lrelu(v);
    }
    __syncthreads();
    int j = blockIdx.x*128 + (t&127), half = t>>7;
    float acc[8] = {0,0,0,0,0,0,0,0};
    int k0 = half*256;
    for(int kk=k0;kk<k0+256;kk++){
        float w = W1[(size_t)kk*512 + j];
        #pragma unroll
        for(int m=0;m<8;m++) acc[m] += lh[m][kk]*w;
    }
    if(half==1){
        #pragma unroll
        for(int m=0;m<8;m++) part[m][t&127] = acc[m];
    }
    __syncthreads();
    if(half==0){
        #pragma unroll
        for(int m=0;m<8;m++){
            float sv = flbsc[j];
            #pragma unroll
            for(int p=0;p<8;p++) sv += ppS[(size_t)(p*8+m)*512 + j];
            float t1 = acc[m] + part[m][t&127] + b1c[j];
            latn[m*512+j] = latc[m*512+j] + 0.1f*sv + 0.01f*t1;
        }
    }
}

// ---------------- DK hidden partials (deterministic) --------------------------
__global__ __launch_bounds__(256) void k_dkH(const float* __restrict__ latsAll,
    const float* __restrict__ W0, float* __restrict__ ppD)
{
    __shared__ float ls[64][128];
    int t = threadIdx.x;
    int kb = blockIdx.y*128;
    for(int i=t;i<8192;i+=256) ls[i>>7][i&127] = latsAll[(i>>7)*512 + kb + (i&127)];
    __syncthreads();
    int j = blockIdx.x*128 + (t&127);
    int ksub = t>>7;
    int p = blockIdx.y*2 + ksub;
    for(int mc=0;mc<4;mc++){
        float acc[16] = {0,0,0,0,0,0,0,0,0,0,0,0,0,0,0,0};
        for(int kk=0;kk<64;kk++){
            float wv_ = W0[(size_t)(kb + ksub*64 + kk)*1024 + j];
            #pragma unroll
            for(int mi=0;mi<16;mi++) acc[mi] += ls[mc*16+mi][ksub*64+kk]*wv_;
        }
        #pragma unroll
        for(int mi=0;mi<16;mi++) ppD[(size_t)(p*64 + mc*16+mi)*1024 + j] = acc[mi];
    }
}

__global__ __launch_bounds__(256) void k_dkAcvt(const float* __restrict__ latsAll,
    const float* __restrict__ ppD, const float* __restrict__ dkb0,
    unsigned short* __restrict__ Ahi, unsigned short* __restrict__ Alo)
{
    int i = blockIdx.x*256 + threadIdx.x;
    int m = i/1536, k = i - m*1536;
    float v;
    if(k < 512) v = latsAll[m*512 + k];
    else {
        int j = k - 512;
        float hv = dkb0[j];
        #pragma unroll
        for(int p=0;p<8;p++) hv += ppD[(size_t)(p*64+m)*1024 + j];
        v = 0.1f*lrelu(hv);
    }
    unsigned short hh = bfrne(v);
    Ahi[i] = hh; Alo[i] = bfrne(v - bf2f(hh));
}

// ---------------- KS = A @ [dkWs ; dkW1] + bias (LDS-staged GEMM) -------------
__global__ __launch_bounds__(256) void k_dkMain(const unsigned short* __restrict__ Ahi,
    const unsigned short* __restrict__ Alo,
    const float* __restrict__ Wsb, const float* __restrict__ W1b,
    const float* __restrict__ bs, const float* __restrict__ b1,
    unsigned short* __restrict__ KShi, unsigned short* __restrict__ KSlo,
    float* __restrict__ KSb32)
{
    __shared__ unsigned short Wh[64][138];
    __shared__ unsigned short Wl[64][138];
    __shared__ unsigned short Ah[64][72];
    __shared__ unsigned short Al[64][72];
    int t = threadIdx.x, wv = t>>6, lane = t&63, l15 = lane&15, lg = lane>>4, lkb = lg*8;
    int n0 = blockIdx.x*128;
    int sk = t>>5, sc = (t&31)*4;
    int am = t>>2, ac = (t&3)*16;

    f32x4 wreg[8];
    s16x8 ah0, ah1, al0, al1;
    {
        #pragma unroll
        for(int s=0;s<8;s++)
            wreg[s] = *(const f32x4*)(Wsb + (size_t)(sk + s*8)*DKT + n0 + sc);
        const unsigned short* Abh = Ahi + am*1536 + ac;
        const unsigned short* Abl = Alo + am*1536 + ac;
        ah0 = *(const s16x8*)(Abh);     ah1 = *(const s16x8*)(Abh + 8);
        al0 = *(const s16x8*)(Abl);     al1 = *(const s16x8*)(Abl + 8);
    }

    f32x4 acc[4][2];
    #pragma unroll
    for(int mt=0;mt<4;mt++){ acc[mt][0]=f32x4{0,0,0,0}; acc[mt][1]=f32x4{0,0,0,0}; }

    for(int kt=0;kt<24;kt++){
        #pragma unroll
        for(int s=0;s<8;s++){
            int k = sk + s*8;
            unsigned short hh[4], ll[4];
            #pragma unroll
            for(int e=0;e<4;e++){
                float w = wreg[s][e];
                hh[e] = bfrne(w); ll[e] = bfrne(w - bf2f(hh[e]));
            }
            *(unsigned*)(&Wh[k][sc])   = (unsigned)hh[0] | ((unsigned)hh[1]<<16);
            *(unsigned*)(&Wh[k][sc+2]) = (unsigned)hh[2] | ((unsigned)hh[3]<<16);
            *(unsigned*)(&Wl[k][sc])   = (unsigned)ll[0] | ((unsigned)ll[1]<<16);
            *(unsigned*)(&Wl[k][sc+2]) = (unsigned)ll[2] | ((unsigned)ll[3]<<16);
        }
        *(s16x8*)(&Ah[am][ac]) = ah0;  *(s16x8*)(&Ah[am][ac+8]) = ah1;
        *(s16x8*)(&Al[am][ac]) = al0;  *(s16x8*)(&Al[am][ac+8]) = al1;
        __syncthreads();
        if(kt < 23){
            int kn = kt+1;
            const float* Wb = (kn<8) ? (Wsb + (size_t)(kn*64)*DKT)
                                     : (W1b + (size_t)(kn*64-512)*DKT);
            #pragma unroll
            for(int s=0;s<8;s++)
                wreg[s] = *(const f32x4*)(Wb + (size_t)(sk + s*8)*DKT + n0 + sc);
            const unsigned short* Abh = Ahi + am*1536 + kn*64 + ac;
            const unsigned short* Abl = Alo + am*1536 + kn*64 + ac;
            ah0 = *(const s16x8*)(Abh);     ah1 = *(const s16x8*)(Abh + 8);
            al0 = *(const s16x8*)(Abl);     al1 = *(const s16x8*)(Abl + 8);
        }
        #pragma unroll
        for(int ks=0;ks<2;ks++){
            s16x8 afh[4], afl[4];
            #pragma unroll
            for(int mt=0;mt<4;mt++){
                afh[mt] = *(const s16x8*)(&Ah[mt*16+l15][ks*32+lkb]);
                afl[mt] = *(const s16x8*)(&Al[mt*16+l15][ks*32+lkb]);
            }
            #pragma unroll
            for(int nt=0;nt<2;nt++){
                int col = wv*32 + nt*16 + l15;
                FragU bh, bl;
                #pragma unroll
                for(int j=0;j<8;j++){
                    bh.h[j] = Wh[ks*32+lkb+j][col];
                    bl.h[j] = Wl[ks*32+lkb+j][col];
                }
                #pragma unroll
                for(int mt=0;mt<4;mt++){
                    acc[mt][nt] = mfma16(afh[mt], bh.v, acc[mt][nt]);
                    acc[mt][nt] = mfma16(afh[mt], bl.v, acc[mt][nt]);
                    acc[mt][nt] = mfma16(afl[mt], bh.v, acc[mt][nt]);
                }
            }
        }
        __syncthreads();
    }
    #pragma unroll
    for(int nt=0;nt<2;nt++){
        int n = n0 + wv*32 + nt*16 + l15;
        float bias = bs[n] + 0.1f*b1[n];
        #pragma unroll
        for(int mt=0;mt<4;mt++)
            #pragma unroll
            for(int q=0;q<4;q++){
                int row = mt*16 + lg*4 + q;
                float v = acc[mt][nt][q] + bias;
                unsigned short hh = bfrne(v);
                KShi[(size_t)row*DKT + n] = hh;
                KSlo[(size_t)row*DKT + n] = bfrne(v - bf2f(hh));
                if(n >= 110592) KSb32[(size_t)row*1152 + (n - 110592)] = v;
            }
    }
}

// ---------------- repack KS into frag-major -----------------------------------
__global__ __launch_bounds__(256) void k_ksperm(const unsigned short* __restrict__ KShi,
    const unsigned short* __restrict__ KSlo,
    unsigned short* __restrict__ KSfh, unsigned short* __restrict__ KSfl)
{
    int idx = blockIdx.x*256 + threadIdx.x;     // < 884736
    int lane = idx & 63;
    int q    = idx >> 6;
    int f    = q % 18;       q /= 18;
    int L    = q % 3;        q /= 3;
    int g    = q % 4;
    int r    = q / 4;
    int mt = f/3, kt = f - mt*3;
    size_t src = (size_t)r*DKT + L*36864 + g*9216
               + (mt*16 + (lane&15))*96 + kt*32 + (lane>>4)*8;
    *(s16x8*)(KSfh + (size_t)idx*8) = *(const s16x8*)(KShi + src);
    *(s16x8*)(KSfl + (size_t)idx*8) = *(const s16x8*)(KSlo + src);
}

// ---------------- stats ----------------
__global__ __launch_bounds__(256) void k_stat(const float* __restrict__ outPrev,
    float2* __restrict__ stats)
{
    __shared__ float img[4096], va[4096], vb[4096];
    __shared__ float ct[17], stp[17];
    __shared__ float red[8];
    int t = threadIdx.x, ch = blockIdx.x, b = blockIdx.y;
    const float* src = outPrev + ((size_t)b*32 + ch)*4096;
    float2* stc = stats + (b*32 + ch)*9;
    for(int i=t;i<4096;i+=256) img[i] = src[i];
    __syncthreads();
    float s0=0.f, s1=0.f;
    for(int i=t;i<4096;i+=256){ float v=img[i]; s0+=v; s1+=v*v; }
    blk_reduce2(s0, s1, red);
    float mu = s0*(1.f/4096.f);
    float var = s1*(1.f/4096.f) - mu*mu; var = var<0.f?0.f:var;
    if(t==0) stc[0] = make_float2(mu, rsqrtf(var + 1e-5f));
    const int ksz[4] = {3,5,9,17};
    for(int s=0;s<4;s++){
        int k = ksz[s], p = (k-1)>>1;
        if(t < k){
            float cc = -1.f + 2.f*(float)t/(float)(k-1);
            ct[t]  = cosf(1.5707963267948966f*cc);
            stp[t] = sinf(1.5707963267948966f*cc);
        }
        __syncthreads();
        for(int i=t;i<4096;i+=256){
            int y = i>>6, x = i&63; float ac=0.f, as=0.f;
            for(int tt=0;tt<k;tt++){
                int yy = y+tt-p;
                if(yy>=0 && yy<64){ float f = img[yy*64+x]; ac += ct[tt]*f; as += stp[tt]*f; }
            }
            va[i]=ac; vb[i]=as;
        }
        __syncthreads();
        float gx0=0.f,gx1=0.f,gy0=0.f,gy1=0.f;
        for(int i=t;i<4096;i+=256){
            int y=i>>6, x=i&63; float gx=0.f, gy=0.f;
            for(int tt=0;tt<k;tt++){
                int xx = x+tt-p;
                if(xx>=0 && xx<64){ gx += stp[tt]*va[y*64+xx]; gy += ct[tt]*vb[y*64+xx]; }
            }
            gx0+=gx; gx1+=gx*gx; gy0+=gy; gy1+=gy*gy;
        }
        blk_reduce2(gx0, gx1, red);
        blk_reduce2(gy0, gy1, red);
        float mgx = gx0*(1.f/4096.f), vgx = gx1*(1.f/4096.f)-mgx*mgx; vgx=vgx<0.f?0.f:vgx;
        float mgy = gy0*(1.f/4096.f), vgy = gy1*(1.f/4096.f)-mgy*mgy; vgy=vgy<0.f?0.f:vgy;
        if(t==0){
            stc[1+2*s] = make_float2(mgx, rsqrtf(vgx+1e-5f));
            stc[2+2*s] = make_float2(mgy, rsqrtf(vgy+1e-5f));
        }
        __syncthreads();
    }
}

// ---------------- MEGA: znorm + dyna + res_block fused, z/zz in LDS -----------
// block = (y row, b). 256 threads. LDS ~151 KB -> 1 block/CU.
// phase 1 (cooperative): normalize id/gx/gy into zt LDS (hi/lo)
// phase 2+3 (wave-local): dyna 4 groups for this wave's 16 px; res_block; out.
__global__ __launch_bounds__(256) void k_mega(const float* __restrict__ outPrev,
    const float2* __restrict__ stats,
    const unsigned short* __restrict__ KSfh, const unsigned short* __restrict__ KSfl,
    const float* __restrict__ KSb32,
    const unsigned short* __restrict__ w016, const unsigned short* __restrict__ w116,
    const unsigned short* __restrict__ wcsh, const unsigned short* __restrict__ wcsl,
    const float* __restrict__ c0b, const float* __restrict__ c1b,
    const float* __restrict__ csb,
    float* __restrict__ outNext, int cCall)
{
    __shared__ __align__(16) unsigned short zth[12][64][32];   // 48 KB
    __shared__ __align__(16) unsigned short ztl[12][64][32];   // 48 KB
    __shared__ __align__(16) unsigned short lh[4][2][2][16][100]; // 50 KB (dyna h; reused as resb dx1)
    __shared__ float va[4][80], vb[4][80];
    __shared__ float ct[17], stp[17];
    __shared__ float2 sst[288];
    int t = threadIdx.x, x = t&63, cq = t>>6;
    int y = blockIdx.x, b = blockIdx.y;
    const float* ob = outPrev + (size_t)b*131072;
    for(int i=t;i<288;i+=256) sst[i] = stats[b*288 + i];
    if(x < 16){
        int xp2 = (x<8) ? x : (x+64);
        va[cq][xp2] = 0.f; vb[cq][xp2] = 0.f;
    }
    __syncthreads();
    // ---- phase 1a: identity part -> parts 0,3,6,9 ----
    #pragma unroll
    for(int i=0;i<8;i++){
        int ch = cq*8 + i;
        float v = ob[(size_t)ch*4096 + y*64 + x];
        float2 sr = sst[ch*9];
        float z = (v - sr.x)*sr.y;
        unsigned short hh = bfrne(z), hl = bfrne(z - bf2f(hh));
        #pragma unroll
        for(int s=0;s<4;s++){ zth[3*s][x][ch] = hh; ztl[3*s][x][ch] = hl; }
    }
    // ---- phase 1b: gx/gy parts ----
    const int ksz[4] = {3,5,9,17};
    for(int s=0;s<4;s++){
        int k = ksz[s], p = (k-1)>>1, off = 8-p;
        __syncthreads();                 // all waves done with previous ct/stp
        if(t < k){
            float cc = -1.f + 2.f*(float)t/(float)(k-1);
            ct[t]  = cosf(1.5707963267948966f*cc);
            stp[t] = sinf(1.5707963267948966f*cc);
        }
        __syncthreads();
        #pragma unroll 1
        for(int i=0;i<8;i++){
            int ch = cq*8 + i;
            const float* oc = ob + (size_t)ch*4096;
            float ac=0.f, as=0.f;
            for(int tt=0;tt<k;tt++){
                int yy = y+tt-p;
                if(yy>=0 && yy<64){ float f = oc[yy*64 + x]; ac += ct[tt]*f; as += stp[tt]*f; }
            }
            va[cq][x+8] = ac; vb[cq][x+8] = as;
            __builtin_amdgcn_wave_barrier();
            float gx=0.f, gy=0.f;
            for(int tt=0;tt<k;tt++){
                gx += stp[tt]*va[cq][x+tt+off];
                gy += ct[tt]*vb[cq][x+tt+off];
            }
            __builtin_amdgcn_wave_barrier();
            float2 sx = sst[ch*9 + 1+2*s], sy = sst[ch*9 + 2+2*s];
            float zx = (gx - sx.x)*sx.y, zy = (gy - sy.x)*sy.y;
            unsigned short hx = bfrne(zx), hy = bfrne(zy);
            zth[3*s+1][x][ch] = hx; ztl[3*s+1][x][ch] = bfrne(zx - bf2f(hx));
            zth[3*s+2][x][ch] = hy; ztl[3*s+2][x][ch] = bfrne(zy - bf2f(hy));
        }
    }
    __syncthreads();    // all z in LDS before cross-wave consumption

    // ---- phase 2: dyna (wave-local px = wv*16+l15, loop over 4 groups) ----
    int lane = t&63, l15 = lane&15, lg = lane>>4, lkb = lg*8, wv = cq;
    int row = cCall*8 + b;
    int pxl = wv*16 + l15;     // local px for B-frags / gate / resb
    for(int g=0; g<4; g++){
        const unsigned short* Kfh = KSfh + (size_t)((row*4 + g)*3)*9216;
        const unsigned short* Kfl = KSfl + (size_t)((row*4 + g)*3)*9216;
        const float* Bf = KSb32 + (size_t)row*1152 + g*96;

        f32x4 acc[6];
        // layer 1: B from zt LDS
        #pragma unroll
        for(int mt=0;mt<6;mt++) acc[mt]=f32x4{0,0,0,0};
        #pragma unroll
        for(int kt=0;kt<3;kt++){
            s16x8 bh = *(const s16x8*)(&zth[g*3+kt][pxl][lkb]);
            s16x8 bl = *(const s16x8*)(&ztl[g*3+kt][pxl][lkb]);
            #pragma unroll
            for(int mt=0;mt<6;mt++){
                s16x8 ah = *(const s16x8*)(Kfh + ((mt*3+kt)*64 + lane)*8);
                s16x8 al = *(const s16x8*)(Kfl + ((mt*3+kt)*64 + lane)*8);
                acc[mt] = mfma16(ah, bh, acc[mt]);
                acc[mt] = mfma16(ah, bl, acc[mt]);
                acc[mt] = mfma16(al, bh, acc[mt]);
            }
        }
        #pragma unroll
        for(int mt=0;mt<6;mt++){
            int o0 = mt*16 + lg*4;
            f32x4 bb = *(const f32x4*)(Bf + o0);
            U4 hh, hl;
            #pragma unroll
            for(int q=0;q<4;q++){
                float v = lrelu(acc[mt][q] + bb[q]);
                hh.h[q] = bfrne(v); hl.h[q] = bfrne(v - bf2f(hh.h[q]));
            }
            *(s16x4*)(&lh[wv][0][0][l15][o0]) = hh.v;
            *(s16x4*)(&lh[wv][0][1][l15][o0]) = hl.v;
        }
        // layer 2
        #pragma unroll
        for(int mt=0;mt<6;mt++) acc[mt]=f32x4{0,0,0,0};
        #pragma unroll
        for(int kt=0;kt<3;kt++){
            s16x8 bh = *(const s16x8*)(&lh[wv][0][0][l15][kt*32+lkb]);
            s16x8 bl = *(const s16x8*)(&lh[wv][0][1][l15][kt*32+lkb]);
            #pragma unroll
            for(int mt=0;mt<6;mt++){
                s16x8 ah = *(const s16x8*)(Kfh + 9216 + ((mt*3+kt)*64 + lane)*8);
                s16x8 al = *(const s16x8*)(Kfl + 9216 + ((mt*3+kt)*64 + lane)*8);
                acc[mt] = mfma16(ah, bh, acc[mt]);
                acc[mt] = mfma16(ah, bl, acc[mt]);
                acc[mt] = mfma16(al, bh, acc[mt]);
            }
        }
        #pragma unroll
        for(int mt=0;mt<6;mt++){
            int o0 = mt*16 + lg*4;
            f32x4 bb = *(const f32x4*)(Bf + 384 + o0);
            U4 hh, hl;
            #pragma unroll
            for(int q=0;q<4;q++){
                float v = lrelu(acc[mt][q] + bb[q]);
                hh.h[q] = bfrne(v); hl.h[q] = bfrne(v - bf2f(hh.h[q]));
            }
            *(s16x4*)(&lh[wv][1][0][l15][o0]) = hh.v;
            *(s16x4*)(&lh[wv][1][1][l15][o0]) = hl.v;
        }
        // layer 3 + gate (zz hi written back into zth)
        #pragma unroll
        for(int mt=0;mt<6;mt++) acc[mt]=f32x4{0,0,0,0};
        #pragma unroll
        for(int kt=0;kt<3;kt++){
            s16x8 bh = *(const s16x8*)(&lh[wv][1][0][l15][kt*32+lkb]);
            s16x8 bl = *(const s16x8*)(&lh[wv][1][1][l15][kt*32+lkb]);
            #pragma unroll
            for(int mt=0;mt<6;mt++){
                s16x8 ah = *(const s16x8*)(Kfh + 18432 + ((mt*3+kt)*64 + lane)*8);
                s16x8 al = *(const s16x8*)(Kfl + 18432 + ((mt*3+kt)*64 + lane)*8);
                acc[mt] = mfma16(ah, bh, acc[mt]);
                acc[mt] = mfma16(ah, bl, acc[mt]);
                acc[mt] = mfma16(al, bh, acc[mt]);
            }
        }
        #pragma unroll
        for(int mt=0;mt<6;mt++){
            int o0 = mt*16 + lg*4;
            f32x4 bb = *(const f32x4*)(Bf + 768 + o0);
            int part = g*3 + (o0>>5), cc = o0&31;
            U4 zvh, zvl;
            zvh.v = *(const s16x4*)(&zth[part][pxl][cc]);
            zvl.v = *(const s16x4*)(&ztl[part][pxl][cc]);
            U4 ozh;
            #pragma unroll
            for(int q=0;q<4;q++){
                float zf = bf2f(zvh.h[q]) + bf2f(zvl.h[q]);
                float d  = zf + acc[mt][q] + bb[q];
                float sg = 1.f/(1.f + __expf(-d));
                ozh.h[q] = bfrne(zf*sg);
            }
            *(s16x4*)(&zth[part][pxl][cc]) = ozh.v;   // zz (hi only)
        }
    }

    // ---- phase 3: res_block (wave-local; dx1 reuses lh storage) ----
    unsigned short* ldx = (unsigned short*)lh + wv*6400;   // [16 px][392] fits in lh[wv]
    f32x4 a1[24];
    #pragma unroll
    for(int mt=0;mt<24;mt++) a1[mt]=f32x4{0,0,0,0};
    #pragma unroll 1
    for(int kt=0;kt<12;kt++){
        FragU bzh, blz;
        bzh.v = *(const s16x8*)(&zth[kt][pxl][lkb]);
        #pragma unroll
        for(int j=0;j<8;j++) blz.h[j] = bfrne(lrelu(bf2f(bzh.h[j])));
        #pragma unroll
        for(int mt=0;mt<24;mt++){
            s16x8 af = *(const s16x8*)(w016 + ((size_t)(mt*12+kt)<<9) + (lane<<3));
            a1[mt] = mfma16(af, blz.v, a1[mt]);
        }
    }
    #pragma unroll
    for(int mt=0;mt<24;mt++){
        int o0 = mt*16 + lg*4;
        f32x4 bb = *(const f32x4*)(c0b + o0);
        U4 hv;
        #pragma unroll
        for(int q=0;q<4;q++) hv.h[q] = bfrne(lrelu(a1[mt][q] + bb[q]));
        *(s16x4*)(ldx + l15*392 + o0) = hv.v;
    }
    f32x4 a2[2] = {f32x4{0,0,0,0}, f32x4{0,0,0,0}};
    f32x4 a3[2] = {f32x4{0,0,0,0}, f32x4{0,0,0,0}};
    #pragma unroll 1
    for(int kt=0;kt<12;kt++){
        s16x8 bh_ = *(const s16x8*)(ldx + l15*392 + kt*32 + lkb);
        s16x8 bzh = *(const s16x8*)(&zth[kt][pxl][lkb]);
        #pragma unroll
        for(int mt=0;mt<2;mt++){
            s16x8 af1 = *(const s16x8*)(w116 + ((size_t)(mt*12+kt)<<9) + (lane<<3));
            a2[mt] = mfma16(af1, bh_, a2[mt]);
            s16x8 wh = *(const s16x8*)(wcsh + ((size_t)(mt*12+kt)<<9) + (lane<<3));
            s16x8 wl = *(const s16x8*)(wcsl + ((size_t)(mt*12+kt)<<9) + (lane<<3));
            a3[mt] = mfma16(wh, bzh, a3[mt]);
            a3[mt] = mfma16(wl, bzh, a3[mt]);
        }
    }
    #pragma unroll
    for(int mt=0;mt<2;mt++){
        int o0 = mt*16 + lg*4;
        #pragma unroll
        for(int q=0;q<4;q++){
            int o = o0+q;
            int px = y*64 + pxl;
            float dx2 = a2[mt][q] + c1b[o];
            float r   = a3[mt][q] + csb[o] + 0.1f*dx2;
            size_t oidx = (size_t)b*131072 + (size_t)o*4096 + px;
            outNext[oidx] = outPrev[oidx] + 0.1f*r;
        }
    }
}

// ---------------- head ----------------
__global__ __launch_bounds__(256) void k_head1(const float* __restrict__ outF,
    const float* __restrict__ wout, const float* __restrict__ bout, float* __restrict__ state)
{
    __shared__ float sw[97*32];
    __shared__ float sb_[97];
    __shared__ float fp[32];
    __shared__ float fwp[2048];
    int t = threadIdx.x, b = blockIdx.y, pxb = blockIdx.x*256;
    for(int i=t;i<97*32;i+=256) sw[i] = wout[i];
    if(t<97) sb_[t] = bout[t];
    if(t<32) fp[t] = 0.f;
    for(int i=t;i<2048;i+=256) fwp[i] = 0.f;
    __syncthreads();
    int px = pxb + t, lane = t&63, wv = t>>6;
    float xi[32];
    #pragma unroll
    for(int i=0;i<32;i++) xi[i] = outF[(size_t)b*131072 + (size_t)i*4096 + px];
    float* st = state + (size_t)b*8224;
    int row = (pxb>>6) + wv, x = lane;
    for(int o=0;o<97;o++){
        float acc = sb_[o];
        #pragma unroll
        for(int i=0;i<32;i++) acc += sw[o*32+i]*xi[i];
        if(o < 32){
            float s = wave_sum(acc);
            if(lane==0) atomicAdd(&fp[o], s);
        } else if(o < 64){
            float s = wave_sum(acc);
            if(lane==0) st[32 + (o-32)*64 + row] = s*(1.f/64.f);
        } else if(o < 96){
            atomicAdd(&fwp[(o-64)*64 + x], acc);
        } else {
            st[4128 + px] = acc;
        }
    }
    __syncthreads();
    if(t<32) atomicAdd(&st[t], fp[t]*(1.f/4096.f));
    for(int i=t;i<2048;i+=256) atomicAdd(&st[2080+i], fwp[i]*(1.f/64.f));
}

__global__ __launch_bounds__(256) void k_head2(const float* __restrict__ state,
    const float* __restrict__ otlw, float* __restrict__ latout)
{
    __shared__ float ss[8*514];
    int t = threadIdx.x, j = blockIdx.x*256 + t, s0 = blockIdx.y*514;
    for(int i=t;i<8*514;i+=256){ int bb=i/514, si=i-bb*514; ss[i] = state[(size_t)bb*8224 + s0 + si]; }
    __syncthreads();
    float acc[8] = {0,0,0,0,0,0,0,0};
    for(int si=0;si<514;si++){
        float wv_ = otlw[(size_t)(s0+si)*512 + j];
        #pragma unroll
        for(int b2=0;b2<8;b2++) acc[b2] += ss[b2*514+si]*wv_;
    }
    #pragma unroll
    for(int b2=0;b2<8;b2++) atomicAdd(latout + b2*512 + j, acc[b2]);
}

// =============================================================================
extern "C" void kernel_launch(void* const* d_in, const int* in_sizes, int n_in,
                              void* d_out, int out_size, void* d_ws, size_t ws_size,
                              hipStream_t stream)
{
    const float* x    = (const float*)d_in[0];
    const float* inj  = (const float*)d_in[1];
    const float* icw  = (const float*)d_in[2];
    const float* icb  = (const float*)d_in[3];
    const float* flWs = (const float*)d_in[4];
    const float* flbs = (const float*)d_in[5];
    const float* flW0 = (const float*)d_in[6];
    const float* flb0 = (const float*)d_in[7];
    const float* flW1 = (const float*)d_in[8];
    const float* flb1 = (const float*)d_in[9];
    const float* dkWs = (const float*)d_in[10];
    const float* dkbs = (const float*)d_in[11];
    const float* dkW0 = (const float*)d_in[12];
    const float* dkb0 = (const float*)d_in[13];
    const float* dkW1 = (const float*)d_in[14];
    const float* dkb1 = (const float*)d_in[15];
    const float* c0w  = (const float*)d_in[16];
    const float* c0b  = (const float*)d_in[17];
    const float* c1w  = (const float*)d_in[18];
    const float* c1b  = (const float*)d_in[19];
    const float* csw  = (const float*)d_in[20];
    const float* csb  = (const float*)d_in[21];
    const float* ocw  = (const float*)d_in[22];
    const float* ocb  = (const float*)d_in[23];
    const float* otlw = (const float*)d_in[24];
    const float* otlb = (const float*)d_in[25];
    float* out = (float*)d_out;

    char* wp = (char*)d_ws;
    auto carve = [&](size_t bytes)->void*{ void* p = wp; wp += (bytes + 255) & ~(size_t)255; return p; };
    float* lats  = (float*)carve(36864*4);
    float* ppS   = (float*)carve(32768*4);
    float* ppH   = (float*)carve(32768*4);
    float* ppD   = (float*)carve(524288*4);
    float* state = (float*)carve(65792*4);
    float2* stats = (float2*)carve(2304*8);
    unsigned short* Ahi   = (unsigned short*)carve((size_t)98304*2);
    unsigned short* Alo   = (unsigned short*)carve((size_t)98304*2);
    unsigned short* KShi  = (unsigned short*)carve((size_t)7151616*2);
    unsigned short* KSlo  = (unsigned short*)carve((size_t)7151616*2);
    unsigned short* KSfh  = (unsigned short*)carve((size_t)7077888*2);  // frag-major
    unsigned short* KSfl  = (unsigned short*)carve((size_t)7077888*2);
    float*          KSb32 = (float*)carve((size_t)73728*4);
    unsigned short* w016  = (unsigned short*)carve((size_t)147456*2);   // frag-major
    unsigned short* w116  = (unsigned short*)carve((size_t)12288*2);
    unsigned short* wcsh  = (unsigned short*)carve((size_t)12288*2);
    unsigned short* wcsl  = (unsigned short*)carve((size_t)12288*2);

    k_init<<<1009,256,0,stream>>>(state, out, otlb, lats, inj,
                                  w016, c0w, w116, c1w, wcsh, wcsl, csw);
    k_out0<<<4096,256,0,stream>>>(x, icw, icb, out + 4096);

    for(int c=0;c<8;c++){
        const float* latc = lats + c*4096;
        k_latA<<<dim3(4,4,2),256,0,stream>>>(latc, flWs + (size_t)c*262144, flW0 + (size_t)c*262144,
                                             ppS, ppH);
        k_latBC<<<4,256,0,stream>>>(ppH, flb0 + (size_t)c*512,
                                    flW1 + (size_t)c*262144, flb1 + (size_t)c*512,
                                    latc, ppS, flbs + (size_t)c*512, lats + (c+1)*4096);
    }

    k_dkH<<<dim3(8,4),256,0,stream>>>(lats + 4096, dkW0, ppD);
    k_dkAcvt<<<384,256,0,stream>>>(lats + 4096, ppD, dkb0, Ahi, Alo);
    k_dkMain<<<873,256,0,stream>>>(Ahi, Alo, dkWs, dkW1, dkbs, dkb1, KShi, KSlo, KSb32);
    k_ksperm<<<3456,256,0,stream>>>(KShi, KSlo, KSfh, KSfl);

    for(int c=0;c<8;c++){
        const float* outPrev = out + 4096 + (size_t)c*EMB;
        float*       outNext = out + 4096 + (size_t)(c+1)*EMB;
        k_stat<<<dim3(32,8),256,0,stream>>>(outPrev, stats);
        k_mega<<<dim3(64,8),256,0,stream>>>(outPrev, stats, KSfh, KSfl, KSb32,
                                            w016, w116, wcsh, wcsl,
                                            c0b, c1b, csb, outNext, c);
    }

    k_head1<<<dim3(16,8),256,0,stream>>>(out + 4096 + (size_t)8*EMB, ocw, ocb, state);
    k_head2<<<dim3(2,16),256,0,stream>>>(state, otlw, out);
}

// Round 9
// 3116.159 us; speedup vs baseline: 1.3091x; 1.0010x over previous
//
#include <hip/hip_runtime.h>

#define DEV __device__ __forceinline__

typedef __attribute__((ext_vector_type(4))) float  f32x4;
typedef __attribute__((ext_vector_type(8))) short  s16x8;   // 8 bf16 (MFMA frag)
typedef __attribute__((ext_vector_type(4))) short  s16x4;   // 4 bf16 (8B ld/st)

union FragU { s16x8 v; unsigned short h[8]; };
union U4    { s16x4 v; unsigned short h[4]; };

DEV float lrelu(float x){ return x > 0.f ? x : 0.2f*x; }
DEV unsigned short bfrne(float f){
    unsigned u = __builtin_bit_cast(unsigned, f);
    u += 0x7fffu + ((u>>16)&1u);
    return (unsigned short)(u>>16);
}
DEV float bf2f(unsigned short h){
    unsigned u = ((unsigned)h)<<16; return __builtin_bit_cast(float,u);
}
DEV f32x4 mfma16(s16x8 a, s16x8 b, f32x4 c){
    return __builtin_amdgcn_mfma_f32_16x16x32_bf16(a, b, c, 0, 0, 0);
}
DEV float wave_sum(float v){
    #pragma unroll
    for(int m=32;m>0;m>>=1) v += __shfl_xor(v, m, 64);
    return v;
}
DEV void blk_reduce2(float& a, float& b, float* sm){
    a = wave_sum(a); b = wave_sum(b);
    int wv = threadIdx.x>>6, ln = threadIdx.x&63;
    if(ln==0){ sm[wv*2]=a; sm[wv*2+1]=b; }
    __syncthreads();
    a = sm[0]+sm[2]+sm[4]+sm[6];
    b = sm[1]+sm[3]+sm[5]+sm[7];
    __syncthreads();
}

// ---------------- sizes ----------------
#define EMB   1048576               // 8*32*4096, one out_emb
#define DKT   111744

// ---------------- init (weights emitted FRAG-MAJOR) ---------------------------
__global__ __launch_bounds__(256) void k_init(
    float* state, float* latout, const float* otlb,
    float* lats, const float* inj,
    unsigned short* w016, const float* c0w,
    unsigned short* w116, const float* c1w,
    unsigned short* wcsh, unsigned short* wcsl, const float* csw)
{
    int i = blockIdx.x*256 + threadIdx.x;
    if(i < 65792){ state[i] = 0.f; return; }            i -= 65792;
    if(i < 4096){ latout[i] = otlb[i&511]; return; }    i -= 4096;
    if(i < 4096){ lats[i] = inj[i]; return; }           i -= 4096;
    if(i < 147456){
        int j = i&7, ln = (i>>3)&63, f2 = i>>9, mt = f2/12, kt = f2 - mt*12;
        w016[i] = bfrne(c0w[(mt*16 + (ln&15))*384 + kt*32 + (ln>>4)*8 + j]);
        return; }                                       i -= 147456;
    if(i < 12288){
        int j = i&7, ln = (i>>3)&63, f2 = i>>9, mt = f2/12, kt = f2 - mt*12;
        w116[i] = bfrne(c1w[(mt*16 + (ln&15))*384 + kt*32 + (ln>>4)*8 + j]);
        return; }                                       i -= 12288;
    if(i < 12288){
        int j = i&7, ln = (i>>3)&63, f2 = i>>9, mt = f2/12, kt = f2 - mt*12;
        wcsh[i] = bfrne(csw[(mt*16 + (ln&15))*384 + kt*32 + (ln>>4)*8 + j]);
        return; }                                       i -= 12288;
    if(i < 12288){
        int j = i&7, ln = (i>>3)&63, f2 = i>>9, mt = f2/12, kt = f2 - mt*12;
        float w = csw[(mt*16 + (ln&15))*384 + kt*32 + (ln>>4)*8 + j];
        unsigned short hh = bfrne(w);
        wcsl[i] = bfrne(w - bf2f(hh)); return; }
}

// ---------------- out_embs[0] = in_conv(x) ----------------
__global__ __launch_bounds__(256) void k_out0(const float* __restrict__ x,
    const float* __restrict__ w, const float* __restrict__ b, float* __restrict__ out0)
{
    int i = blockIdx.x*256 + threadIdx.x;
    int p = i & 4095, o = (i>>12)&31, bb = i>>17;
    const float* xb = x + (size_t)bb*12288 + p;
    out0[i] = b[o] + w[o*3]*xb[0] + w[o*3+1]*xb[4096] + w[o*3+2]*xb[8192];
}

// ---------------- latent chain (f32, deterministic; BITWISE-FROZEN) -----------
__global__ __launch_bounds__(256) void k_latA(const float* __restrict__ lat,
    const float* __restrict__ Ws, const float* __restrict__ W0,
    float* __restrict__ ppS, float* __restrict__ ppH)
{
    __shared__ float ls[8][128];
    int t = threadIdx.x;
    int kb = blockIdx.y*128;
    for(int i=t;i<1024;i+=256) ls[i>>7][i&127] = lat[(i>>7)*512 + kb + (i&127)];
    __syncthreads();
    const float* W = blockIdx.z ? W0 : Ws;
    float* pp = blockIdx.z ? ppH : ppS;
    int j = blockIdx.x*128 + (t&127);
    int half = t>>7, klo = half*64;
    int p = blockIdx.y*2 + half;
    float acc[8] = {0,0,0,0,0,0,0,0};
    for(int kk=0;kk<64;kk++){
        float wv_ = W[(size_t)(kb+klo+kk)*512 + j];
        #pragma unroll
        for(int m=0;m<8;m++) acc[m] += ls[m][klo+kk]*wv_;
    }
    #pragma unroll
    for(int m=0;m<8;m++) pp[(size_t)(p*8+m)*512 + j] = acc[m];
}

__global__ __launch_bounds__(256) void k_latBC(const float* __restrict__ ppH,
    const float* __restrict__ flb0c,
    const float* __restrict__ W1, const float* __restrict__ b1c,
    const float* __restrict__ latc, const float* __restrict__ ppS,
    const float* __restrict__ flbsc, float* __restrict__ latn)
{
    __shared__ float lh[8][512];
    __shared__ float part[8][128];
    int t = threadIdx.x;
    for(int i=t;i<4096;i+=256){
        int m = i>>9, jj = i&511;
        float v = flb0c[jj];
        #pragma unroll
        for(int p=0;p<8;p++) v += ppH[(size_t)(p*8+m)*512 + jj];
        lh[m][jj] = lrelu(v);
    }
    __syncthreads();
    int j = blockIdx.x*128 + (t&127), half = t>>7;
    float acc[8] = {0,0,0,0,0,0,0,0};
    int k0 = half*256;
    for(int kk=k0;kk<k0+256;kk++){
        float w = W1[(size_t)kk*512 + j];
        #pragma unroll
        for(int m=0;m<8;m++) acc[m] += lh[m][kk]*w;
    }
    if(half==1){
        #pragma unroll
        for(int m=0;m<8;m++) part[m][t&127] = acc[m];
    }
    __syncthreads();
    if(half==0){
        #pragma unroll
        for(int m=0;m<8;m++){
            float sv = flbsc[j];
            #pragma unroll
            for(int p=0;p<8;p++) sv += ppS[(size_t)(p*8+m)*512 + j];
            float t1 = acc[m] + part[m][t&127] + b1c[j];
            latn[m*512+j] = latc[m*512+j] + 0.1f*sv + 0.01f*t1;
        }
    }
}

// ---------------- DK hidden partials (deterministic; BITWISE-FROZEN) ----------
__global__ __launch_bounds__(256) void k_dkH(const float* __restrict__ latsAll,
    const float* __restrict__ W0, float* __restrict__ ppD)
{
    __shared__ float ls[64][128];
    int t = threadIdx.x;
    int kb = blockIdx.y*128;
    for(int i=t;i<8192;i+=256) ls[i>>7][i&127] = latsAll[(i>>7)*512 + kb + (i&127)];
    __syncthreads();
    int j = blockIdx.x*128 + (t&127);
    int ksub = t>>7;
    int p = blockIdx.y*2 + ksub;
    for(int mc=0;mc<4;mc++){
        float acc[16] = {0,0,0,0,0,0,0,0,0,0,0,0,0,0,0,0};
        for(int kk=0;kk<64;kk++){
            float wv_ = W0[(size_t)(kb + ksub*64 + kk)*1024 + j];
            #pragma unroll
            for(int mi=0;mi<16;mi++) acc[mi] += ls[mc*16+mi][ksub*64+kk]*wv_;
        }
        #pragma unroll
        for(int mi=0;mi<16;mi++) ppD[(size_t)(p*64 + mc*16+mi)*1024 + j] = acc[mi];
    }
}

__global__ __launch_bounds__(256) void k_dkAcvt(const float* __restrict__ latsAll,
    const float* __restrict__ ppD, const float* __restrict__ dkb0,
    unsigned short* __restrict__ Ahi, unsigned short* __restrict__ Alo)
{
    int i = blockIdx.x*256 + threadIdx.x;
    int m = i/1536, k = i - m*1536;
    float v;
    if(k < 512) v = latsAll[m*512 + k];
    else {
        int j = k - 512;
        float hv = dkb0[j];
        #pragma unroll
        for(int p=0;p<8;p++) hv += ppD[(size_t)(p*64+m)*1024 + j];
        v = 0.1f*lrelu(hv);
    }
    unsigned short hh = bfrne(v);
    Ahi[i] = hh; Alo[i] = bfrne(v - bf2f(hh));
}

// ---------------- KS GEMM; epilogue writes FRAG-MAJOR directly ----------------
__global__ __launch_bounds__(256) void k_dkMain(const unsigned short* __restrict__ Ahi,
    const unsigned short* __restrict__ Alo,
    const float* __restrict__ Wsb, const float* __restrict__ W1b,
    const float* __restrict__ bs, const float* __restrict__ b1,
    unsigned short* __restrict__ KSfh, unsigned short* __restrict__ KSfl,
    float* __restrict__ KSb32)
{
    __shared__ unsigned short Wh[64][138];
    __shared__ unsigned short Wl[64][138];
    __shared__ unsigned short Ah[64][72];
    __shared__ unsigned short Al[64][72];
    int t = threadIdx.x, wv = t>>6, lane = t&63, l15 = lane&15, lg = lane>>4, lkb = lg*8;
    int n0 = blockIdx.x*128;
    int sk = t>>5, sc = (t&31)*4;
    int am = t>>2, ac = (t&3)*16;

    f32x4 wreg[8];
    s16x8 ah0, ah1, al0, al1;
    {
        #pragma unroll
        for(int s=0;s<8;s++)
            wreg[s] = *(const f32x4*)(Wsb + (size_t)(sk + s*8)*DKT + n0 + sc);
        const unsigned short* Abh = Ahi + am*1536 + ac;
        const unsigned short* Abl = Alo + am*1536 + ac;
        ah0 = *(const s16x8*)(Abh);     ah1 = *(const s16x8*)(Abh + 8);
        al0 = *(const s16x8*)(Abl);     al1 = *(const s16x8*)(Abl + 8);
    }

    f32x4 acc[4][2];
    #pragma unroll
    for(int mt=0;mt<4;mt++){ acc[mt][0]=f32x4{0,0,0,0}; acc[mt][1]=f32x4{0,0,0,0}; }

    for(int kt=0;kt<24;kt++){
        #pragma unroll
        for(int s=0;s<8;s++){
            int k = sk + s*8;
            unsigned short hh[4], ll[4];
            #pragma unroll
            for(int e=0;e<4;e++){
                float w = wreg[s][e];
                hh[e] = bfrne(w); ll[e] = bfrne(w - bf2f(hh[e]));
            }
            *(unsigned*)(&Wh[k][sc])   = (unsigned)hh[0] | ((unsigned)hh[1]<<16);
            *(unsigned*)(&Wh[k][sc+2]) = (unsigned)hh[2] | ((unsigned)hh[3]<<16);
            *(unsigned*)(&Wl[k][sc])   = (unsigned)ll[0] | ((unsigned)ll[1]<<16);
            *(unsigned*)(&Wl[k][sc+2]) = (unsigned)ll[2] | ((unsigned)ll[3]<<16);
        }
        *(s16x8*)(&Ah[am][ac]) = ah0;  *(s16x8*)(&Ah[am][ac+8]) = ah1;
        *(s16x8*)(&Al[am][ac]) = al0;  *(s16x8*)(&Al[am][ac+8]) = al1;
        __syncthreads();
        if(kt < 23){
            int kn = kt+1;
            const float* Wb = (kn<8) ? (Wsb + (size_t)(kn*64)*DKT)
                                     : (W1b + (size_t)(kn*64-512)*DKT);
            #pragma unroll
            for(int s=0;s<8;s++)
                wreg[s] = *(const f32x4*)(Wb + (size_t)(sk + s*8)*DKT + n0 + sc);
            const unsigned short* Abh = Ahi + am*1536 + kn*64 + ac;
            const unsigned short* Abl = Alo + am*1536 + kn*64 + ac;
            ah0 = *(const s16x8*)(Abh);     ah1 = *(const s16x8*)(Abh + 8);
            al0 = *(const s16x8*)(Abl);     al1 = *(const s16x8*)(Abl + 8);
        }
        #pragma unroll
        for(int ks=0;ks<2;ks++){
            s16x8 afh[4], afl[4];
            #pragma unroll
            for(int mt=0;mt<4;mt++){
                afh[mt] = *(const s16x8*)(&Ah[mt*16+l15][ks*32+lkb]);
                afl[mt] = *(const s16x8*)(&Al[mt*16+l15][ks*32+lkb]);
            }
            #pragma unroll
            for(int nt=0;nt<2;nt++){
                int col = wv*32 + nt*16 + l15;
                FragU bh, bl;
                #pragma unroll
                for(int j=0;j<8;j++){
                    bh.h[j] = Wh[ks*32+lkb+j][col];
                    bl.h[j] = Wl[ks*32+lkb+j][col];
                }
                #pragma unroll
                for(int mt=0;mt<4;mt++){
                    acc[mt][nt] = mfma16(afh[mt], bh.v, acc[mt][nt]);
                    acc[mt][nt] = mfma16(afh[mt], bl.v, acc[mt][nt]);
                    acc[mt][nt] = mfma16(afl[mt], bh.v, acc[mt][nt]);
                }
            }
        }
        __syncthreads();
    }
    // epilogue: write frag-major (k_ksperm folded in; bitwise-identical values)
    #pragma unroll
    for(int nt=0;nt<2;nt++){
        int n = n0 + wv*32 + nt*16 + l15;
        float bias = bs[n] + 0.1f*b1[n];
        bool isW = (n < 110592);
        size_t colpart = 0; int nb2 = 0;
        if(isW){
            int L = n / 36864, rem = n - L*36864;
            int g = rem / 9216; int rem2 = rem - g*9216;
            int oo = rem2 / 96; int kk = rem2 - oo*96;
            int lane2 = (((kk&31)>>3)<<4) + (oo&15);
            int f = (oo>>4)*3 + (kk>>5);
            colpart = ((((size_t)(g*3 + L))*18 + f)*64 + lane2)*8 + (kk&7);
        } else nb2 = n - 110592;
        #pragma unroll
        for(int mt=0;mt<4;mt++)
            #pragma unroll
            for(int q=0;q<4;q++){
                int row = mt*16 + lg*4 + q;
                float v = acc[mt][nt][q] + bias;
                unsigned short hh = bfrne(v);
                if(isW){
                    size_t dst = (size_t)row*110592 + colpart;   // 13824*8
                    KSfh[dst] = hh;
                    KSfl[dst] = bfrne(v - bf2f(hh));
                } else {
                    KSb32[(size_t)row*1152 + nb2] = v;
                }
            }
    }
}

// ---------------- stats (BITWISE-FROZEN) ----------------
__global__ __launch_bounds__(256) void k_stat(const float* __restrict__ outPrev,
    float2* __restrict__ stats)
{
    __shared__ float img[4096], va[4096], vb[4096];
    __shared__ float ct[17], stp[17];
    __shared__ float red[8];
    int t = threadIdx.x, ch = blockIdx.x, b = blockIdx.y;
    const float* src = outPrev + ((size_t)b*32 + ch)*4096;
    float2* stc = stats + (b*32 + ch)*9;
    for(int i=t;i<4096;i+=256) img[i] = src[i];
    __syncthreads();
    float s0=0.f, s1=0.f;
    for(int i=t;i<4096;i+=256){ float v=img[i]; s0+=v; s1+=v*v; }
    blk_reduce2(s0, s1, red);
    float mu = s0*(1.f/4096.f);
    float var = s1*(1.f/4096.f) - mu*mu; var = var<0.f?0.f:var;
    if(t==0) stc[0] = make_float2(mu, rsqrtf(var + 1e-5f));
    const int ksz[4] = {3,5,9,17};
    for(int s=0;s<4;s++){
        int k = ksz[s], p = (k-1)>>1;
        if(t < k){
            float cc = -1.f + 2.f*(float)t/(float)(k-1);
            ct[t]  = cosf(1.5707963267948966f*cc);
            stp[t] = sinf(1.5707963267948966f*cc);
        }
        __syncthreads();
        for(int i=t;i<4096;i+=256){
            int y = i>>6, x = i&63; float ac=0.f, as=0.f;
            for(int tt=0;tt<k;tt++){
                int yy = y+tt-p;
                if(yy>=0 && yy<64){ float f = img[yy*64+x]; ac += ct[tt]*f; as += stp[tt]*f; }
            }
            va[i]=ac; vb[i]=as;
        }
        __syncthreads();
        float gx0=0.f,gx1=0.f,gy0=0.f,gy1=0.f;
        for(int i=t;i<4096;i+=256){
            int y=i>>6, x=i&63; float gx=0.f, gy=0.f;
            for(int tt=0;tt<k;tt++){
                int xx = x+tt-p;
                if(xx>=0 && xx<64){ gx += stp[tt]*va[y*64+xx]; gy += ct[tt]*vb[y*64+xx]; }
            }
            gx0+=gx; gx1+=gx*gx; gy0+=gy; gy1+=gy*gy;
        }
        blk_reduce2(gx0, gx1, red);
        blk_reduce2(gy0, gy1, red);
        float mgx = gx0*(1.f/4096.f), vgx = gx1*(1.f/4096.f)-mgx*mgx; vgx=vgx<0.f?0.f:vgx;
        float mgy = gy0*(1.f/4096.f), vgy = gy1*(1.f/4096.f)-mgy*mgy; vgy=vgy<0.f?0.f:vgy;
        if(t==0){
            stc[1+2*s] = make_float2(mgx, rsqrtf(vgx+1e-5f));
            stc[2+2*s] = make_float2(mgy, rsqrtf(vgy+1e-5f));
        }
        __syncthreads();
    }
}

// ---------------- MEGA v2: 512 threads (8 waves = 2/SIMD), bitwise-identical --
// wave w: pxslot = w&3 (16 px), half = w>>2.
// phase2: groups {2*half, 2*half+1}. phase3 G1: mt half. G2/G3: (pxslot, mt=half).
__global__ __launch_bounds__(512) void k_mega(const float* __restrict__ outPrev,
    const float2* __restrict__ stats,
    const unsigned short* __restrict__ KSfh, const unsigned short* __restrict__ KSfl,
    const float* __restrict__ KSb32,
    const unsigned short* __restrict__ w016, const unsigned short* __restrict__ w116,
    const unsigned short* __restrict__ wcsh, const unsigned short* __restrict__ wcsl,
    const float* __restrict__ c0b, const float* __restrict__ c1b,
    const float* __restrict__ csb,
    float* __restrict__ outNext, int cCall)
{
    __shared__ __align__(16) unsigned short zth[12][64][32];   // 48 KB
    __shared__ __align__(16) unsigned short ztl[12][64][32];   // 48 KB
    __shared__ __align__(16) unsigned short lhf[25600];        // 50 KB: 8x per-wave h (3200) / 4x ldx (6272)
    __shared__ float va[8][80], vb[8][80];
    __shared__ float ct[17], stp[17];
    __shared__ float2 sst[288];
    int t = threadIdx.x, x = t&63, cq = t>>6;     // cq = wave 0..7
    int y = blockIdx.x, b = blockIdx.y;
    const float* ob = outPrev + (size_t)b*131072;
    for(int i=t;i<288;i+=512) sst[i] = stats[b*288 + i];
    if(x < 16){
        int xp2 = (x<8) ? x : (x+64);
        va[cq][xp2] = 0.f; vb[cq][xp2] = 0.f;
    }
    __syncthreads();
    // ---- phase 1a: identity part -> parts 0,3,6,9 (4 ch per thread) ----
    #pragma unroll
    for(int i=0;i<4;i++){
        int ch = cq*4 + i;
        float v = ob[(size_t)ch*4096 + y*64 + x];
        float2 sr = sst[ch*9];
        float z = (v - sr.x)*sr.y;
        unsigned short hh = bfrne(z), hl = bfrne(z - bf2f(hh));
        #pragma unroll
        for(int s=0;s<4;s++){ zth[3*s][x][ch] = hh; ztl[3*s][x][ch] = hl; }
    }
    // ---- phase 1b: gx/gy parts ----
    const int ksz[4] = {3,5,9,17};
    for(int s=0;s<4;s++){
        int k = ksz[s], p = (k-1)>>1, off = 8-p;
        __syncthreads();
        if(t < k){
            float cc = -1.f + 2.f*(float)t/(float)(k-1);
            ct[t]  = cosf(1.5707963267948966f*cc);
            stp[t] = sinf(1.5707963267948966f*cc);
        }
        __syncthreads();
        #pragma unroll 1
        for(int i=0;i<4;i++){
            int ch = cq*4 + i;
            const float* oc = ob + (size_t)ch*4096;
            float ac=0.f, as=0.f;
            for(int tt=0;tt<k;tt++){
                int yy = y+tt-p;
                if(yy>=0 && yy<64){ float f = oc[yy*64 + x]; ac += ct[tt]*f; as += stp[tt]*f; }
            }
            va[cq][x+8] = ac; vb[cq][x+8] = as;
            __builtin_amdgcn_wave_barrier();
            float gx=0.f, gy=0.f;
            for(int tt=0;tt<k;tt++){
                gx += stp[tt]*va[cq][x+tt+off];
                gy += ct[tt]*vb[cq][x+tt+off];
            }
            __builtin_amdgcn_wave_barrier();
            float2 sx = sst[ch*9 + 1+2*s], sy = sst[ch*9 + 2+2*s];
            float zx = (gx - sx.x)*sx.y, zy = (gy - sy.x)*sy.y;
            unsigned short hx = bfrne(zx), hy = bfrne(zy);
            zth[3*s+1][x][ch] = hx; ztl[3*s+1][x][ch] = bfrne(zx - bf2f(hx));
            zth[3*s+2][x][ch] = hy; ztl[3*s+2][x][ch] = bfrne(zy - bf2f(hy));
        }
    }
    __syncthreads();    // all z in LDS

    // ---- phase 2: dyna. wave w: pxslot, 2 groups ----
    int lane = t&63, l15 = lane&15, lg = lane>>4, lkb = lg*8, w = cq;
    int pxslot = w&3, half = w>>2;
    int row = cCall*8 + b;
    int pxl = pxslot*16 + l15;
    unsigned short* lhh = &lhf[w*3200];          // [16][100]
    unsigned short* lhl = &lhf[w*3200 + 1600];
    #pragma unroll 1
    for(int gi=0; gi<2; gi++){
        int g = half*2 + gi;
        const unsigned short* Kfh = KSfh + (size_t)((row*4 + g)*3)*9216;
        const unsigned short* Kfl = KSfl + (size_t)((row*4 + g)*3)*9216;
        const float* Bf = KSb32 + (size_t)row*1152 + g*96;

        f32x4 acc[6];
        // layer 1
        #pragma unroll
        for(int mt=0;mt<6;mt++) acc[mt]=f32x4{0,0,0,0};
        #pragma unroll
        for(int kt=0;kt<3;kt++){
            s16x8 bh = *(const s16x8*)(&zth[g*3+kt][pxl][lkb]);
            s16x8 bl = *(const s16x8*)(&ztl[g*3+kt][pxl][lkb]);
            #pragma unroll
            for(int mt=0;mt<6;mt++){
                s16x8 ah = *(const s16x8*)(Kfh + ((mt*3+kt)*64 + lane)*8);
                s16x8 al = *(const s16x8*)(Kfl + ((mt*3+kt)*64 + lane)*8);
                acc[mt] = mfma16(ah, bh, acc[mt]);
                acc[mt] = mfma16(ah, bl, acc[mt]);
                acc[mt] = mfma16(al, bh, acc[mt]);
            }
        }
        #pragma unroll
        for(int mt=0;mt<6;mt++){
            int o0 = mt*16 + lg*4;
            f32x4 bb = *(const f32x4*)(Bf + o0);
            U4 hh, hl;
            #pragma unroll
            for(int q=0;q<4;q++){
                float v = lrelu(acc[mt][q] + bb[q]);
                hh.h[q] = bfrne(v); hl.h[q] = bfrne(v - bf2f(hh.h[q]));
            }
            *(s16x4*)(&lhh[l15*100 + o0]) = hh.v;
            *(s16x4*)(&lhl[l15*100 + o0]) = hl.v;
        }
        // layer 2 (reads all of h1, then overwrites in place)
        #pragma unroll
        for(int mt=0;mt<6;mt++) acc[mt]=f32x4{0,0,0,0};
        #pragma unroll
        for(int kt=0;kt<3;kt++){
            s16x8 bh = *(const s16x8*)(&lhh[l15*100 + kt*32+lkb]);
            s16x8 bl = *(const s16x8*)(&lhl[l15*100 + kt*32+lkb]);
            #pragma unroll
            for(int mt=0;mt<6;mt++){
                s16x8 ah = *(const s16x8*)(Kfh + 9216 + ((mt*3+kt)*64 + lane)*8);
                s16x8 al = *(const s16x8*)(Kfl + 9216 + ((mt*3+kt)*64 + lane)*8);
                acc[mt] = mfma16(ah, bh, acc[mt]);
                acc[mt] = mfma16(ah, bl, acc[mt]);
                acc[mt] = mfma16(al, bh, acc[mt]);
            }
        }
        #pragma unroll
        for(int mt=0;mt<6;mt++){
            int o0 = mt*16 + lg*4;
            f32x4 bb = *(const f32x4*)(Bf + 384 + o0);
            U4 hh, hl;
            #pragma unroll
            for(int q=0;q<4;q++){
                float v = lrelu(acc[mt][q] + bb[q]);
                hh.h[q] = bfrne(v); hl.h[q] = bfrne(v - bf2f(hh.h[q]));
            }
            *(s16x4*)(&lhh[l15*100 + o0]) = hh.v;
            *(s16x4*)(&lhl[l15*100 + o0]) = hl.v;
        }
        // layer 3 + gate (zz hi into zth)
        #pragma unroll
        for(int mt=0;mt<6;mt++) acc[mt]=f32x4{0,0,0,0};
        #pragma unroll
        for(int kt=0;kt<3;kt++){
            s16x8 bh = *(const s16x8*)(&lhh[l15*100 + kt*32+lkb]);
            s16x8 bl = *(const s16x8*)(&lhl[l15*100 + kt*32+lkb]);
            #pragma unroll
            for(int mt=0;mt<6;mt++){
                s16x8 ah = *(const s16x8*)(Kfh + 18432 + ((mt*3+kt)*64 + lane)*8);
                s16x8 al = *(const s16x8*)(Kfl + 18432 + ((mt*3+kt)*64 + lane)*8);
                acc[mt] = mfma16(ah, bh, acc[mt]);
                acc[mt] = mfma16(ah, bl, acc[mt]);
                acc[mt] = mfma16(al, bh, acc[mt]);
            }
        }
        #pragma unroll
        for(int mt=0;mt<6;mt++){
            int o0 = mt*16 + lg*4;
            f32x4 bb = *(const f32x4*)(Bf + 768 + o0);
            int part = g*3 + (o0>>5), cc = o0&31;
            U4 zvh, zvl;
            zvh.v = *(const s16x4*)(&zth[part][pxl][cc]);
            zvl.v = *(const s16x4*)(&ztl[part][pxl][cc]);
            U4 ozh;
            #pragma unroll
            for(int q=0;q<4;q++){
                float zf = bf2f(zvh.h[q]) + bf2f(zvl.h[q]);
                float d  = zf + acc[mt][q] + bb[q];
                float sg = 1.f/(1.f + __expf(-d));
                ozh.h[q] = bfrne(zf*sg);
            }
            *(s16x4*)(&zth[part][pxl][cc]) = ozh.v;   // zz (hi only)
        }
    }
    __syncthreads();   // all zz ready (each pxslot needs parts from both halves)

    // ---- phase 3 G1: wave w does mt in [half*12, half*12+12) for its pxslot ----
    unsigned short* ldx = &lhf[pxslot*6272];     // [16][392]
    f32x4 a1[12];
    #pragma unroll
    for(int lm=0;lm<12;lm++) a1[lm]=f32x4{0,0,0,0};
    #pragma unroll 1
    for(int kt=0;kt<12;kt++){
        FragU bzh, blz;
        bzh.v = *(const s16x8*)(&zth[kt][pxl][lkb]);
        #pragma unroll
        for(int j=0;j<8;j++) blz.h[j] = bfrne(lrelu(bf2f(bzh.h[j])));
        #pragma unroll
        for(int lm=0;lm<12;lm++){
            int mt = half*12 + lm;
            s16x8 af = *(const s16x8*)(w016 + ((size_t)(mt*12+kt)<<9) + (lane<<3));
            a1[lm] = mfma16(af, blz.v, a1[lm]);
        }
    }
    #pragma unroll
    for(int lm=0;lm<12;lm++){
        int mt = half*12 + lm;
        int o0 = mt*16 + lg*4;
        f32x4 bb = *(const f32x4*)(c0b + o0);
        U4 hv;
        #pragma unroll
        for(int q=0;q<4;q++) hv.h[q] = bfrne(lrelu(a1[lm][q] + bb[q]));
        *(s16x4*)(&ldx[l15*392 + o0]) = hv.v;
    }
    __syncthreads();   // dx1 complete for all pxslots

    // ---- G2/G3: wave w -> (pxslot, mt = half) ----
    {
        int mt = half;
        f32x4 a2 = f32x4{0,0,0,0};
        f32x4 a3 = f32x4{0,0,0,0};
        #pragma unroll 1
        for(int kt=0;kt<12;kt++){
            s16x8 bh_ = *(const s16x8*)(&ldx[l15*392 + kt*32 + lkb]);
            s16x8 bzh = *(const s16x8*)(&zth[kt][pxl][lkb]);
            s16x8 af1 = *(const s16x8*)(w116 + ((size_t)(mt*12+kt)<<9) + (lane<<3));
            a2 = mfma16(af1, bh_, a2);
            s16x8 wh = *(const s16x8*)(wcsh + ((size_t)(mt*12+kt)<<9) + (lane<<3));
            s16x8 wl = *(const s16x8*)(wcsl + ((size_t)(mt*12+kt)<<9) + (lane<<3));
            a3 = mfma16(wh, bzh, a3);
            a3 = mfma16(wl, bzh, a3);
        }
        int o0 = mt*16 + lg*4;
        #pragma unroll
        for(int q=0;q<4;q++){
            int o = o0+q;
            int px = y*64 + pxl;
            float dx2 = a2[q] + c1b[o];
            float r   = a3[q] + csb[o] + 0.1f*dx2;
            size_t oidx = (size_t)b*131072 + (size_t)o*4096 + px;
            outNext[oidx] = outPrev[oidx] + 0.1f*r;
        }
    }
}

// ---------------- head ----------------
__global__ __launch_bounds__(256) void k_head1(const float* __restrict__ outF,
    const float* __restrict__ wout, const float* __restrict__ bout, float* __restrict__ state)
{
    __shared__ float sw[97*32];
    __shared__ float sb_[97];
    __shared__ float fp[32];
    __shared__ float fwp[2048];
    int t = threadIdx.x, b = blockIdx.y, pxb = blockIdx.x*256;
    for(int i=t;i<97*32;i+=256) sw[i] = wout[i];
    if(t<97) sb_[t] = bout[t];
    if(t<32) fp[t] = 0.f;
    for(int i=t;i<2048;i+=256) fwp[i] = 0.f;
    __syncthreads();
    int px = pxb + t, lane = t&63, wv = t>>6;
    float xi[32];
    #pragma unroll
    for(int i=0;i<32;i++) xi[i] = outF[(size_t)b*131072 + (size_t)i*4096 + px];
    float* st = state + (size_t)b*8224;
    int row = (pxb>>6) + wv, x = lane;
    for(int o=0;o<97;o++){
        float acc = sb_[o];
        #pragma unroll
        for(int i=0;i<32;i++) acc += sw[o*32+i]*xi[i];
        if(o < 32){
            float s = wave_sum(acc);
            if(lane==0) atomicAdd(&fp[o], s);
        } else if(o < 64){
            float s = wave_sum(acc);
            if(lane==0) st[32 + (o-32)*64 + row] = s*(1.f/64.f);
        } else if(o < 96){
            atomicAdd(&fwp[(o-64)*64 + x], acc);
        } else {
            st[4128 + px] = acc;
        }
    }
    __syncthreads();
    if(t<32) atomicAdd(&st[t], fp[t]*(1.f/4096.f));
    for(int i=t;i<2048;i+=256) atomicAdd(&st[2080+i], fwp[i]*(1.f/64.f));
}

__global__ __launch_bounds__(256) void k_head2(const float* __restrict__ state,
    const float* __restrict__ otlw, float* __restrict__ latout)
{
    __shared__ float ss[8*514];
    int t = threadIdx.x, j = blockIdx.x*256 + t, s0 = blockIdx.y*514;
    for(int i=t;i<8*514;i+=256){ int bb=i/514, si=i-bb*514; ss[i] = state[(size_t)bb*8224 + s0 + si]; }
    __syncthreads();
    float acc[8] = {0,0,0,0,0,0,0,0};
    for(int si=0;si<514;si++){
        float wv_ = otlw[(size_t)(s0+si)*512 + j];
        #pragma unroll
        for(int b2=0;b2<8;b2++) acc[b2] += ss[b2*514+si]*wv_;
    }
    #pragma unroll
    for(int b2=0;b2<8;b2++) atomicAdd(latout + b2*512 + j, acc[b2]);
}

// =============================================================================
extern "C" void kernel_launch(void* const* d_in, const int* in_sizes, int n_in,
                              void* d_out, int out_size, void* d_ws, size_t ws_size,
                              hipStream_t stream)
{
    const float* x    = (const float*)d_in[0];
    const float* inj  = (const float*)d_in[1];
    const float* icw  = (const float*)d_in[2];
    const float* icb  = (const float*)d_in[3];
    const float* flWs = (const float*)d_in[4];
    const float* flbs = (const float*)d_in[5];
    const float* flW0 = (const float*)d_in[6];
    const float* flb0 = (const float*)d_in[7];
    const float* flW1 = (const float*)d_in[8];
    const float* flb1 = (const float*)d_in[9];
    const float* dkWs = (const float*)d_in[10];
    const float* dkbs = (const float*)d_in[11];
    const float* dkW0 = (const float*)d_in[12];
    const float* dkb0 = (const float*)d_in[13];
    const float* dkW1 = (const float*)d_in[14];
    const float* dkb1 = (const float*)d_in[15];
    const float* c0w  = (const float*)d_in[16];
    const float* c0b  = (const float*)d_in[17];
    const float* c1w  = (const float*)d_in[18];
    const float* c1b  = (const float*)d_in[19];
    const float* csw  = (const float*)d_in[20];
    const float* csb  = (const float*)d_in[21];
    const float* ocw  = (const float*)d_in[22];
    const float* ocb  = (const float*)d_in[23];
    const float* otlw = (const float*)d_in[24];
    const float* otlb = (const float*)d_in[25];
    float* out = (float*)d_out;

    char* wp = (char*)d_ws;
    auto carve = [&](size_t bytes)->void*{ void* p = wp; wp += (bytes + 255) & ~(size_t)255; return p; };
    float* lats  = (float*)carve(36864*4);
    float* ppS   = (float*)carve(32768*4);
    float* ppH   = (float*)carve(32768*4);
    float* ppD   = (float*)carve(524288*4);
    float* state = (float*)carve(65792*4);
    float2* stats = (float2*)carve(2304*8);
    unsigned short* Ahi   = (unsigned short*)carve((size_t)98304*2);
    unsigned short* Alo   = (unsigned short*)carve((size_t)98304*2);
    unsigned short* KSfh  = (unsigned short*)carve((size_t)7077888*2);  // frag-major
    unsigned short* KSfl  = (unsigned short*)carve((size_t)7077888*2);
    float*          KSb32 = (float*)carve((size_t)73728*4);
    unsigned short* w016  = (unsigned short*)carve((size_t)147456*2);   // frag-major
    unsigned short* w116  = (unsigned short*)carve((size_t)12288*2);
    unsigned short* wcsh  = (unsigned short*)carve((size_t)12288*2);
    unsigned short* wcsl  = (unsigned short*)carve((size_t)12288*2);

    k_init<<<1009,256,0,stream>>>(state, out, otlb, lats, inj,
                                  w016, c0w, w116, c1w, wcsh, wcsl, csw);
    k_out0<<<4096,256,0,stream>>>(x, icw, icb, out + 4096);

    for(int c=0;c<8;c++){
        const float* latc = lats + c*4096;
        k_latA<<<dim3(4,4,2),256,0,stream>>>(latc, flWs + (size_t)c*262144, flW0 + (size_t)c*262144,
                                             ppS, ppH);
        k_latBC<<<4,256,0,stream>>>(ppH, flb0 + (size_t)c*512,
                                    flW1 + (size_t)c*262144, flb1 + (size_t)c*512,
                                    latc, ppS, flbs + (size_t)c*512, lats + (c+1)*4096);
    }

    k_dkH<<<dim3(8,4),256,0,stream>>>(lats + 4096, dkW0, ppD);
    k_dkAcvt<<<384,256,0,stream>>>(lats + 4096, ppD, dkb0, Ahi, Alo);
    k_dkMain<<<873,256,0,stream>>>(Ahi, Alo, dkWs, dkW1, dkbs, dkb1, KSfh, KSfl, KSb32);

    for(int c=0;c<8;c++){
        const float* outPrev = out + 4096 + (size_t)c*EMB;
        float*       outNext = out + 4096 + (size_t)(c+1)*EMB;
        k_stat<<<dim3(32,8),256,0,stream>>>(outPrev, stats);
        k_mega<<<dim3(64,8),512,0,stream>>>(outPrev, stats, KSfh, KSfl, KSb32,
                                            w016, w116, wcsh, wcsl,
                                            c0b, c1b, csb, outNext, c);
    }

    k_head1<<<dim3(16,8),256,0,stream>>>(out + 4096 + (size_t)8*EMB, ocw, ocb, state);
    k_head2<<<dim3(2,16),256,0,stream>>>(state, otlw, out);
}

// Round 10
// 2415.821 us; speedup vs baseline: 1.6886x; 1.2899x over previous
//
#include <hip/hip_runtime.h>

#define DEV __device__ __forceinline__

typedef __attribute__((ext_vector_type(4))) float  f32x4;
typedef __attribute__((ext_vector_type(8))) short  s16x8;   // 8 bf16 (MFMA frag)
typedef __attribute__((ext_vector_type(4))) short  s16x4;   // 4 bf16 (8B ld/st)

union FragU { s16x8 v; unsigned short h[8]; };
union U4    { s16x4 v; unsigned short h[4]; };

DEV float lrelu(float x){ return x > 0.f ? x : 0.2f*x; }
DEV unsigned short bfrne(float f){
    unsigned u = __builtin_bit_cast(unsigned, f);
    u += 0x7fffu + ((u>>16)&1u);
    return (unsigned short)(u>>16);
}
DEV float bf2f(unsigned short h){
    unsigned u = ((unsigned)h)<<16; return __builtin_bit_cast(float,u);
}
DEV f32x4 mfma16(s16x8 a, s16x8 b, f32x4 c){
    return __builtin_amdgcn_mfma_f32_16x16x32_bf16(a, b, c, 0, 0, 0);
}
DEV float wave_sum(float v){
    #pragma unroll
    for(int m=32;m>0;m>>=1) v += __shfl_xor(v, m, 64);
    return v;
}
DEV void blk_reduce2(float& a, float& b, float* sm){
    a = wave_sum(a); b = wave_sum(b);
    int wv = threadIdx.x>>6, ln = threadIdx.x&63;
    if(ln==0){ sm[wv*2]=a; sm[wv*2+1]=b; }
    __syncthreads();
    a = sm[0]+sm[2]+sm[4]+sm[6];
    b = sm[1]+sm[3]+sm[5]+sm[7];
    __syncthreads();
}

// ---------------- sizes ----------------
#define EMB   1048576               // 8*32*4096, one out_emb
#define DKT   111744

// ---------------- init (weights emitted FRAG-MAJOR) ---------------------------
__global__ __launch_bounds__(256) void k_init(
    float* state, float* latout, const float* otlb,
    float* lats, const float* inj,
    unsigned short* w016, const float* c0w,
    unsigned short* w116, const float* c1w,
    unsigned short* wcsh, unsigned short* wcsl, const float* csw)
{
    int i = blockIdx.x*256 + threadIdx.x;
    if(i < 65792){ state[i] = 0.f; return; }            i -= 65792;
    if(i < 4096){ latout[i] = otlb[i&511]; return; }    i -= 4096;
    if(i < 4096){ lats[i] = inj[i]; return; }           i -= 4096;
    if(i < 147456){
        int j = i&7, ln = (i>>3)&63, f2 = i>>9, mt = f2/12, kt = f2 - mt*12;
        w016[i] = bfrne(c0w[(mt*16 + (ln&15))*384 + kt*32 + (ln>>4)*8 + j]);
        return; }                                       i -= 147456;
    if(i < 12288){
        int j = i&7, ln = (i>>3)&63, f2 = i>>9, mt = f2/12, kt = f2 - mt*12;
        w116[i] = bfrne(c1w[(mt*16 + (ln&15))*384 + kt*32 + (ln>>4)*8 + j]);
        return; }                                       i -= 12288;
    if(i < 12288){
        int j = i&7, ln = (i>>3)&63, f2 = i>>9, mt = f2/12, kt = f2 - mt*12;
        wcsh[i] = bfrne(csw[(mt*16 + (ln&15))*384 + kt*32 + (ln>>4)*8 + j]);
        return; }                                       i -= 12288;
    if(i < 12288){
        int j = i&7, ln = (i>>3)&63, f2 = i>>9, mt = f2/12, kt = f2 - mt*12;
        float w = csw[(mt*16 + (ln&15))*384 + kt*32 + (ln>>4)*8 + j];
        unsigned short hh = bfrne(w);
        wcsl[i] = bfrne(w - bf2f(hh)); return; }
}

// ---------------- out_embs[0] = in_conv(x) ----------------
__global__ __launch_bounds__(256) void k_out0(const float* __restrict__ x,
    const float* __restrict__ w, const float* __restrict__ b, float* __restrict__ out0)
{
    int i = blockIdx.x*256 + threadIdx.x;
    int p = i & 4095, o = (i>>12)&31, bb = i>>17;
    const float* xb = x + (size_t)bb*12288 + p;
    out0[i] = b[o] + w[o*3]*xb[0] + w[o*3+1]*xb[4096] + w[o*3+2]*xb[8192];
}

// ---------------- latent chain (f32, deterministic; BITWISE-FROZEN) -----------
__global__ __launch_bounds__(256) void k_latA(const float* __restrict__ lat,
    const float* __restrict__ Ws, const float* __restrict__ W0,
    float* __restrict__ ppS, float* __restrict__ ppH)
{
    __shared__ float ls[8][128];
    int t = threadIdx.x;
    int kb = blockIdx.y*128;
    for(int i=t;i<1024;i+=256) ls[i>>7][i&127] = lat[(i>>7)*512 + kb + (i&127)];
    __syncthreads();
    const float* W = blockIdx.z ? W0 : Ws;
    float* pp = blockIdx.z ? ppH : ppS;
    int j = blockIdx.x*128 + (t&127);
    int half = t>>7, klo = half*64;
    int p = blockIdx.y*2 + half;
    float acc[8] = {0,0,0,0,0,0,0,0};
    for(int kk=0;kk<64;kk++){
        float wv_ = W[(size_t)(kb+klo+kk)*512 + j];
        #pragma unroll
        for(int m=0;m<8;m++) acc[m] += ls[m][klo+kk]*wv_;
    }
    #pragma unroll
    for(int m=0;m<8;m++) pp[(size_t)(p*8+m)*512 + j] = acc[m];
}

__global__ __launch_bounds__(256) void k_latBC(const float* __restrict__ ppH,
    const float* __restrict__ flb0c,
    const float* __restrict__ W1, const float* __restrict__ b1c,
    const float* __restrict__ latc, const float* __restrict__ ppS,
    const float* __restrict__ flbsc, float* __restrict__ latn)
{
    __shared__ float lh[8][512];
    __shared__ float part[8][128];
    int t = threadIdx.x;
    for(int i=t;i<4096;i+=256){
        int m = i>>9, jj = i&511;
        float v = flb0c[jj];
        #pragma unroll
        for(int p=0;p<8;p++) v += ppH[(size_t)(p*8+m)*512 + jj];
        lh[m][jj] = lrelu(v);
    }
    __syncthreads();
    int j = blockIdx.x*128 + (t&127), half = t>>7;
    float acc[8] = {0,0,0,0,0,0,0,0};
    int k0 = half*256;
    for(int kk=k0;kk<k0+256;kk++){
        float w = W1[(size_t)kk*512 + j];
        #pragma unroll
        for(int m=0;m<8;m++) acc[m] += lh[m][kk]*w;
    }
    if(half==1){
        #pragma unroll
        for(int m=0;m<8;m++) part[m][t&127] = acc[m];
    }
    __syncthreads();
    if(half==0){
        #pragma unroll
        for(int m=0;m<8;m++){
            float sv = flbsc[j];
            #pragma unroll
            for(int p=0;p<8;p++) sv += ppS[(size_t)(p*8+m)*512 + j];
            float t1 = acc[m] + part[m][t&127] + b1c[j];
            latn[m*512+j] = latc[m*512+j] + 0.1f*sv + 0.01f*t1;
        }
    }
}

// ---------------- DK hidden partials (deterministic; BITWISE-FROZEN) ----------
__global__ __launch_bounds__(256) void k_dkH(const float* __restrict__ latsAll,
    const float* __restrict__ W0, float* __restrict__ ppD)
{
    __shared__ float ls[64][128];
    int t = threadIdx.x;
    int kb = blockIdx.y*128;
    for(int i=t;i<8192;i+=256) ls[i>>7][i&127] = latsAll[(i>>7)*512 + kb + (i&127)];
    __syncthreads();
    int j = blockIdx.x*128 + (t&127);
    int ksub = t>>7;
    int p = blockIdx.y*2 + ksub;
    for(int mc=0;mc<4;mc++){
        float acc[16] = {0,0,0,0,0,0,0,0,0,0,0,0,0,0,0,0};
        for(int kk=0;kk<64;kk++){
            float wv_ = W0[(size_t)(kb + ksub*64 + kk)*1024 + j];
            #pragma unroll
            for(int mi=0;mi<16;mi++) acc[mi] += ls[mc*16+mi][ksub*64+kk]*wv_;
        }
        #pragma unroll
        for(int mi=0;mi<16;mi++) ppD[(size_t)(p*64 + mc*16+mi)*1024 + j] = acc[mi];
    }
}

__global__ __launch_bounds__(256) void k_dkAcvt(const float* __restrict__ latsAll,
    const float* __restrict__ ppD, const float* __restrict__ dkb0,
    unsigned short* __restrict__ Ahi, unsigned short* __restrict__ Alo)
{
    int i = blockIdx.x*256 + threadIdx.x;
    int m = i/1536, k = i - m*1536;
    float v;
    if(k < 512) v = latsAll[m*512 + k];
    else {
        int j = k - 512;
        float hv = dkb0[j];
        #pragma unroll
        for(int p=0;p<8;p++) hv += ppD[(size_t)(p*64+m)*1024 + j];
        v = 0.1f*lrelu(hv);
    }
    unsigned short hh = bfrne(v);
    Ahi[i] = hh; Alo[i] = bfrne(v - bf2f(hh));
}

// ---------------- KS GEMM; epilogue writes FRAG-MAJOR directly ----------------
__global__ __launch_bounds__(256) void k_dkMain(const unsigned short* __restrict__ Ahi,
    const unsigned short* __restrict__ Alo,
    const float* __restrict__ Wsb, const float* __restrict__ W1b,
    const float* __restrict__ bs, const float* __restrict__ b1,
    unsigned short* __restrict__ KSfh, unsigned short* __restrict__ KSfl,
    float* __restrict__ KSb32)
{
    __shared__ unsigned short Wh[64][138];
    __shared__ unsigned short Wl[64][138];
    __shared__ unsigned short Ah[64][72];
    __shared__ unsigned short Al[64][72];
    int t = threadIdx.x, wv = t>>6, lane = t&63, l15 = lane&15, lg = lane>>4, lkb = lg*8;
    int n0 = blockIdx.x*128;
    int sk = t>>5, sc = (t&31)*4;
    int am = t>>2, ac = (t&3)*16;

    f32x4 wreg[8];
    s16x8 ah0, ah1, al0, al1;
    {
        #pragma unroll
        for(int s=0;s<8;s++)
            wreg[s] = *(const f32x4*)(Wsb + (size_t)(sk + s*8)*DKT + n0 + sc);
        const unsigned short* Abh = Ahi + am*1536 + ac;
        const unsigned short* Abl = Alo + am*1536 + ac;
        ah0 = *(const s16x8*)(Abh);     ah1 = *(const s16x8*)(Abh + 8);
        al0 = *(const s16x8*)(Abl);     al1 = *(const s16x8*)(Abl + 8);
    }

    f32x4 acc[4][2];
    #pragma unroll
    for(int mt=0;mt<4;mt++){ acc[mt][0]=f32x4{0,0,0,0}; acc[mt][1]=f32x4{0,0,0,0}; }

    for(int kt=0;kt<24;kt++){
        #pragma unroll
        for(int s=0;s<8;s++){
            int k = sk + s*8;
            unsigned short hh[4], ll[4];
            #pragma unroll
            for(int e=0;e<4;e++){
                float w = wreg[s][e];
                hh[e] = bfrne(w); ll[e] = bfrne(w - bf2f(hh[e]));
            }
            *(unsigned*)(&Wh[k][sc])   = (unsigned)hh[0] | ((unsigned)hh[1]<<16);
            *(unsigned*)(&Wh[k][sc+2]) = (unsigned)hh[2] | ((unsigned)hh[3]<<16);
            *(unsigned*)(&Wl[k][sc])   = (unsigned)ll[0] | ((unsigned)ll[1]<<16);
            *(unsigned*)(&Wl[k][sc+2]) = (unsigned)ll[2] | ((unsigned)ll[3]<<16);
        }
        *(s16x8*)(&Ah[am][ac]) = ah0;  *(s16x8*)(&Ah[am][ac+8]) = ah1;
        *(s16x8*)(&Al[am][ac]) = al0;  *(s16x8*)(&Al[am][ac+8]) = al1;
        __syncthreads();
        if(kt < 23){
            int kn = kt+1;
            const float* Wb = (kn<8) ? (Wsb + (size_t)(kn*64)*DKT)
                                     : (W1b + (size_t)(kn*64-512)*DKT);
            #pragma unroll
            for(int s=0;s<8;s++)
                wreg[s] = *(const f32x4*)(Wb + (size_t)(sk + s*8)*DKT + n0 + sc);
            const unsigned short* Abh = Ahi + am*1536 + kn*64 + ac;
            const unsigned short* Abl = Alo + am*1536 + kn*64 + ac;
            ah0 = *(const s16x8*)(Abh);     ah1 = *(const s16x8*)(Abh + 8);
            al0 = *(const s16x8*)(Abl);     al1 = *(const s16x8*)(Abl + 8);
        }
        #pragma unroll
        for(int ks=0;ks<2;ks++){
            s16x8 afh[4], afl[4];
            #pragma unroll
            for(int mt=0;mt<4;mt++){
                afh[mt] = *(const s16x8*)(&Ah[mt*16+l15][ks*32+lkb]);
                afl[mt] = *(const s16x8*)(&Al[mt*16+l15][ks*32+lkb]);
            }
            #pragma unroll
            for(int nt=0;nt<2;nt++){
                int col = wv*32 + nt*16 + l15;
                FragU bh, bl;
                #pragma unroll
                for(int j=0;j<8;j++){
                    bh.h[j] = Wh[ks*32+lkb+j][col];
                    bl.h[j] = Wl[ks*32+lkb+j][col];
                }
                #pragma unroll
                for(int mt=0;mt<4;mt++){
                    acc[mt][nt] = mfma16(afh[mt], bh.v, acc[mt][nt]);
                    acc[mt][nt] = mfma16(afh[mt], bl.v, acc[mt][nt]);
                    acc[mt][nt] = mfma16(afl[mt], bh.v, acc[mt][nt]);
                }
            }
        }
        __syncthreads();
    }
    // epilogue: write frag-major (bitwise-identical values)
    #pragma unroll
    for(int nt=0;nt<2;nt++){
        int n = n0 + wv*32 + nt*16 + l15;
        float bias = bs[n] + 0.1f*b1[n];
        bool isW = (n < 110592);
        size_t colpart = 0; int nb2 = 0;
        if(isW){
            int L = n / 36864, rem = n - L*36864;
            int g = rem / 9216; int rem2 = rem - g*9216;
            int oo = rem2 / 96; int kk = rem2 - oo*96;
            int lane2 = (((kk&31)>>3)<<4) + (oo&15);
            int f = (oo>>4)*3 + (kk>>5);
            colpart = ((((size_t)(g*3 + L))*18 + f)*64 + lane2)*8 + (kk&7);
        } else nb2 = n - 110592;
        #pragma unroll
        for(int mt=0;mt<4;mt++)
            #pragma unroll
            for(int q=0;q<4;q++){
                int row = mt*16 + lg*4 + q;
                float v = acc[mt][nt][q] + bias;
                unsigned short hh = bfrne(v);
                if(isW){
                    size_t dst = (size_t)row*110592 + colpart;
                    KSfh[dst] = hh;
                    KSfl[dst] = bfrne(v - bf2f(hh));
                } else {
                    KSb32[(size_t)row*1152 + nb2] = v;
                }
            }
    }
}

// ---------------- stats + raw conv dump (gx/gy to gxy, coalesced f32) ---------
__global__ __launch_bounds__(256) void k_stat(const float* __restrict__ outPrev,
    float2* __restrict__ stats, float* __restrict__ gxy)
{
    __shared__ float img[4096], va[4096], vb[4096];
    __shared__ float ct[17], stp[17];
    __shared__ float red[8];
    int t = threadIdx.x, ch = blockIdx.x, b = blockIdx.y;
    const float* src = outPrev + ((size_t)b*32 + ch)*4096;
    float2* stc = stats + (b*32 + ch)*9;
    float* gb = gxy + ((size_t)(b*32 + ch)*8)*4096;
    for(int i=t;i<4096;i+=256) img[i] = src[i];
    __syncthreads();
    float s0=0.f, s1=0.f;
    for(int i=t;i<4096;i+=256){ float v=img[i]; s0+=v; s1+=v*v; }
    blk_reduce2(s0, s1, red);
    float mu = s0*(1.f/4096.f);
    float var = s1*(1.f/4096.f) - mu*mu; var = var<0.f?0.f:var;
    if(t==0) stc[0] = make_float2(mu, rsqrtf(var + 1e-5f));
    const int ksz[4] = {3,5,9,17};
    for(int s=0;s<4;s++){
        int k = ksz[s], p = (k-1)>>1;
        if(t < k){
            float cc = -1.f + 2.f*(float)t/(float)(k-1);
            ct[t]  = cosf(1.5707963267948966f*cc);
            stp[t] = sinf(1.5707963267948966f*cc);
        }
        __syncthreads();
        for(int i=t;i<4096;i+=256){
            int y = i>>6, x = i&63; float ac=0.f, as=0.f;
            for(int tt=0;tt<k;tt++){
                int yy = y+tt-p;
                if(yy>=0 && yy<64){ float f = img[yy*64+x]; ac += ct[tt]*f; as += stp[tt]*f; }
            }
            va[i]=ac; vb[i]=as;
        }
        __syncthreads();
        float gx0=0.f,gx1=0.f,gy0=0.f,gy1=0.f;
        float* g0 = gb + (size_t)(2*s)*4096;
        float* g1 = gb + (size_t)(2*s+1)*4096;
        for(int i=t;i<4096;i+=256){
            int y=i>>6, x=i&63; float gx=0.f, gy=0.f;
            for(int tt=0;tt<k;tt++){
                int xx = x+tt-p;
                if(xx>=0 && xx<64){ gx += stp[tt]*va[y*64+xx]; gy += ct[tt]*vb[y*64+xx]; }
            }
            g0[i] = gx; g1[i] = gy;               // raw conv dump (coalesced)
            gx0+=gx; gx1+=gx*gx; gy0+=gy; gy1+=gy*gy;
        }
        blk_reduce2(gx0, gx1, red);
        blk_reduce2(gy0, gy1, red);
        float mgx = gx0*(1.f/4096.f), vgx = gx1*(1.f/4096.f)-mgx*mgx; vgx=vgx<0.f?0.f:vgx;
        float mgy = gy0*(1.f/4096.f), vgy = gy1*(1.f/4096.f)-mgy*mgy; vgy=vgy<0.f?0.f:vgy;
        if(t==0){
            stc[1+2*s] = make_float2(mgx, rsqrtf(vgx+1e-5f));
            stc[2+2*s] = make_float2(mgy, rsqrtf(vgy+1e-5f));
        }
        __syncthreads();
    }
}

// ---------------- MEGA v3: z-build from precomputed conv; dyna; res_block -----
// 512 threads (8 waves). wave w: pxslot = w&3 (16 px), half = w>>2.
__global__ __launch_bounds__(512) void k_mega(const float* __restrict__ outPrev,
    const float2* __restrict__ stats, const float* __restrict__ gxy,
    const unsigned short* __restrict__ KSfh, const unsigned short* __restrict__ KSfl,
    const float* __restrict__ KSb32,
    const unsigned short* __restrict__ w016, const unsigned short* __restrict__ w116,
    const unsigned short* __restrict__ wcsh, const unsigned short* __restrict__ wcsl,
    const float* __restrict__ c0b, const float* __restrict__ c1b,
    const float* __restrict__ csb,
    float* __restrict__ outNext, int cCall)
{
    __shared__ __align__(16) unsigned short zth[12][64][32];   // 48 KB
    __shared__ __align__(16) unsigned short ztl[12][64][32];   // 48 KB
    __shared__ __align__(16) unsigned short lhf[25600];        // 50 KB
    __shared__ float2 sst[288];
    int t = threadIdx.x, x = t&63, cq = t>>6;     // cq = wave 0..7
    int y = blockIdx.x, b = blockIdx.y;
    const float* ob = outPrev + (size_t)b*131072;
    for(int i=t;i<288;i+=512) sst[i] = stats[b*288 + i];
    __syncthreads();
    // ---- phase 1: build z in LDS from ob (id) + gxy (conv), normalize --------
    #pragma unroll
    for(int i=0;i<4;i++){
        int ch = cq*4 + i;
        float v = ob[(size_t)ch*4096 + y*64 + x];
        float2 sr = sst[ch*9];
        float z = (v - sr.x)*sr.y;
        unsigned short hh = bfrne(z), hl = bfrne(z - bf2f(hh));
        #pragma unroll
        for(int s=0;s<4;s++){ zth[3*s][x][ch] = hh; ztl[3*s][x][ch] = hl; }
        const float* gsrc = gxy + ((size_t)(b*32 + ch)*8)*4096 + y*64 + x;
        #pragma unroll
        for(int s=0;s<4;s++){
            float gx = gsrc[(size_t)(2*s)*4096];
            float gy = gsrc[(size_t)(2*s+1)*4096];
            float2 sx = sst[ch*9 + 1+2*s], sy = sst[ch*9 + 2+2*s];
            float zx = (gx - sx.x)*sx.y, zy = (gy - sy.x)*sy.y;
            unsigned short hx = bfrne(zx), hy = bfrne(zy);
            zth[3*s+1][x][ch] = hx; ztl[3*s+1][x][ch] = bfrne(zx - bf2f(hx));
            zth[3*s+2][x][ch] = hy; ztl[3*s+2][x][ch] = bfrne(zy - bf2f(hy));
        }
    }
    __syncthreads();    // all z in LDS

    // ---- phase 2: dyna. wave w: pxslot, 2 groups ----
    int lane = t&63, l15 = lane&15, lg = lane>>4, lkb = lg*8, w = cq;
    int pxslot = w&3, half = w>>2;
    int row = cCall*8 + b;
    int pxl = pxslot*16 + l15;
    unsigned short* lhh = &lhf[w*3200];          // [16][100]
    unsigned short* lhl = &lhf[w*3200 + 1600];
    #pragma unroll 1
    for(int gi=0; gi<2; gi++){
        int g = half*2 + gi;
        const unsigned short* Kfh = KSfh + (size_t)((row*4 + g)*3)*9216;
        const unsigned short* Kfl = KSfl + (size_t)((row*4 + g)*3)*9216;
        const float* Bf = KSb32 + (size_t)row*1152 + g*96;

        f32x4 acc[6];
        // layer 1
        #pragma unroll
        for(int mt=0;mt<6;mt++) acc[mt]=f32x4{0,0,0,0};
        #pragma unroll
        for(int kt=0;kt<3;kt++){
            s16x8 bh = *(const s16x8*)(&zth[g*3+kt][pxl][lkb]);
            s16x8 bl = *(const s16x8*)(&ztl[g*3+kt][pxl][lkb]);
            #pragma unroll
            for(int mt=0;mt<6;mt++){
                s16x8 ah = *(const s16x8*)(Kfh + ((mt*3+kt)*64 + lane)*8);
                s16x8 al = *(const s16x8*)(Kfl + ((mt*3+kt)*64 + lane)*8);
                acc[mt] = mfma16(ah, bh, acc[mt]);
                acc[mt] = mfma16(ah, bl, acc[mt]);
                acc[mt] = mfma16(al, bh, acc[mt]);
            }
        }
        #pragma unroll
        for(int mt=0;mt<6;mt++){
            int o0 = mt*16 + lg*4;
            f32x4 bb = *(const f32x4*)(Bf + o0);
            U4 hh, hl;
            #pragma unroll
            for(int q=0;q<4;q++){
                float v = lrelu(acc[mt][q] + bb[q]);
                hh.h[q] = bfrne(v); hl.h[q] = bfrne(v - bf2f(hh.h[q]));
            }
            *(s16x4*)(&lhh[l15*100 + o0]) = hh.v;
            *(s16x4*)(&lhl[l15*100 + o0]) = hl.v;
        }
        // layer 2
        #pragma unroll
        for(int mt=0;mt<6;mt++) acc[mt]=f32x4{0,0,0,0};
        #pragma unroll
        for(int kt=0;kt<3;kt++){
            s16x8 bh = *(const s16x8*)(&lhh[l15*100 + kt*32+lkb]);
            s16x8 bl = *(const s16x8*)(&lhl[l15*100 + kt*32+lkb]);
            #pragma unroll
            for(int mt=0;mt<6;mt++){
                s16x8 ah = *(const s16x8*)(Kfh + 9216 + ((mt*3+kt)*64 + lane)*8);
                s16x8 al = *(const s16x8*)(Kfl + 9216 + ((mt*3+kt)*64 + lane)*8);
                acc[mt] = mfma16(ah, bh, acc[mt]);
                acc[mt] = mfma16(ah, bl, acc[mt]);
                acc[mt] = mfma16(al, bh, acc[mt]);
            }
        }
        #pragma unroll
        for(int mt=0;mt<6;mt++){
            int o0 = mt*16 + lg*4;
            f32x4 bb = *(const f32x4*)(Bf + 384 + o0);
            U4 hh, hl;
            #pragma unroll
            for(int q=0;q<4;q++){
                float v = lrelu(acc[mt][q] + bb[q]);
                hh.h[q] = bfrne(v); hl.h[q] = bfrne(v - bf2f(hh.h[q]));
            }
            *(s16x4*)(&lhh[l15*100 + o0]) = hh.v;
            *(s16x4*)(&lhl[l15*100 + o0]) = hl.v;
        }
        // layer 3 + gate (zz hi into zth)
        #pragma unroll
        for(int mt=0;mt<6;mt++) acc[mt]=f32x4{0,0,0,0};
        #pragma unroll
        for(int kt=0;kt<3;kt++){
            s16x8 bh = *(const s16x8*)(&lhh[l15*100 + kt*32+lkb]);
            s16x8 bl = *(const s16x8*)(&lhl[l15*100 + kt*32+lkb]);
            #pragma unroll
            for(int mt=0;mt<6;mt++){
                s16x8 ah = *(const s16x8*)(Kfh + 18432 + ((mt*3+kt)*64 + lane)*8);
                s16x8 al = *(const s16x8*)(Kfl + 18432 + ((mt*3+kt)*64 + lane)*8);
                acc[mt] = mfma16(ah, bh, acc[mt]);
                acc[mt] = mfma16(ah, bl, acc[mt]);
                acc[mt] = mfma16(al, bh, acc[mt]);
            }
        }
        #pragma unroll
        for(int mt=0;mt<6;mt++){
            int o0 = mt*16 + lg*4;
            f32x4 bb = *(const f32x4*)(Bf + 768 + o0);
            int part = g*3 + (o0>>5), cc = o0&31;
            U4 zvh, zvl;
            zvh.v = *(const s16x4*)(&zth[part][pxl][cc]);
            zvl.v = *(const s16x4*)(&ztl[part][pxl][cc]);
            U4 ozh;
            #pragma unroll
            for(int q=0;q<4;q++){
                float zf = bf2f(zvh.h[q]) + bf2f(zvl.h[q]);
                float d  = zf + acc[mt][q] + bb[q];
                float sg = 1.f/(1.f + __expf(-d));
                ozh.h[q] = bfrne(zf*sg);
            }
            *(s16x4*)(&zth[part][pxl][cc]) = ozh.v;   // zz (hi only)
        }
    }
    __syncthreads();   // all zz ready

    // ---- phase 3 G1: wave w does mt in [half*12, half*12+12) for its pxslot ----
    unsigned short* ldx = &lhf[pxslot*6272];     // [16][392]
    f32x4 a1[12];
    #pragma unroll
    for(int lm=0;lm<12;lm++) a1[lm]=f32x4{0,0,0,0};
    #pragma unroll 1
    for(int kt=0;kt<12;kt++){
        FragU bzh, blz;
        bzh.v = *(const s16x8*)(&zth[kt][pxl][lkb]);
        #pragma unroll
        for(int j=0;j<8;j++) blz.h[j] = bfrne(lrelu(bf2f(bzh.h[j])));
        #pragma unroll
        for(int lm=0;lm<12;lm++){
            int mt = half*12 + lm;
            s16x8 af = *(const s16x8*)(w016 + ((size_t)(mt*12+kt)<<9) + (lane<<3));
            a1[lm] = mfma16(af, blz.v, a1[lm]);
        }
    }
    #pragma unroll
    for(int lm=0;lm<12;lm++){
        int mt = half*12 + lm;
        int o0 = mt*16 + lg*4;
        f32x4 bb = *(const f32x4*)(c0b + o0);
        U4 hv;
        #pragma unroll
        for(int q=0;q<4;q++) hv.h[q] = bfrne(lrelu(a1[lm][q] + bb[q]));
        *(s16x4*)(&ldx[l15*392 + o0]) = hv.v;
    }
    __syncthreads();   // dx1 complete for all pxslots

    // ---- G2/G3: wave w -> (pxslot, mt = half) ----
    {
        int mt = half;
        f32x4 a2 = f32x4{0,0,0,0};
        f32x4 a3 = f32x4{0,0,0,0};
        #pragma unroll 1
        for(int kt=0;kt<12;kt++){
            s16x8 bh_ = *(const s16x8*)(&ldx[l15*392 + kt*32 + lkb]);
            s16x8 bzh = *(const s16x8*)(&zth[kt][pxl][lkb]);
            s16x8 af1 = *(const s16x8*)(w116 + ((size_t)(mt*12+kt)<<9) + (lane<<3));
            a2 = mfma16(af1, bh_, a2);
            s16x8 wh = *(const s16x8*)(wcsh + ((size_t)(mt*12+kt)<<9) + (lane<<3));
            s16x8 wl = *(const s16x8*)(wcsl + ((size_t)(mt*12+kt)<<9) + (lane<<3));
            a3 = mfma16(wh, bzh, a3);
            a3 = mfma16(wl, bzh, a3);
        }
        int o0 = mt*16 + lg*4;
        #pragma unroll
        for(int q=0;q<4;q++){
            int o = o0+q;
            int px = y*64 + pxl;
            float dx2 = a2[q] + c1b[o];
            float r   = a3[q] + csb[o] + 0.1f*dx2;
            size_t oidx = (size_t)b*131072 + (size_t)o*4096 + px;
            outNext[oidx] = outPrev[oidx] + 0.1f*r;
        }
    }
}

// ---------------- head ----------------
__global__ __launch_bounds__(256) void k_head1(const float* __restrict__ outF,
    const float* __restrict__ wout, const float* __restrict__ bout, float* __restrict__ state)
{
    __shared__ float sw[97*32];
    __shared__ float sb_[97];
    __shared__ float fp[32];
    __shared__ float fwp[2048];
    int t = threadIdx.x, b = blockIdx.y, pxb = blockIdx.x*256;
    for(int i=t;i<97*32;i+=256) sw[i] = wout[i];
    if(t<97) sb_[t] = bout[t];
    if(t<32) fp[t] = 0.f;
    for(int i=t;i<2048;i+=256) fwp[i] = 0.f;
    __syncthreads();
    int px = pxb + t, lane = t&63, wv = t>>6;
    float xi[32];
    #pragma unroll
    for(int i=0;i<32;i++) xi[i] = outF[(size_t)b*131072 + (size_t)i*4096 + px];
    float* st = state + (size_t)b*8224;
    int row = (pxb>>6) + wv, x = lane;
    for(int o=0;o<97;o++){
        float acc = sb_[o];
        #pragma unroll
        for(int i=0;i<32;i++) acc += sw[o*32+i]*xi[i];
        if(o < 32){
            float s = wave_sum(acc);
            if(lane==0) atomicAdd(&fp[o], s);
        } else if(o < 64){
            float s = wave_sum(acc);
            if(lane==0) st[32 + (o-32)*64 + row] = s*(1.f/64.f);
        } else if(o < 96){
            atomicAdd(&fwp[(o-64)*64 + x], acc);
        } else {
            st[4128 + px] = acc;
        }
    }
    __syncthreads();
    if(t<32) atomicAdd(&st[t], fp[t]*(1.f/4096.f));
    for(int i=t;i<2048;i+=256) atomicAdd(&st[2080+i], fwp[i]*(1.f/64.f));
}

__global__ __launch_bounds__(256) void k_head2(const float* __restrict__ state,
    const float* __restrict__ otlw, float* __restrict__ latout)
{
    __shared__ float ss[8*514];
    int t = threadIdx.x, j = blockIdx.x*256 + t, s0 = blockIdx.y*514;
    for(int i=t;i<8*514;i+=256){ int bb=i/514, si=i-bb*514; ss[i] = state[(size_t)bb*8224 + s0 + si]; }
    __syncthreads();
    float acc[8] = {0,0,0,0,0,0,0,0};
    for(int si=0;si<514;si++){
        float wv_ = otlw[(size_t)(s0+si)*512 + j];
        #pragma unroll
        for(int b2=0;b2<8;b2++) acc[b2] += ss[b2*514+si]*wv_;
    }
    #pragma unroll
    for(int b2=0;b2<8;b2++) atomicAdd(latout + b2*512 + j, acc[b2]);
}

// =============================================================================
extern "C" void kernel_launch(void* const* d_in, const int* in_sizes, int n_in,
                              void* d_out, int out_size, void* d_ws, size_t ws_size,
                              hipStream_t stream)
{
    const float* x    = (const float*)d_in[0];
    const float* inj  = (const float*)d_in[1];
    const float* icw  = (const float*)d_in[2];
    const float* icb  = (const float*)d_in[3];
    const float* flWs = (const float*)d_in[4];
    const float* flbs = (const float*)d_in[5];
    const float* flW0 = (const float*)d_in[6];
    const float* flb0 = (const float*)d_in[7];
    const float* flW1 = (const float*)d_in[8];
    const float* flb1 = (const float*)d_in[9];
    const float* dkWs = (const float*)d_in[10];
    const float* dkbs = (const float*)d_in[11];
    const float* dkW0 = (const float*)d_in[12];
    const float* dkb0 = (const float*)d_in[13];
    const float* dkW1 = (const float*)d_in[14];
    const float* dkb1 = (const float*)d_in[15];
    const float* c0w  = (const float*)d_in[16];
    const float* c0b  = (const float*)d_in[17];
    const float* c1w  = (const float*)d_in[18];
    const float* c1b  = (const float*)d_in[19];
    const float* csw  = (const float*)d_in[20];
    const float* csb  = (const float*)d_in[21];
    const float* ocw  = (const float*)d_in[22];
    const float* ocb  = (const float*)d_in[23];
    const float* otlw = (const float*)d_in[24];
    const float* otlb = (const float*)d_in[25];
    float* out = (float*)d_out;

    char* wp = (char*)d_ws;
    auto carve = [&](size_t bytes)->void*{ void* p = wp; wp += (bytes + 255) & ~(size_t)255; return p; };
    float* lats  = (float*)carve(36864*4);
    float* ppS   = (float*)carve(32768*4);
    float* ppH   = (float*)carve(32768*4);
    float* ppD   = (float*)carve(524288*4);
    float* state = (float*)carve(65792*4);
    float2* stats = (float2*)carve(2304*8);
    float* gxy   = (float*)carve((size_t)8388608*4);                    // [8][32][8][4096] raw conv
    unsigned short* Ahi   = (unsigned short*)carve((size_t)98304*2);
    unsigned short* Alo   = (unsigned short*)carve((size_t)98304*2);
    unsigned short* KSfh  = (unsigned short*)carve((size_t)7077888*2);  // frag-major
    unsigned short* KSfl  = (unsigned short*)carve((size_t)7077888*2);
    float*          KSb32 = (float*)carve((size_t)73728*4);
    unsigned short* w016  = (unsigned short*)carve((size_t)147456*2);   // frag-major
    unsigned short* w116  = (unsigned short*)carve((size_t)12288*2);
    unsigned short* wcsh  = (unsigned short*)carve((size_t)12288*2);
    unsigned short* wcsl  = (unsigned short*)carve((size_t)12288*2);

    k_init<<<1009,256,0,stream>>>(state, out, otlb, lats, inj,
                                  w016, c0w, w116, c1w, wcsh, wcsl, csw);
    k_out0<<<4096,256,0,stream>>>(x, icw, icb, out + 4096);

    for(int c=0;c<8;c++){
        const float* latc = lats + c*4096;
        k_latA<<<dim3(4,4,2),256,0,stream>>>(latc, flWs + (size_t)c*262144, flW0 + (size_t)c*262144,
                                             ppS, ppH);
        k_latBC<<<4,256,0,stream>>>(ppH, flb0 + (size_t)c*512,
                                    flW1 + (size_t)c*262144, flb1 + (size_t)c*512,
                                    latc, ppS, flbs + (size_t)c*512, lats + (c+1)*4096);
    }

    k_dkH<<<dim3(8,4),256,0,stream>>>(lats + 4096, dkW0, ppD);
    k_dkAcvt<<<384,256,0,stream>>>(lats + 4096, ppD, dkb0, Ahi, Alo);
    k_dkMain<<<873,256,0,stream>>>(Ahi, Alo, dkWs, dkW1, dkbs, dkb1, KSfh, KSfl, KSb32);

    for(int c=0;c<8;c++){
        const float* outPrev = out + 4096 + (size_t)c*EMB;
        float*       outNext = out + 4096 + (size_t)(c+1)*EMB;
        k_stat<<<dim3(32,8),256,0,stream>>>(outPrev, stats, gxy);
        k_mega<<<dim3(64,8),512,0,stream>>>(outPrev, stats, gxy, KSfh, KSfl, KSb32,
                                            w016, w116, wcsh, wcsl,
                                            c0b, c1b, csb, outNext, c);
    }

    k_head1<<<dim3(16,8),256,0,stream>>>(out + 4096 + (size_t)8*EMB, ocw, ocb, state);
    k_head2<<<dim3(2,16),256,0,stream>>>(state, otlw, out);
}